// Round 14
// baseline (444.632 us; speedup 1.0000x reference)
//
#include <hip/hip_runtime.h>
#include <hip/hip_bf16.h>

#define Bq 2
#define Cc 64
#define Hh 48
#define Ww 48
#define Ll 2304
#define NHh 8
#define DKk 64
#define DVv 128
#define DNn 128
#define NSs 16
#define Rr 4
#define SCH 48
#define SNC 48
#define TT 8      // tokens per block in GEMM-ish kernels

// ---- workspace layout (float offsets) ----
#define OQ    0u                 // (B*8, L, 64) Q bf16 (ushort), pre-scaled by 1/8
#define OK_   2359296u           // (B*8, L, 64) K bf16 (ushort)
#define OV    4718592u           // (B*8, L, 128) V fp32
#define OO    9437184u           // (B, L, 1024) attention out fp32
#define OX2   15040512u
#define OVT   15630336u          // (B*8, 128, L) V^T bf16 (ushort)
#define WS_NEED_FLOATS (OVT + 4718592u)
// aliases (lifetimes: q,k,v,vt dead after k_attn; o dead after k_oprojxz)
#define ODT2  OQ                 // (B*4, L, 128) dt, l-major
#define OYS2  OK_                // (B*4, L, 128) scan y, l-major
#define OX1P  OV                 // (B,L,128)
#define OZ    (OV + 589824u)     // (B,L,128)
#define OX1S  (OV + 1179648u)    // (B,L,128)
#define OBS2  (OV + 1769472u)    // (B*4, L, 16)
#define OCS2  (OV + 2064384u)    // (B*4, L, 16)
#define OCSA  (OV + 2359296u)    // (B*4, SNC, 128, 16)
#define OCSB  (OV + 3145728u)    // (B*4, SNC, 128, 16)
#define OHST  (OV + 3932160u)    // (B*4, SNC, 128, 16)
#define OH1A  OO                 // (B,L,256)
#define OH1B  (OO + 1179648u)    // (B,L,256)

typedef short short8v __attribute__((ext_vector_type(8)));
typedef short short4v __attribute__((ext_vector_type(4)));
typedef float f32x4 __attribute__((ext_vector_type(4)));
typedef unsigned short ushort_t;

__device__ __forceinline__ float geluf(float x) {
  return 0.5f * x * (1.0f + erff(x * 0.70710678118654752f));
}
__device__ __forceinline__ float siluf(float x) {
  return x / (1.0f + __expf(-x));
}
__device__ __forceinline__ float softplusf(float x) {
  return fmaxf(x, 0.0f) + log1pf(__expf(-fabsf(x)));
}
__device__ __forceinline__ int spmap(int k, int l) {
  if (k == 0) return l;
  if (k == 1) return (l % 48) * 48 + l / 48;
  if (k == 2) return 2303 - l;
  int l2 = 2303 - l; return (l2 % 48) * 48 + l2 / 48;
}
__device__ __forceinline__ short f2bf(float f) {
  unsigned u = __float_as_uint(f);
  unsigned r = (u + 0x7FFFu + ((u >> 16) & 1u)) >> 16;
  return (short)r;
}

__global__ void k_code(float* out) { if (threadIdx.x == 0) out[0] = 25000.f; }

// ============ 1. QKV projection, 8 tokens/block (V fp32, coalesced) ============
__global__ __launch_bounds__(256) void k_qkv(const float* __restrict__ enc,
    const float* __restrict__ wq, const float* __restrict__ wk,
    const float* __restrict__ wv, float* __restrict__ ws) {
  int l0 = blockIdx.x * TT; int b = blockIdx.y;
  int t = threadIdx.x;
  __shared__ float xs[64][12];   // [c][token]
  {
    int idx = t, c = idx >> 3, i = idx & 7;
    xs[c][i] = enc[(size_t)b * Cc * Ll + (size_t)c * Ll + l0 + i];
    idx = t + 256; c = idx >> 3; i = idx & 7;
    xs[c][i] = enc[(size_t)b * Cc * Ll + (size_t)c * Ll + l0 + i];
  }
  __syncthreads();
  ushort_t* qb = (ushort_t*)(ws + OQ);
  ushort_t* kb = (ushort_t*)(ws + OK_);
  float* v = ws + OV;
#pragma unroll
  for (int g = 0; g < 6; ++g) {
    int j = t + g * 256;
    float acc[TT];
#pragma unroll
    for (int i = 0; i < TT; ++i) acc[i] = 0.f;
    const float* wp; int col, stride;
    if (j < 512) { wp = wq + j; stride = 512; col = j; }
    else if (j < 1024) { wp = wk + (j - 512); stride = 512; col = j - 512; }
    else { wp = wv + (j - 1024); stride = 1024; col = j - 1024; }
    for (int c = 0; c < 64; ++c) {
      float w = wp[(size_t)c * stride];
      const float4* xc = (const float4*)&xs[c][0];
      float4 x0 = xc[0], x1 = xc[1];
      acc[0] += x0.x * w; acc[1] += x0.y * w;
      acc[2] += x0.z * w; acc[3] += x0.w * w;
      acc[4] += x1.x * w; acc[5] += x1.y * w;
      acc[6] += x1.z * w; acc[7] += x1.w * w;
    }
    if (j < 512) {
#pragma unroll
      for (int i = 0; i < TT; ++i)
        qb[((size_t)(b * 8 + (col >> 6)) * Ll + l0 + i) * 64 + (col & 63)] =
            (ushort_t)f2bf(acc[i] * 0.125f);
    } else if (j < 1024) {
#pragma unroll
      for (int i = 0; i < TT; ++i)
        kb[((size_t)(b * 8 + (col >> 6)) * Ll + l0 + i) * 64 + (col & 63)] =
            (ushort_t)f2bf(acc[i]);
    } else {
#pragma unroll
      for (int i = 0; i < TT; ++i)
        v[((size_t)(b * 8 + (col >> 7)) * Ll + l0 + i) * 128 + (col & 127)] = acc[i];
    }
  }
}

// ============ 1b. transpose V -> vt bf16 (bh, dv, L) ============
__global__ __launch_bounds__(256) void k_vt(float* __restrict__ ws) {
  int bh = blockIdx.y;
  int l0 = blockIdx.x * 64;
  int t = threadIdx.x;
  __shared__ float tile[128][65];
  const float* vp = ws + OV + ((size_t)bh * Ll + l0) * 128;
  for (int i = t; i < 64 * 32; i += 256) {
    int l = i >> 5, dv4 = (i & 31) * 4;
    float4 a = *(const float4*)(vp + (size_t)l * 128 + dv4);
    tile[dv4][l] = a.x; tile[dv4 + 1][l] = a.y;
    tile[dv4 + 2][l] = a.z; tile[dv4 + 3][l] = a.w;
  }
  __syncthreads();
  ushort_t* vt = (ushort_t*)(ws + OVT) + (size_t)bh * 128 * Ll + l0;
  for (int i = t; i < 128 * 16; i += 256) {
    int dv = i >> 4, l4 = (i & 15) * 4;
    short4v a;
    a[0] = f2bf(tile[dv][l4]); a[1] = f2bf(tile[dv][l4 + 1]);
    a[2] = f2bf(tile[dv][l4 + 2]); a[3] = f2bf(tile[dv][l4 + 3]);
    *(short4v*)(vt + (size_t)dv * Ll + l4) = a;
  }
}

// ============ 2. flash attention (bf16 MFMA, ping-pong LDS, 1 barrier/iter) ============
#define NKT 36
#define LSK 72
__global__ __launch_bounds__(256) void k_attn(const float* __restrict__ snr,
                                              float* __restrict__ ws) {
  int bh = blockIdx.y; int b = bh >> 3; int hd = bh & 7;
  int q0 = blockIdx.x * 64;
  int t = threadIdx.x;
  int w = t >> 6, lane = t & 63;
  int m16 = lane & 15, quad = lane >> 4;

  __shared__ __align__(16) ushort_t Ks[2][64 * LSK];
  __shared__ __align__(16) ushort_t Vs[2][128 * LSK];
  __shared__ __align__(16) ushort_t Ps[4 * 16 * LSK];
  __shared__ float sfac_s[2][64];
  __shared__ float lsc[4][16];

  const ushort_t* qbf = (const ushort_t*)(ws + OQ) + (size_t)bh * Ll * 64;
  const ushort_t* kbf = (const ushort_t*)(ws + OK_) + (size_t)bh * Ll * 64;
  const ushort_t* vtb = (const ushort_t*)(ws + OVT) + (size_t)bh * 128 * Ll;

  short8v qa[2];
  {
    const ushort_t* qrp = qbf + (size_t)(q0 + w * 16 + m16) * 64 + quad * 8;
    qa[0] = *(const short8v*)qrp;
    qa[1] = *(const short8v*)(qrp + 32);
  }
  int sk_key = t >> 2, sk_d0 = (t & 3) * 16;
  int sv_dv = t >> 1, sv_k0 = (t & 1) * 32;

  short8v kreg[2], vreg[4];
  float snr_reg = 0.f;
  {
    const ushort_t* ksrc = kbf + (size_t)sk_key * 64 + sk_d0;
    kreg[0] = *(const short8v*)ksrc;
    kreg[1] = *(const short8v*)(ksrc + 8);
    const ushort_t* vsrc = vtb + (size_t)sv_dv * Ll + sv_k0;
#pragma unroll
    for (int i = 0; i < 4; ++i) vreg[i] = *(const short8v*)(vsrc + i * 8);
    if (t < 64) snr_reg = snr[b * Ll + t];
  }

  f32x4 oacc[8];
#pragma unroll
  for (int i = 0; i < 8; ++i) oacc[i] = (f32x4)0.f;
  float l_r[4] = {0.f, 0.f, 0.f, 0.f};

  for (int kt = 0; kt < NKT; ++kt) {
    int buf = kt & 1;
    // write tile kt (held in regs) into ping-pong buffer; other waves may still
    // be computing tile kt-1 from the OTHER buffer -> no race.
    *(short8v*)&Ks[buf][sk_key * LSK + sk_d0] = kreg[0];
    *(short8v*)&Ks[buf][sk_key * LSK + sk_d0 + 8] = kreg[1];
#pragma unroll
    for (int i = 0; i < 4; ++i)
      *(short8v*)&Vs[buf][sv_dv * LSK + sv_k0 + i * 8] = vreg[i];
    if (t < 64) sfac_s[buf][t] = snr_reg + 1e-4f;
    __syncthreads();
    if (kt + 1 < NKT) {
      int k0n = (kt + 1) * 64;
      const ushort_t* ksrc = kbf + (size_t)(k0n + sk_key) * 64 + sk_d0;
      kreg[0] = *(const short8v*)ksrc;
      kreg[1] = *(const short8v*)(ksrc + 8);
      const ushort_t* vsrc = vtb + (size_t)sv_dv * Ll + k0n + sv_k0;
#pragma unroll
      for (int i = 0; i < 4; ++i) vreg[i] = *(const short8v*)(vsrc + i * 8);
      if (t < 64) snr_reg = snr[b * Ll + k0n + t];
    }

    f32x4 sac[4];
#pragma unroll
    for (int n = 0; n < 4; ++n) {
      int key = n * 16 + m16;
      short8v kb0 = *(const short8v*)&Ks[buf][key * LSK + quad * 8];
      short8v kb1 = *(const short8v*)&Ks[buf][key * LSK + 32 + quad * 8];
      f32x4 acc = (f32x4)0.f;
      acc = __builtin_amdgcn_mfma_f32_16x16x32_bf16(qa[0], kb0, acc, 0, 0, 0);
      acc = __builtin_amdgcn_mfma_f32_16x16x32_bf16(qa[1], kb1, acc, 0, 0, 0);
      sac[n] = acc;
    }
    float sf[4];
#pragma unroll
    for (int n = 0; n < 4; ++n) sf[n] = sfac_s[buf][n * 16 + m16];
    ushort_t* pw = &Ps[w * 16 * LSK];
#pragma unroll
    for (int r = 0; r < 4; ++r) {
#pragma unroll
      for (int n = 0; n < 4; ++n) {
        float p = __expf(sac[n][r]) * sf[n];
        l_r[r] += p;
        pw[(quad * 4 + r) * LSK + n * 16 + m16] = (ushort_t)f2bf(p);
      }
    }
    short8v pb0 = *(const short8v*)&pw[m16 * LSK + quad * 8];
    short8v pb1 = *(const short8v*)&pw[m16 * LSK + 32 + quad * 8];
#pragma unroll
    for (int dt_ = 0; dt_ < 8; ++dt_) {
      const ushort_t* vrow = &Vs[buf][(dt_ * 16 + m16) * LSK];
      short8v va0 = *(const short8v*)&vrow[quad * 8];
      short8v va1 = *(const short8v*)&vrow[32 + quad * 8];
      f32x4 o = oacc[dt_];
      o = __builtin_amdgcn_mfma_f32_16x16x32_bf16(va0, pb0, o, 0, 0, 0);
      o = __builtin_amdgcn_mfma_f32_16x16x32_bf16(va1, pb1, o, 0, 0, 0);
      oacc[dt_] = o;
    }
  }
#pragma unroll
  for (int r = 0; r < 4; ++r) {
    float lv = l_r[r];
    lv += __shfl_xor(lv, 1, 64);
    lv += __shfl_xor(lv, 2, 64);
    lv += __shfl_xor(lv, 4, 64);
    lv += __shfl_xor(lv, 8, 64);
    l_r[r] = lv;
  }
  if (m16 == 0) {
#pragma unroll
    for (int r = 0; r < 4; ++r) lsc[w][quad * 4 + r] = l_r[r];
  }
  __builtin_amdgcn_s_waitcnt(0);  // lgkmcnt for lsc write (same wave ordering ok)
  float linv = 1.f / lsc[w][m16];
  float* op = ws + OO + ((size_t)(b * Ll + q0 + w * 16 + m16)) * 1024 + hd * 128;
#pragma unroll
  for (int dt_ = 0; dt_ < 8; ++dt_) {
#pragma unroll
    for (int r = 0; r < 4; ++r) {
      op[dt_ * 16 + quad * 4 + r] = oacc[dt_][r] * linv;
    }
  }
}

// ============ 3+4. o@fc + residual + LN + xz, 8 tokens/block ============
__global__ __launch_bounds__(256) void k_oprojxz(const float* __restrict__ enc,
    const float* __restrict__ fc, const float* __restrict__ lnw,
    const float* __restrict__ lnb, const float* __restrict__ ssin,
    float* __restrict__ ws) {
  int l0 = blockIdx.x * TT, b = blockIdx.y, t = threadIdx.x;
  __shared__ float orow[1024][9];
  __shared__ float part[4][TT][64];
  __shared__ float xh_s[64][9];
  const float* op = ws + OO + ((size_t)(b * Ll + l0)) * 1024;
#pragma unroll
  for (int k = 0; k < 4; ++k) {
    int c = t + k * 256;
#pragma unroll
    for (int i = 0; i < TT; ++i) orow[c][i] = op[(size_t)i * 1024 + c];
  }
  __syncthreads();
  int col = t & 63, seg = t >> 6;
  {
    float acc[TT];
#pragma unroll
    for (int i = 0; i < TT; ++i) acc[i] = 0.f;
    const float* fcs = fc + (size_t)(seg * 256) * 64 + col;
    for (int c = 0; c < 256; ++c) {
      float w = fcs[(size_t)c * 64];
      const float* orc = &orow[seg * 256 + c][0];
#pragma unroll
      for (int i = 0; i < TT; ++i) acc[i] += orc[i] * w;
    }
#pragma unroll
    for (int i = 0; i < TT; ++i) part[seg][i][col] = acc[i];
  }
  __syncthreads();
  if (t < 64) {
    float lw = lnw[t], lb = lnb[t];
#pragma unroll
    for (int i = 0; i < TT; ++i) {
      float a = part[0][i][t] + part[1][i][t] + part[2][i][t] + part[3][i][t];
      a += enc[(size_t)b * Cc * Ll + (size_t)t * Ll + l0 + i];
      float s = a;
#pragma unroll
      for (int o = 32; o >= 1; o >>= 1) s += __shfl_xor(s, o, 64);
      float m = s * (1.f / 64.f);
      float dd = a - m;
      float vs = dd * dd;
#pragma unroll
      for (int o = 32; o >= 1; o >>= 1) vs += __shfl_xor(vs, o, 64);
      xh_s[t][i] = dd * rsqrtf(vs * (1.f / 64.f) + 1e-5f) * lw + lb;
    }
  }
  __syncthreads();
  {
    float acc2[TT];
#pragma unroll
    for (int i = 0; i < TT; ++i) acc2[i] = 0.f;
    for (int c = 0; c < 64; ++c) {
      float w = ssin[c * 256 + t];
      const float* xc = &xh_s[c][0];
#pragma unroll
      for (int i = 0; i < TT; ++i) acc2[i] += xc[i] * w;
    }
    if (t < 128) {
#pragma unroll
      for (int i = 0; i < TT; ++i)
        ws[OX1P + ((size_t)(b * Ll + l0 + i)) * 128 + t] = acc2[i];
    } else {
#pragma unroll
      for (int i = 0; i < TT; ++i)
        ws[OZ + ((size_t)(b * Ll + l0 + i)) * 128 + (t - 128)] = acc2[i];
    }
  }
}

// ============ 5. depthwise conv3x3 + bias + silu, 8 tokens/block ============
__global__ __launch_bounds__(256) void k_conv(const float* __restrict__ cw,
    const float* __restrict__ cb, float* __restrict__ ws) {
  int l0 = blockIdx.x * TT, b = blockIdx.y, t = threadIdx.x;
  int h = l0 / 48, w0 = l0 % 48;
  __shared__ float tile[3][10][128];
  for (int idx = t; idx < 3840; idx += 256) {
    int r = idx / 1280, rem = idx % 1280;
    int col = rem >> 7, d = rem & 127;
    int hh = h + r - 1, wx = w0 + col - 1;
    float v = 0.f;
    if (hh >= 0 && hh < 48 && wx >= 0 && wx < 48)
      v = ws[OX1P + ((size_t)(b * Ll + hh * 48 + wx)) * 128 + d];
    tile[r][col][d] = v;
  }
  __syncthreads();
  int d = t & 127, half = t >> 7;
  float cwr[9];
#pragma unroll
  for (int j = 0; j < 9; ++j) cwr[j] = cw[d * 9 + j];
  float cbv = cb[d];
#pragma unroll
  for (int j = 0; j < 4; ++j) {
    int i = half * 4 + j;
    float acc = cbv;
#pragma unroll
    for (int kh = 0; kh < 3; ++kh)
#pragma unroll
      for (int kw = 0; kw < 3; ++kw)
        acc += tile[kh][i + kw][d] * cwr[kh * 3 + kw];
    ws[OX1S + ((size_t)(b * Ll + l0 + i)) * 128 + d] = siluf(acc);
  }
}

// ============ 6. x_dbl projections, 8 tokens/block ============
__global__ __launch_bounds__(128) void k_xdbl(const float* __restrict__ xw,
    const float* __restrict__ dtw, const float* __restrict__ dtb,
    float* __restrict__ ws) {
  int l0 = blockIdx.x * TT;
  int by = blockIdx.y; int b = by >> 2; int k = by & 3;
  int t = threadIdx.x;
  __shared__ float xv[128][9];
  __shared__ float pr[36][TT];
#pragma unroll
  for (int i = 0; i < TT; ++i) {
    int sp = spmap(k, l0 + i);
    xv[t][i] = ws[OX1S + ((size_t)(b * Ll) + sp) * 128 + t];
  }
  __syncthreads();
  if (t < 36) {
    float s[TT];
#pragma unroll
    for (int i = 0; i < TT; ++i) s[i] = 0.f;
    const float* wp = xw + (size_t)(k * 36 + t) * 128;
    for (int d = 0; d < 128; ++d) {
      float w = wp[d];
      const float* xc = &xv[d][0];
#pragma unroll
      for (int i = 0; i < TT; ++i) s[i] += xc[i] * w;
    }
#pragma unroll
    for (int i = 0; i < TT; ++i) pr[t][i] = s[i];
  }
  __syncthreads();
  {
    int d = t;
    const float* wp = dtw + (size_t)(k * 128 + d) * 4;
    float w0 = wp[0], w1 = wp[1], w2 = wp[2], w3 = wp[3];
    float bb = dtb[k * 128 + d];
#pragma unroll
    for (int i = 0; i < TT; ++i) {
      float v = pr[0][i] * w0 + pr[1][i] * w1 + pr[2][i] * w2 + pr[3][i] * w3 + bb;
      ws[ODT2 + ((size_t)(by * Ll + l0 + i)) * 128 + d] = softplusf(v);
    }
  }
  if (t < 16) {
#pragma unroll
    for (int i = 0; i < TT; ++i)
      ws[OBS2 + ((size_t)(by * Ll + l0 + i)) * 16 + t] = pr[4 + t][i];
  } else if (t < 32) {
#pragma unroll
    for (int i = 0; i < TT; ++i)
      ws[OCS2 + ((size_t)(by * Ll + l0 + i)) * 16 + (t - 16)] = pr[20 + (t - 16)][i];
  }
}

// ============ 7a. scan phase A (ping-pong, 1 barrier/step) ============
__global__ __launch_bounds__(256) void k_scanA(const float* __restrict__ alog,
                                               float* __restrict__ ws) {
  int c = blockIdx.x;
  int bk = blockIdx.y;
  int b = bk >> 2, k = bk & 3;
  int t = threadIdx.x;
  int n = t & 15, dg = t >> 4;
  __shared__ float dt_s[2][128], x_s[2][128], Bs_s[2][16];
  float A_r[8], ap[8], bc[8];
#pragma unroll
  for (int i = 0; i < 8; ++i) {
    int d = dg * 8 + i;
    A_r[i] = -__expf(alog[(size_t)((k * 128 + d) * 16) + n]);
    ap[i] = 1.f; bc[i] = 0.f;
  }
  const float* dtp = ws + ODT2 + ((size_t)bk * Ll) * 128;
  const float* bsp = ws + OBS2 + ((size_t)bk * Ll) * 16;
  const float* xb = ws + OX1S + (size_t)b * Ll * 128;
  float r_a = 0.f, r_Bs = 0.f;
  {
    int l = c * SCH;
    int sp = spmap(k, l);
    if (t < 128) r_a = dtp[(size_t)l * 128 + t];
    else r_a = xb[(size_t)sp * 128 + (t - 128)];
    if (t < 16) r_Bs = bsp[(size_t)l * 16 + t];
  }
  for (int ll = 0; ll < SCH; ++ll) {
    int buf = ll & 1;
    if (t < 128) dt_s[buf][t] = r_a;
    else x_s[buf][t - 128] = r_a;
    if (t < 16) Bs_s[buf][t] = r_Bs;
    __syncthreads();
    if (ll + 1 < SCH) {
      int l2 = c * SCH + ll + 1;
      int sp2 = spmap(k, l2);
      if (t < 128) r_a = dtp[(size_t)l2 * 128 + t];
      else r_a = xb[(size_t)sp2 * 128 + (t - 128)];
      if (t < 16) r_Bs = bsp[(size_t)l2 * 16 + t];
    }
    float Bv = Bs_s[buf][n];
#pragma unroll
    for (int i = 0; i < 8; ++i) {
      int d = dg * 8 + i;
      float dtv = dt_s[buf][d];
      float a = __expf(dtv * A_r[i]);
      bc[i] = bc[i] * a + dtv * x_s[buf][d] * Bv;
      ap[i] *= a;
    }
  }
  float* csa = ws + OCSA + ((size_t)(bk * SNC + c) * 128) * 16;
  float* csb = ws + OCSB + ((size_t)(bk * SNC + c) * 128) * 16;
#pragma unroll
  for (int i = 0; i < 8; ++i) {
    int d = dg * 8 + i;
    csa[d * 16 + n] = ap[i];
    csb[d * 16 + n] = bc[i];
  }
}

// ============ 7b. scan phase B (register prefetch) ============
__global__ __launch_bounds__(256) void k_scanB(float* __restrict__ ws) {
  int g = blockIdx.x * 256 + threadIdx.x;
  int bk = g >> 11;
  int dn = g & 2047;
  const float* csa = ws + OCSA;
  const float* csb = ws + OCSB;
  float* hst = ws + OHST;
  size_t base = (size_t)bk * SNC * 2048 + dn;
  float h = 0.f;
  float a = csa[base], bq = csb[base];
  for (int c = 0; c < SNC; ++c) {
    float na = 0.f, nb = 0.f;
    if (c + 1 < SNC) {
      size_t idx2 = base + (size_t)(c + 1) * 2048;
      na = csa[idx2]; nb = csb[idx2];
    }
    hst[base + (size_t)c * 2048] = h;
    h = a * h + bq;
    a = na; bq = nb;
  }
}

// ============ 7c. scan phase C (ping-pong, 1 barrier/step) ============
__global__ __launch_bounds__(256) void k_scanC(const float* __restrict__ alog,
    const float* __restrict__ Dp, float* __restrict__ ws) {
  int c = blockIdx.x, bk = blockIdx.y;
  int b = bk >> 2, k = bk & 3;
  int t = threadIdx.x;
  int n = t & 15, dg = t >> 4;
  __shared__ float dt_s[2][128], x_s[2][128], Bs_s[2][16], Cs_s[2][16];
  float A_r[8], h[8], Dv[8];
#pragma unroll
  for (int i = 0; i < 8; ++i) {
    int d = dg * 8 + i;
    A_r[i] = -__expf(alog[(size_t)((k * 128 + d) * 16) + n]);
    h[i] = ws[OHST + ((size_t)(bk * SNC + c) * 128 + d) * 16 + n];
    Dv[i] = Dp[k * 128 + d];
  }
  const float* dtp = ws + ODT2 + ((size_t)bk * Ll) * 128;
  const float* bsp = ws + OBS2 + ((size_t)bk * Ll) * 16;
  const float* csp = ws + OCS2 + ((size_t)bk * Ll) * 16;
  const float* xb = ws + OX1S + (size_t)b * Ll * 128;
  float* yp = ws + OYS2 + ((size_t)bk * Ll) * 128;
  float r_a = 0.f, r_bc = 0.f;
  {
    int l = c * SCH;
    int sp = spmap(k, l);
    if (t < 128) r_a = dtp[(size_t)l * 128 + t];
    else r_a = xb[(size_t)sp * 128 + (t - 128)];
    if (t < 16) r_bc = bsp[(size_t)l * 16 + t];
    else if (t < 32) r_bc = csp[(size_t)l * 16 + (t - 16)];
  }
  for (int ll = 0; ll < SCH; ++ll) {
    int buf = ll & 1;
    if (t < 128) dt_s[buf][t] = r_a;
    else x_s[buf][t - 128] = r_a;
    if (t < 16) Bs_s[buf][t] = r_bc;
    else if (t < 32) Cs_s[buf][t - 16] = r_bc;
    __syncthreads();
    if (ll + 1 < SCH) {
      int l2 = c * SCH + ll + 1;
      int sp2 = spmap(k, l2);
      if (t < 128) r_a = dtp[(size_t)l2 * 128 + t];
      else r_a = xb[(size_t)sp2 * 128 + (t - 128)];
      if (t < 16) r_bc = bsp[(size_t)l2 * 16 + t];
      else if (t < 32) r_bc = csp[(size_t)l2 * 16 + (t - 16)];
    }
    int l = c * SCH + ll;
    float Bv = Bs_s[buf][n], Cv = Cs_s[buf][n];
    float yacc[8];
#pragma unroll
    for (int i = 0; i < 8; ++i) {
      int d = dg * 8 + i;
      float dtv = dt_s[buf][d];
      float a = __expf(dtv * A_r[i]);
      h[i] = h[i] * a + dtv * x_s[buf][d] * Bv;
      yacc[i] = h[i] * Cv;
    }
#pragma unroll
    for (int i = 0; i < 8; ++i) {
      float yv = yacc[i];
      yv += __shfl_xor(yv, 1, 64);
      yv += __shfl_xor(yv, 2, 64);
      yv += __shfl_xor(yv, 4, 64);
      yv += __shfl_xor(yv, 8, 64);
      yacc[i] = yv;
    }
    if (n == 0) {
#pragma unroll
      for (int i = 0; i < 8; ++i) {
        int d = dg * 8 + i;
        yp[(size_t)l * 128 + d] = yacc[i] + Dv[i] * x_s[buf][d];
      }
    }
  }
}

// ============ 8+9+10. comb + LN + gate + x2 + LN + FFN conv1 (fused, 8 tok) ============
__global__ __launch_bounds__(256) void k_combffn1(const float* __restrict__ enc,
    const float* __restrict__ nw, const float* __restrict__ nb,
    const float* __restrict__ snr, const float* __restrict__ ow,
    const float* __restrict__ lw, const float* __restrict__ lb,
    const float* __restrict__ w1, float* __restrict__ ws) {
  int l0 = blockIdx.x * TT, b = blockIdx.y, t = threadIdx.x;
  __shared__ float yr[128][9];
  __shared__ float redm[2][TT], redq[2][TT];
  __shared__ float part[2][TT][64];
  __shared__ float xn_s[64][9];
  int lane = t & 63, wid = (t >> 6) & 1;
  float v[TT], m[TT];
  if (t < 128) {
    int d = t;
    const float* ysb = ws + OYS2;
#pragma unroll
    for (int i = 0; i < TT; ++i) {
      int l = l0 + i;
      int hh = l / 48, wwp = l % 48;
      int lT = wwp * 48 + hh;
      v[i] = ysb[((size_t)(b * 4 + 0) * Ll + l) * 128 + d] +
             ysb[((size_t)(b * 4 + 2) * Ll + (2303 - l)) * 128 + d] +
             ysb[((size_t)(b * 4 + 1) * Ll + lT) * 128 + d] +
             ysb[((size_t)(b * 4 + 3) * Ll + (2303 - lT)) * 128 + d];
    }
    float s[TT];
#pragma unroll
    for (int i = 0; i < TT; ++i) s[i] = v[i];
#pragma unroll
    for (int o = 32; o >= 1; o >>= 1)
#pragma unroll
      for (int i = 0; i < TT; ++i) s[i] += __shfl_xor(s[i], o, 64);
    if (lane == 0) {
#pragma unroll
      for (int i = 0; i < TT; ++i) redm[wid][i] = s[i];
    }
  }
  __syncthreads();
  if (t < 128) {
    float q[TT];
#pragma unroll
    for (int i = 0; i < TT; ++i) {
      m[i] = (redm[0][i] + redm[1][i]) * (1.f / 128.f);
      float dv = v[i] - m[i];
      q[i] = dv * dv;
    }
#pragma unroll
    for (int o = 32; o >= 1; o >>= 1)
#pragma unroll
      for (int i = 0; i < TT; ++i) q[i] += __shfl_xor(q[i], o, 64);
    if (lane == 0) {
#pragma unroll
      for (int i = 0; i < TT; ++i) redq[wid][i] = q[i];
    }
  }
  __syncthreads();
  if (t < 128) {
    int d = t;
    float nwv = nw[d], nbv = nb[d];
#pragma unroll
    for (int i = 0; i < TT; ++i) {
      int l = l0 + i;
      float var = (redq[0][i] + redq[1][i]) * (1.f / 128.f);
      float y = (v[i] - m[i]) * rsqrtf(var + 1e-5f) * nwv + nbv;
      float zv = ws[OZ + ((size_t)(b * Ll + l)) * 128 + d];
      y *= siluf(zv);
      y *= snr[b * Ll + l];
      yr[d][i] = y;
    }
  }
  __syncthreads();
  if (t < 128) {
    int col = t & 63, seg = t >> 6;
    float acc[TT];
#pragma unroll
    for (int i = 0; i < TT; ++i) acc[i] = 0.f;
    const float* ows = ow + (size_t)(seg * 64) * 64 + col;
    for (int c = 0; c < 64; ++c) {
      float w = ows[c * 64];
      const float* yc = &yr[seg * 64 + c][0];
#pragma unroll
      for (int i = 0; i < TT; ++i) acc[i] += yc[i] * w;
    }
#pragma unroll
    for (int i = 0; i < TT; ++i) part[seg][i][col] = acc[i];
  }
  __syncthreads();
  if (t < 64) {
    float lwv = lw[t], lbv = lb[t];
#pragma unroll
    for (int i = 0; i < TT; ++i) {
      float a = part[0][i][t] + part[1][i][t];
      a += enc[(size_t)b * Cc * Ll + (size_t)t * Ll + l0 + i];
      ws[OX2 + ((size_t)(b * Ll + l0 + i)) * 64 + t] = a;
      float s = a;
#pragma unroll
      for (int o = 32; o >= 1; o >>= 1) s += __shfl_xor(s, o, 64);
      float mm = s * (1.f / 64.f);
      float dd2 = a - mm;
      float vs = dd2 * dd2;
#pragma unroll
      for (int o = 32; o >= 1; o >>= 1) vs += __shfl_xor(vs, o, 64);
      xn_s[t][i] = dd2 * rsqrtf(vs * (1.f / 64.f) + 1e-5f) * lwv + lbv;
    }
  }
  __syncthreads();
  {
    float acc2[TT];
#pragma unroll
    for (int i = 0; i < TT; ++i) acc2[i] = 0.f;
    const float* wp = w1 + (size_t)t * 64;
    for (int c = 0; c < 64; ++c) {
      float w = wp[c];
      const float* xc = &xn_s[c][0];
#pragma unroll
      for (int i = 0; i < TT; ++i) acc2[i] += xc[i] * w;
    }
#pragma unroll
    for (int i = 0; i < TT; ++i)
      ws[OH1A + ((size_t)(b * Ll + l0 + i)) * 256 + t] = geluf(acc2[i]);
  }
}

// ============ 11. FFN depthwise 3x3 + gelu, 8 tokens/block ============
__global__ __launch_bounds__(256) void k_ffndw(const float* __restrict__ dww,
                                               float* __restrict__ ws) {
  int l0 = blockIdx.x * TT, b = blockIdx.y, t = threadIdx.x;
  int h = l0 / 48, w0 = l0 % 48;
  __shared__ float tile[3][10][256];
  for (int idx = t; idx < 7680; idx += 256) {
    int r = idx / 2560, rem = idx % 2560;
    int col = rem >> 8, ch = rem & 255;
    int hh = h + r - 1, wx = w0 + col - 1;
    float v = 0.f;
    if (hh >= 0 && hh < 48 && wx >= 0 && wx < 48)
      v = ws[OH1A + ((size_t)(b * Ll + hh * 48 + wx)) * 256 + ch];
    tile[r][col][ch] = v;
  }
  __syncthreads();
  float dwr[9];
#pragma unroll
  for (int j = 0; j < 9; ++j) dwr[j] = dww[t * 9 + j];
#pragma unroll
  for (int i = 0; i < TT; ++i) {
    float acc = 0.f;
#pragma unroll
    for (int kh = 0; kh < 3; ++kh)
#pragma unroll
      for (int kw = 0; kw < 3; ++kw)
        acc += tile[kh][i + kw][t] * dwr[kh * 3 + kw];
    ws[OH1B + ((size_t)(b * Ll + l0 + i)) * 256 + t] = geluf(acc);
  }
}

// ============ 12. FFN conv2 1x1 + residual + transposed out, 8 tokens/block ============
__global__ __launch_bounds__(256) void k_ffn2(const float* __restrict__ w2,
                                              float* __restrict__ ws,
                                              float* __restrict__ out) {
  int l0 = blockIdx.x * TT, b = blockIdx.y, t = threadIdx.x;
  __shared__ float hr[256][9];
  __shared__ float part[4][TT][64];
  const float* hp = ws + OH1B + ((size_t)(b * Ll + l0)) * 256;
#pragma unroll
  for (int i = 0; i < TT; ++i) hr[t][i] = hp[(size_t)i * 256 + t];
  __syncthreads();
  int col = t & 63, seg = t >> 6;
  {
    float acc[TT];
#pragma unroll
    for (int i = 0; i < TT; ++i) acc[i] = 0.f;
    const float* wp = w2 + (size_t)col * 256 + seg * 64;
    for (int c = 0; c < 64; ++c) {
      float w = wp[c];
      const float* hc = &hr[seg * 64 + c][0];
#pragma unroll
      for (int i = 0; i < TT; ++i) acc[i] += hc[i] * w;
    }
#pragma unroll
    for (int i = 0; i < TT; ++i) part[seg][i][col] = acc[i];
  }
  __syncthreads();
  if (t < 64) {
    float av[TT];
#pragma unroll
    for (int i = 0; i < TT; ++i) {
      float a = part[0][i][t] + part[1][i][t] + part[2][i][t] + part[3][i][t];
      av[i] = a + ws[OX2 + ((size_t)(b * Ll + l0 + i)) * 64 + t];
    }
    float* opx = out + ((size_t)(b * 64 + t)) * 2304 + l0;
    *(float4*)opx = make_float4(av[0], av[1], av[2], av[3]);
    *((float4*)opx + 1) = make_float4(av[4], av[5], av[6], av[7]);
  }
}

extern "C" void kernel_launch(void* const* d_in, const int* in_sizes, int n_in,
                              void* d_out, int out_size, void* d_ws, size_t ws_size,
                              hipStream_t stream) {
  (void)in_sizes; (void)n_in; (void)out_size;
  const float* enc  = (const float*)d_in[0];
  const float* snr  = (const float*)d_in[1];
  const float* wq   = (const float*)d_in[2];
  const float* wk   = (const float*)d_in[3];
  const float* wv   = (const float*)d_in[4];
  const float* fc   = (const float*)d_in[5];
  const float* alnw = (const float*)d_in[6];
  const float* alnb = (const float*)d_in[7];
  const float* ssin = (const float*)d_in[8];
  const float* cw   = (const float*)d_in[9];
  const float* cb   = (const float*)d_in[10];
  const float* xw   = (const float*)d_in[11];
  const float* dtw  = (const float*)d_in[12];
  const float* dtb  = (const float*)d_in[13];
  const float* alog = (const float*)d_in[14];
  const float* Dp   = (const float*)d_in[15];
  const float* nw   = (const float*)d_in[16];
  const float* nb   = (const float*)d_in[17];
  const float* ow   = (const float*)d_in[18];
  const float* flnw = (const float*)d_in[19];
  const float* flnb = (const float*)d_in[20];
  const float* w1   = (const float*)d_in[21];
  const float* dww  = (const float*)d_in[22];
  const float* w2   = (const float*)d_in[23];
  float* ws = (float*)d_ws;
  float* out = (float*)d_out;

  if (ws_size < (size_t)WS_NEED_FLOATS * 4) {
    hipLaunchKernelGGL(k_code, dim3(1), dim3(64), 0, stream, out);
    return;
  }

  hipLaunchKernelGGL(k_qkv, dim3(Ll / TT, Bq), dim3(256), 0, stream, enc, wq, wk, wv, ws);
  hipLaunchKernelGGL(k_vt, dim3(Ll / 64, Bq * NHh), dim3(256), 0, stream, ws);
  hipLaunchKernelGGL(k_attn, dim3(Ll / 64, Bq * NHh), dim3(256), 0, stream, snr, ws);
  hipLaunchKernelGGL(k_oprojxz, dim3(Ll / TT, Bq), dim3(256), 0, stream, enc, fc, alnw, alnb, ssin, ws);
  hipLaunchKernelGGL(k_conv, dim3(Ll / TT, Bq), dim3(256), 0, stream, cw, cb, ws);
  hipLaunchKernelGGL(k_xdbl, dim3(Ll / TT, Bq * 4), dim3(128), 0, stream, xw, dtw, dtb, ws);
  hipLaunchKernelGGL(k_scanA, dim3(SNC, Bq * 4), dim3(256), 0, stream, alog, ws);
  hipLaunchKernelGGL(k_scanB, dim3(64), dim3(256), 0, stream, ws);
  hipLaunchKernelGGL(k_scanC, dim3(SNC, Bq * 4), dim3(256), 0, stream, alog, Dp, ws);
  hipLaunchKernelGGL(k_combffn1, dim3(Ll / TT, Bq), dim3(256), 0, stream, enc, nw, nb, snr, ow, flnw, flnb, w1, ws);
  hipLaunchKernelGGL(k_ffndw, dim3(Ll / TT, Bq), dim3(256), 0, stream, dww, ws);
  hipLaunchKernelGGL(k_ffn2, dim3(Ll / TT, Bq), dim3(256), 0, stream, w2, ws, out);
}

// Round 15
// 433.685 us; speedup vs baseline: 1.0252x; 1.0252x over previous
//
#include <hip/hip_runtime.h>
#include <hip/hip_bf16.h>

#define Bq 2
#define Cc 64
#define Hh 48
#define Ww 48
#define Ll 2304
#define NHh 8
#define DKk 64
#define DVv 128
#define DNn 128
#define NSs 16
#define Rr 4
#define SCH 48
#define SNC 48
#define TT 8      // tokens per block in GEMM-ish kernels

// ---- workspace layout (float offsets) ----
#define OQ    0u                 // (B*8, L, 64) Q bf16 (ushort), pre-scaled by 1/8
#define OK_   2359296u           // (B*8, L, 64) K bf16 (ushort)
#define OV    4718592u           // (B*8, L, 128) V fp32 / attn partial-1 (B,L,1024)
#define OO    9437184u           // (B, L, 1024) attention out fp32 (partial-0 -> combined)
#define OLP   14450688u          // l-partials: 2 x (B*8, L)  (73728 floats)
#define OX2   15040512u
#define OVT   15630336u          // (B*8, 128, L) V^T bf16 (ushort)
#define WS_NEED_FLOATS (OVT + 4718592u)
// aliases (lifetimes: q,k,v,vt dead after k_ocomb; o dead after k_oprojxz)
#define ODT2  OQ                 // (B*4, L, 128) dt, l-major
#define OYS2  OK_                // (B*4, L, 128) scan y, l-major
#define OX1P  OV                 // (B,L,128)
#define OZ    (OV + 589824u)     // (B,L,128)
#define OX1S  (OV + 1179648u)    // (B,L,128)
#define OBS2  (OV + 1769472u)    // (B*4, L, 16)
#define OCS2  (OV + 2064384u)    // (B*4, L, 16)
#define OCSA  (OV + 2359296u)    // (B*4, SNC, 128, 16)
#define OCSB  (OV + 3145728u)    // (B*4, SNC, 128, 16)
#define OHST  (OV + 3932160u)    // (B*4, SNC, 128, 16)
#define OH1A  OO                 // (B,L,256)
#define OH1B  (OO + 1179648u)    // (B,L,256)

typedef short short8v __attribute__((ext_vector_type(8)));
typedef short short4v __attribute__((ext_vector_type(4)));
typedef float f32x4 __attribute__((ext_vector_type(4)));
typedef unsigned short ushort_t;

__device__ __forceinline__ float geluf(float x) {
  return 0.5f * x * (1.0f + erff(x * 0.70710678118654752f));
}
__device__ __forceinline__ float siluf(float x) {
  return x / (1.0f + __expf(-x));
}
__device__ __forceinline__ float softplusf(float x) {
  return fmaxf(x, 0.0f) + log1pf(__expf(-fabsf(x)));
}
__device__ __forceinline__ int spmap(int k, int l) {
  if (k == 0) return l;
  if (k == 1) return (l % 48) * 48 + l / 48;
  if (k == 2) return 2303 - l;
  int l2 = 2303 - l; return (l2 % 48) * 48 + l2 / 48;
}
__device__ __forceinline__ short f2bf(float f) {
  unsigned u = __float_as_uint(f);
  unsigned r = (u + 0x7FFFu + ((u >> 16) & 1u)) >> 16;
  return (short)r;
}

__global__ void k_code(float* out) { if (threadIdx.x == 0) out[0] = 25000.f; }

// ============ 1. QKV projection, 8 tokens/block (V fp32, coalesced) ============
__global__ __launch_bounds__(256) void k_qkv(const float* __restrict__ enc,
    const float* __restrict__ wq, const float* __restrict__ wk,
    const float* __restrict__ wv, float* __restrict__ ws) {
  int l0 = blockIdx.x * TT; int b = blockIdx.y;
  int t = threadIdx.x;
  __shared__ float xs[64][12];   // [c][token]
  {
    int idx = t, c = idx >> 3, i = idx & 7;
    xs[c][i] = enc[(size_t)b * Cc * Ll + (size_t)c * Ll + l0 + i];
    idx = t + 256; c = idx >> 3; i = idx & 7;
    xs[c][i] = enc[(size_t)b * Cc * Ll + (size_t)c * Ll + l0 + i];
  }
  __syncthreads();
  ushort_t* qb = (ushort_t*)(ws + OQ);
  ushort_t* kb = (ushort_t*)(ws + OK_);
  float* v = ws + OV;
#pragma unroll
  for (int g = 0; g < 6; ++g) {
    int j = t + g * 256;
    float acc[TT];
#pragma unroll
    for (int i = 0; i < TT; ++i) acc[i] = 0.f;
    const float* wp; int col, stride;
    if (j < 512) { wp = wq + j; stride = 512; col = j; }
    else if (j < 1024) { wp = wk + (j - 512); stride = 512; col = j - 512; }
    else { wp = wv + (j - 1024); stride = 1024; col = j - 1024; }
    for (int c = 0; c < 64; ++c) {
      float w = wp[(size_t)c * stride];
      const float4* xc = (const float4*)&xs[c][0];
      float4 x0 = xc[0], x1 = xc[1];
      acc[0] += x0.x * w; acc[1] += x0.y * w;
      acc[2] += x0.z * w; acc[3] += x0.w * w;
      acc[4] += x1.x * w; acc[5] += x1.y * w;
      acc[6] += x1.z * w; acc[7] += x1.w * w;
    }
    if (j < 512) {
#pragma unroll
      for (int i = 0; i < TT; ++i)
        qb[((size_t)(b * 8 + (col >> 6)) * Ll + l0 + i) * 64 + (col & 63)] =
            (ushort_t)f2bf(acc[i] * 0.125f);
    } else if (j < 1024) {
#pragma unroll
      for (int i = 0; i < TT; ++i)
        kb[((size_t)(b * 8 + (col >> 6)) * Ll + l0 + i) * 64 + (col & 63)] =
            (ushort_t)f2bf(acc[i]);
    } else {
#pragma unroll
      for (int i = 0; i < TT; ++i)
        v[((size_t)(b * 8 + (col >> 7)) * Ll + l0 + i) * 128 + (col & 127)] = acc[i];
    }
  }
}

// ============ 1b. transpose V -> vt bf16 (bh, dv, L) ============
__global__ __launch_bounds__(256) void k_vt(float* __restrict__ ws) {
  int bh = blockIdx.y;
  int l0 = blockIdx.x * 64;
  int t = threadIdx.x;
  __shared__ float tile[128][65];
  const float* vp = ws + OV + ((size_t)bh * Ll + l0) * 128;
  for (int i = t; i < 64 * 32; i += 256) {
    int l = i >> 5, dv4 = (i & 31) * 4;
    float4 a = *(const float4*)(vp + (size_t)l * 128 + dv4);
    tile[dv4][l] = a.x; tile[dv4 + 1][l] = a.y;
    tile[dv4 + 2][l] = a.z; tile[dv4 + 3][l] = a.w;
  }
  __syncthreads();
  ushort_t* vt = (ushort_t*)(ws + OVT) + (size_t)bh * 128 * Ll + l0;
  for (int i = t; i < 128 * 16; i += 256) {
    int dv = i >> 4, l4 = (i & 15) * 4;
    short4v a;
    a[0] = f2bf(tile[dv][l4]); a[1] = f2bf(tile[dv][l4 + 1]);
    a[2] = f2bf(tile[dv][l4 + 2]); a[3] = f2bf(tile[dv][l4 + 3]);
    *(short4v*)(vt + (size_t)dv * Ll + l4) = a;
  }
}

// ============ 2. flash attention (bf16 MFMA, fixed-max softmax, 2-way K-split) ============
#define NKT2 18   // (Ll/2)/64 iterations per split
#define LSK 72
__global__ __launch_bounds__(256) void k_attn(const float* __restrict__ snr,
                                              float* __restrict__ ws) {
  int bh = blockIdx.y; int b = bh >> 3; int hd = bh & 7;
  int q0 = blockIdx.x * 64;
  int ks = blockIdx.z;
  int kbase = ks * (Ll / 2);
  int t = threadIdx.x;
  int w = t >> 6, lane = t & 63;
  int m16 = lane & 15, quad = lane >> 4;

  __shared__ __align__(16) ushort_t Ks[64 * LSK];
  __shared__ __align__(16) ushort_t Vs[128 * LSK];
  __shared__ __align__(16) ushort_t Ps[4 * 16 * LSK];
  __shared__ float sfac_s[64];

  const ushort_t* qbf = (const ushort_t*)(ws + OQ) + (size_t)bh * Ll * 64;
  const ushort_t* kbf = (const ushort_t*)(ws + OK_) + (size_t)bh * Ll * 64;
  const ushort_t* vtb = (const ushort_t*)(ws + OVT) + (size_t)bh * 128 * Ll;

  short8v qa[2];
  {
    const ushort_t* qrp = qbf + (size_t)(q0 + w * 16 + m16) * 64 + quad * 8;
    qa[0] = *(const short8v*)qrp;
    qa[1] = *(const short8v*)(qrp + 32);
  }
  int sk_key = t >> 2, sk_d0 = (t & 3) * 16;
  int sv_dv = t >> 1, sv_k0 = (t & 1) * 32;

  short8v kreg[2], vreg[4];
  float snr_reg = 0.f;
  {
    const ushort_t* ksrc = kbf + (size_t)(kbase + sk_key) * 64 + sk_d0;
    kreg[0] = *(const short8v*)ksrc;
    kreg[1] = *(const short8v*)(ksrc + 8);
    const ushort_t* vsrc = vtb + (size_t)sv_dv * Ll + kbase + sv_k0;
#pragma unroll
    for (int i = 0; i < 4; ++i) vreg[i] = *(const short8v*)(vsrc + i * 8);
    if (t < 64) snr_reg = snr[b * Ll + kbase + t];
  }

  f32x4 oacc[8];
#pragma unroll
  for (int i = 0; i < 8; ++i) oacc[i] = (f32x4)0.f;
  float l_r[4] = {0.f, 0.f, 0.f, 0.f};

  for (int kt = 0; kt < NKT2; ++kt) {
    __syncthreads();
    *(short8v*)&Ks[sk_key * LSK + sk_d0] = kreg[0];
    *(short8v*)&Ks[sk_key * LSK + sk_d0 + 8] = kreg[1];
#pragma unroll
    for (int i = 0; i < 4; ++i)
      *(short8v*)&Vs[sv_dv * LSK + sv_k0 + i * 8] = vreg[i];
    if (t < 64) sfac_s[t] = snr_reg + 1e-4f;
    __syncthreads();
    if (kt + 1 < NKT2) {
      int k0n = kbase + (kt + 1) * 64;
      const ushort_t* ksrc = kbf + (size_t)(k0n + sk_key) * 64 + sk_d0;
      kreg[0] = *(const short8v*)ksrc;
      kreg[1] = *(const short8v*)(ksrc + 8);
      const ushort_t* vsrc = vtb + (size_t)sv_dv * Ll + k0n + sv_k0;
#pragma unroll
      for (int i = 0; i < 4; ++i) vreg[i] = *(const short8v*)(vsrc + i * 8);
      if (t < 64) snr_reg = snr[b * Ll + k0n + t];
    }

    f32x4 sac[4];
#pragma unroll
    for (int n = 0; n < 4; ++n) {
      int key = n * 16 + m16;
      short8v kb0 = *(const short8v*)&Ks[key * LSK + quad * 8];
      short8v kb1 = *(const short8v*)&Ks[key * LSK + 32 + quad * 8];
      f32x4 acc = (f32x4)0.f;
      acc = __builtin_amdgcn_mfma_f32_16x16x32_bf16(qa[0], kb0, acc, 0, 0, 0);
      acc = __builtin_amdgcn_mfma_f32_16x16x32_bf16(qa[1], kb1, acc, 0, 0, 0);
      sac[n] = acc;
    }
    float sf[4];
#pragma unroll
    for (int n = 0; n < 4; ++n) sf[n] = sfac_s[n * 16 + m16];
    ushort_t* pw = &Ps[w * 16 * LSK];
#pragma unroll
    for (int r = 0; r < 4; ++r) {
#pragma unroll
      for (int n = 0; n < 4; ++n) {
        float p = __expf(sac[n][r]) * sf[n];
        l_r[r] += p;
        pw[(quad * 4 + r) * LSK + n * 16 + m16] = (ushort_t)f2bf(p);
      }
    }
    short8v pb0 = *(const short8v*)&pw[m16 * LSK + quad * 8];
    short8v pb1 = *(const short8v*)&pw[m16 * LSK + 32 + quad * 8];
#pragma unroll
    for (int dt_ = 0; dt_ < 8; ++dt_) {
      const ushort_t* vrow = &Vs[(dt_ * 16 + m16) * LSK];
      short8v va0 = *(const short8v*)&vrow[quad * 8];
      short8v va1 = *(const short8v*)&vrow[32 + quad * 8];
      f32x4 o = oacc[dt_];
      o = __builtin_amdgcn_mfma_f32_16x16x32_bf16(va0, pb0, o, 0, 0, 0);
      o = __builtin_amdgcn_mfma_f32_16x16x32_bf16(va1, pb1, o, 0, 0, 0);
      oacc[dt_] = o;
    }
  }
  // partial l: reduce over 16 key-lanes, write per qrow
#pragma unroll
  for (int r = 0; r < 4; ++r) {
    float lv = l_r[r];
    lv += __shfl_xor(lv, 1, 64);
    lv += __shfl_xor(lv, 2, 64);
    lv += __shfl_xor(lv, 4, 64);
    lv += __shfl_xor(lv, 8, 64);
    l_r[r] = lv;
  }
  if (m16 == 0) {
    float* lp = ws + OLP + (size_t)ks * (Bq * NHh * Ll) + (size_t)bh * Ll;
#pragma unroll
    for (int r = 0; r < 4; ++r) lp[q0 + w * 16 + quad * 4 + r] = l_r[r];
  }
  // raw (unnormalized) partial O
  float* opb = ws + (ks ? OV : OO);
  float* op = opb + ((size_t)(b * Ll + q0 + w * 16 + m16)) * 1024 + hd * 128;
#pragma unroll
  for (int dt_ = 0; dt_ < 8; ++dt_) {
#pragma unroll
    for (int r = 0; r < 4; ++r) {
      op[dt_ * 16 + quad * 4 + r] = oacc[dt_][r];
    }
  }
}

// ============ 2b. combine partials: OO = (OO + OV) / (l0 + l1) ============
__global__ __launch_bounds__(256) void k_ocomb(float* __restrict__ ws) {
  size_t e4 = (size_t)blockIdx.x * 256 + threadIdx.x;  // float4 index, B*L*256 total
  int c4 = (int)(e4 & 255);
  size_t bl = e4 >> 8;
  int b = (int)(bl / Ll), l = (int)(bl % Ll);
  int hd = c4 >> 5;
  int bh = b * 8 + hd;
  float l1 = ws[OLP + (size_t)bh * Ll + l];
  float l2 = ws[OLP + (size_t)(Bq * NHh * Ll) + (size_t)bh * Ll + l];
  float linv = 1.f / (l1 + l2);
  float4* po = (float4*)(ws + OO) + e4;
  const float4* pv = (const float4*)(ws + OV) + e4;
  float4 a = *po, bq = *pv;
  a.x = (a.x + bq.x) * linv;
  a.y = (a.y + bq.y) * linv;
  a.z = (a.z + bq.z) * linv;
  a.w = (a.w + bq.w) * linv;
  *po = a;
}

// ============ 3+4. o@fc + residual + LN + xz, 8 tokens/block ============
__global__ __launch_bounds__(256) void k_oprojxz(const float* __restrict__ enc,
    const float* __restrict__ fc, const float* __restrict__ lnw,
    const float* __restrict__ lnb, const float* __restrict__ ssin,
    float* __restrict__ ws) {
  int l0 = blockIdx.x * TT, b = blockIdx.y, t = threadIdx.x;
  __shared__ float orow[1024][9];
  __shared__ float part[4][TT][64];
  __shared__ float xh_s[64][9];
  const float* op = ws + OO + ((size_t)(b * Ll + l0)) * 1024;
#pragma unroll
  for (int k = 0; k < 4; ++k) {
    int c = t + k * 256;
#pragma unroll
    for (int i = 0; i < TT; ++i) orow[c][i] = op[(size_t)i * 1024 + c];
  }
  __syncthreads();
  int col = t & 63, seg = t >> 6;
  {
    float acc[TT];
#pragma unroll
    for (int i = 0; i < TT; ++i) acc[i] = 0.f;
    const float* fcs = fc + (size_t)(seg * 256) * 64 + col;
    for (int c = 0; c < 256; ++c) {
      float w = fcs[(size_t)c * 64];
      const float* orc = &orow[seg * 256 + c][0];
#pragma unroll
      for (int i = 0; i < TT; ++i) acc[i] += orc[i] * w;
    }
#pragma unroll
    for (int i = 0; i < TT; ++i) part[seg][i][col] = acc[i];
  }
  __syncthreads();
  if (t < 64) {
    float lw = lnw[t], lb = lnb[t];
#pragma unroll
    for (int i = 0; i < TT; ++i) {
      float a = part[0][i][t] + part[1][i][t] + part[2][i][t] + part[3][i][t];
      a += enc[(size_t)b * Cc * Ll + (size_t)t * Ll + l0 + i];
      float s = a;
#pragma unroll
      for (int o = 32; o >= 1; o >>= 1) s += __shfl_xor(s, o, 64);
      float m = s * (1.f / 64.f);
      float dd = a - m;
      float vs = dd * dd;
#pragma unroll
      for (int o = 32; o >= 1; o >>= 1) vs += __shfl_xor(vs, o, 64);
      xh_s[t][i] = dd * rsqrtf(vs * (1.f / 64.f) + 1e-5f) * lw + lb;
    }
  }
  __syncthreads();
  {
    float acc2[TT];
#pragma unroll
    for (int i = 0; i < TT; ++i) acc2[i] = 0.f;
    for (int c = 0; c < 64; ++c) {
      float w = ssin[c * 256 + t];
      const float* xc = &xh_s[c][0];
#pragma unroll
      for (int i = 0; i < TT; ++i) acc2[i] += xc[i] * w;
    }
    if (t < 128) {
#pragma unroll
      for (int i = 0; i < TT; ++i)
        ws[OX1P + ((size_t)(b * Ll + l0 + i)) * 128 + t] = acc2[i];
    } else {
#pragma unroll
      for (int i = 0; i < TT; ++i)
        ws[OZ + ((size_t)(b * Ll + l0 + i)) * 128 + (t - 128)] = acc2[i];
    }
  }
}

// ============ 5. depthwise conv3x3 + bias + silu, 8 tokens/block ============
__global__ __launch_bounds__(256) void k_conv(const float* __restrict__ cw,
    const float* __restrict__ cb, float* __restrict__ ws) {
  int l0 = blockIdx.x * TT, b = blockIdx.y, t = threadIdx.x;
  int h = l0 / 48, w0 = l0 % 48;
  __shared__ float tile[3][10][128];
  for (int idx = t; idx < 3840; idx += 256) {
    int r = idx / 1280, rem = idx % 1280;
    int col = rem >> 7, d = rem & 127;
    int hh = h + r - 1, wx = w0 + col - 1;
    float v = 0.f;
    if (hh >= 0 && hh < 48 && wx >= 0 && wx < 48)
      v = ws[OX1P + ((size_t)(b * Ll + hh * 48 + wx)) * 128 + d];
    tile[r][col][d] = v;
  }
  __syncthreads();
  int d = t & 127, half = t >> 7;
  float cwr[9];
#pragma unroll
  for (int j = 0; j < 9; ++j) cwr[j] = cw[d * 9 + j];
  float cbv = cb[d];
#pragma unroll
  for (int j = 0; j < 4; ++j) {
    int i = half * 4 + j;
    float acc = cbv;
#pragma unroll
    for (int kh = 0; kh < 3; ++kh)
#pragma unroll
      for (int kw = 0; kw < 3; ++kw)
        acc += tile[kh][i + kw][d] * cwr[kh * 3 + kw];
    ws[OX1S + ((size_t)(b * Ll + l0 + i)) * 128 + d] = siluf(acc);
  }
}

// ============ 6. x_dbl projections, 8 tokens/block ============
__global__ __launch_bounds__(128) void k_xdbl(const float* __restrict__ xw,
    const float* __restrict__ dtw, const float* __restrict__ dtb,
    float* __restrict__ ws) {
  int l0 = blockIdx.x * TT;
  int by = blockIdx.y; int b = by >> 2; int k = by & 3;
  int t = threadIdx.x;
  __shared__ float xv[128][9];
  __shared__ float pr[36][TT];
#pragma unroll
  for (int i = 0; i < TT; ++i) {
    int sp = spmap(k, l0 + i);
    xv[t][i] = ws[OX1S + ((size_t)(b * Ll) + sp) * 128 + t];
  }
  __syncthreads();
  if (t < 36) {
    float s[TT];
#pragma unroll
    for (int i = 0; i < TT; ++i) s[i] = 0.f;
    const float* wp = xw + (size_t)(k * 36 + t) * 128;
    for (int d = 0; d < 128; ++d) {
      float w = wp[d];
      const float* xc = &xv[d][0];
#pragma unroll
      for (int i = 0; i < TT; ++i) s[i] += xc[i] * w;
    }
#pragma unroll
    for (int i = 0; i < TT; ++i) pr[t][i] = s[i];
  }
  __syncthreads();
  {
    int d = t;
    const float* wp = dtw + (size_t)(k * 128 + d) * 4;
    float w0 = wp[0], w1 = wp[1], w2 = wp[2], w3 = wp[3];
    float bb = dtb[k * 128 + d];
#pragma unroll
    for (int i = 0; i < TT; ++i) {
      float v = pr[0][i] * w0 + pr[1][i] * w1 + pr[2][i] * w2 + pr[3][i] * w3 + bb;
      ws[ODT2 + ((size_t)(by * Ll + l0 + i)) * 128 + d] = softplusf(v);
    }
  }
  if (t < 16) {
#pragma unroll
    for (int i = 0; i < TT; ++i)
      ws[OBS2 + ((size_t)(by * Ll + l0 + i)) * 16 + t] = pr[4 + t][i];
  } else if (t < 32) {
#pragma unroll
    for (int i = 0; i < TT; ++i)
      ws[OCS2 + ((size_t)(by * Ll + l0 + i)) * 16 + (t - 16)] = pr[20 + (t - 16)][i];
  }
}

// ============ 7a. scan phase A (ping-pong, 1 barrier/step) ============
__global__ __launch_bounds__(256) void k_scanA(const float* __restrict__ alog,
                                               float* __restrict__ ws) {
  int c = blockIdx.x;
  int bk = blockIdx.y;
  int b = bk >> 2, k = bk & 3;
  int t = threadIdx.x;
  int n = t & 15, dg = t >> 4;
  __shared__ float dt_s[2][128], x_s[2][128], Bs_s[2][16];
  float A_r[8], ap[8], bc[8];
#pragma unroll
  for (int i = 0; i < 8; ++i) {
    int d = dg * 8 + i;
    A_r[i] = -__expf(alog[(size_t)((k * 128 + d) * 16) + n]);
    ap[i] = 1.f; bc[i] = 0.f;
  }
  const float* dtp = ws + ODT2 + ((size_t)bk * Ll) * 128;
  const float* bsp = ws + OBS2 + ((size_t)bk * Ll) * 16;
  const float* xb = ws + OX1S + (size_t)b * Ll * 128;
  float r_a = 0.f, r_Bs = 0.f;
  {
    int l = c * SCH;
    int sp = spmap(k, l);
    if (t < 128) r_a = dtp[(size_t)l * 128 + t];
    else r_a = xb[(size_t)sp * 128 + (t - 128)];
    if (t < 16) r_Bs = bsp[(size_t)l * 16 + t];
  }
  for (int ll = 0; ll < SCH; ++ll) {
    int buf = ll & 1;
    if (t < 128) dt_s[buf][t] = r_a;
    else x_s[buf][t - 128] = r_a;
    if (t < 16) Bs_s[buf][t] = r_Bs;
    __syncthreads();
    if (ll + 1 < SCH) {
      int l2 = c * SCH + ll + 1;
      int sp2 = spmap(k, l2);
      if (t < 128) r_a = dtp[(size_t)l2 * 128 + t];
      else r_a = xb[(size_t)sp2 * 128 + (t - 128)];
      if (t < 16) r_Bs = bsp[(size_t)l2 * 16 + t];
    }
    float Bv = Bs_s[buf][n];
#pragma unroll
    for (int i = 0; i < 8; ++i) {
      int d = dg * 8 + i;
      float dtv = dt_s[buf][d];
      float a = __expf(dtv * A_r[i]);
      bc[i] = bc[i] * a + dtv * x_s[buf][d] * Bv;
      ap[i] *= a;
    }
  }
  float* csa = ws + OCSA + ((size_t)(bk * SNC + c) * 128) * 16;
  float* csb = ws + OCSB + ((size_t)(bk * SNC + c) * 128) * 16;
#pragma unroll
  for (int i = 0; i < 8; ++i) {
    int d = dg * 8 + i;
    csa[d * 16 + n] = ap[i];
    csb[d * 16 + n] = bc[i];
  }
}

// ============ 7b. scan phase B (register prefetch) ============
__global__ __launch_bounds__(256) void k_scanB(float* __restrict__ ws) {
  int g = blockIdx.x * 256 + threadIdx.x;
  int bk = g >> 11;
  int dn = g & 2047;
  const float* csa = ws + OCSA;
  const float* csb = ws + OCSB;
  float* hst = ws + OHST;
  size_t base = (size_t)bk * SNC * 2048 + dn;
  float h = 0.f;
  float a = csa[base], bq = csb[base];
  for (int c = 0; c < SNC; ++c) {
    float na = 0.f, nb = 0.f;
    if (c + 1 < SNC) {
      size_t idx2 = base + (size_t)(c + 1) * 2048;
      na = csa[idx2]; nb = csb[idx2];
    }
    hst[base + (size_t)c * 2048] = h;
    h = a * h + bq;
    a = na; bq = nb;
  }
}

// ============ 7c. scan phase C (ping-pong, 1 barrier/step) ============
__global__ __launch_bounds__(256) void k_scanC(const float* __restrict__ alog,
    const float* __restrict__ Dp, float* __restrict__ ws) {
  int c = blockIdx.x, bk = blockIdx.y;
  int b = bk >> 2, k = bk & 3;
  int t = threadIdx.x;
  int n = t & 15, dg = t >> 4;
  __shared__ float dt_s[2][128], x_s[2][128], Bs_s[2][16], Cs_s[2][16];
  float A_r[8], h[8], Dv[8];
#pragma unroll
  for (int i = 0; i < 8; ++i) {
    int d = dg * 8 + i;
    A_r[i] = -__expf(alog[(size_t)((k * 128 + d) * 16) + n]);
    h[i] = ws[OHST + ((size_t)(bk * SNC + c) * 128 + d) * 16 + n];
    Dv[i] = Dp[k * 128 + d];
  }
  const float* dtp = ws + ODT2 + ((size_t)bk * Ll) * 128;
  const float* bsp = ws + OBS2 + ((size_t)bk * Ll) * 16;
  const float* csp = ws + OCS2 + ((size_t)bk * Ll) * 16;
  const float* xb = ws + OX1S + (size_t)b * Ll * 128;
  float* yp = ws + OYS2 + ((size_t)bk * Ll) * 128;
  float r_a = 0.f, r_bc = 0.f;
  {
    int l = c * SCH;
    int sp = spmap(k, l);
    if (t < 128) r_a = dtp[(size_t)l * 128 + t];
    else r_a = xb[(size_t)sp * 128 + (t - 128)];
    if (t < 16) r_bc = bsp[(size_t)l * 16 + t];
    else if (t < 32) r_bc = csp[(size_t)l * 16 + (t - 16)];
  }
  for (int ll = 0; ll < SCH; ++ll) {
    int buf = ll & 1;
    if (t < 128) dt_s[buf][t] = r_a;
    else x_s[buf][t - 128] = r_a;
    if (t < 16) Bs_s[buf][t] = r_bc;
    else if (t < 32) Cs_s[buf][t - 16] = r_bc;
    __syncthreads();
    if (ll + 1 < SCH) {
      int l2 = c * SCH + ll + 1;
      int sp2 = spmap(k, l2);
      if (t < 128) r_a = dtp[(size_t)l2 * 128 + t];
      else r_a = xb[(size_t)sp2 * 128 + (t - 128)];
      if (t < 16) r_bc = bsp[(size_t)l2 * 16 + t];
      else if (t < 32) r_bc = csp[(size_t)l2 * 16 + (t - 16)];
    }
    int l = c * SCH + ll;
    float Bv = Bs_s[buf][n], Cv = Cs_s[buf][n];
    float yacc[8];
#pragma unroll
    for (int i = 0; i < 8; ++i) {
      int d = dg * 8 + i;
      float dtv = dt_s[buf][d];
      float a = __expf(dtv * A_r[i]);
      h[i] = h[i] * a + dtv * x_s[buf][d] * Bv;
      yacc[i] = h[i] * Cv;
    }
#pragma unroll
    for (int i = 0; i < 8; ++i) {
      float yv = yacc[i];
      yv += __shfl_xor(yv, 1, 64);
      yv += __shfl_xor(yv, 2, 64);
      yv += __shfl_xor(yv, 4, 64);
      yv += __shfl_xor(yv, 8, 64);
      yacc[i] = yv;
    }
    if (n == 0) {
#pragma unroll
      for (int i = 0; i < 8; ++i) {
        int d = dg * 8 + i;
        yp[(size_t)l * 128 + d] = yacc[i] + Dv[i] * x_s[buf][d];
      }
    }
  }
}

// ============ 8+9+10. comb + LN + gate + x2 + LN + FFN conv1 (fused, 8 tok) ============
__global__ __launch_bounds__(256) void k_combffn1(const float* __restrict__ enc,
    const float* __restrict__ nw, const float* __restrict__ nb,
    const float* __restrict__ snr, const float* __restrict__ ow,
    const float* __restrict__ lw, const float* __restrict__ lb,
    const float* __restrict__ w1, float* __restrict__ ws) {
  int l0 = blockIdx.x * TT, b = blockIdx.y, t = threadIdx.x;
  __shared__ float yr[128][9];
  __shared__ float redm[2][TT], redq[2][TT];
  __shared__ float part[2][TT][64];
  __shared__ float xn_s[64][9];
  int lane = t & 63, wid = (t >> 6) & 1;
  float v[TT], m[TT];
  if (t < 128) {
    int d = t;
    const float* ysb = ws + OYS2;
#pragma unroll
    for (int i = 0; i < TT; ++i) {
      int l = l0 + i;
      int hh = l / 48, wwp = l % 48;
      int lT = wwp * 48 + hh;
      v[i] = ysb[((size_t)(b * 4 + 0) * Ll + l) * 128 + d] +
             ysb[((size_t)(b * 4 + 2) * Ll + (2303 - l)) * 128 + d] +
             ysb[((size_t)(b * 4 + 1) * Ll + lT) * 128 + d] +
             ysb[((size_t)(b * 4 + 3) * Ll + (2303 - lT)) * 128 + d];
    }
    float s[TT];
#pragma unroll
    for (int i = 0; i < TT; ++i) s[i] = v[i];
#pragma unroll
    for (int o = 32; o >= 1; o >>= 1)
#pragma unroll
      for (int i = 0; i < TT; ++i) s[i] += __shfl_xor(s[i], o, 64);
    if (lane == 0) {
#pragma unroll
      for (int i = 0; i < TT; ++i) redm[wid][i] = s[i];
    }
  }
  __syncthreads();
  if (t < 128) {
    float q[TT];
#pragma unroll
    for (int i = 0; i < TT; ++i) {
      m[i] = (redm[0][i] + redm[1][i]) * (1.f / 128.f);
      float dv = v[i] - m[i];
      q[i] = dv * dv;
    }
#pragma unroll
    for (int o = 32; o >= 1; o >>= 1)
#pragma unroll
      for (int i = 0; i < TT; ++i) q[i] += __shfl_xor(q[i], o, 64);
    if (lane == 0) {
#pragma unroll
      for (int i = 0; i < TT; ++i) redq[wid][i] = q[i];
    }
  }
  __syncthreads();
  if (t < 128) {
    int d = t;
    float nwv = nw[d], nbv = nb[d];
#pragma unroll
    for (int i = 0; i < TT; ++i) {
      int l = l0 + i;
      float var = (redq[0][i] + redq[1][i]) * (1.f / 128.f);
      float y = (v[i] - m[i]) * rsqrtf(var + 1e-5f) * nwv + nbv;
      float zv = ws[OZ + ((size_t)(b * Ll + l)) * 128 + d];
      y *= siluf(zv);
      y *= snr[b * Ll + l];
      yr[d][i] = y;
    }
  }
  __syncthreads();
  if (t < 128) {
    int col = t & 63, seg = t >> 6;
    float acc[TT];
#pragma unroll
    for (int i = 0; i < TT; ++i) acc[i] = 0.f;
    const float* ows = ow + (size_t)(seg * 64) * 64 + col;
    for (int c = 0; c < 64; ++c) {
      float w = ows[c * 64];
      const float* yc = &yr[seg * 64 + c][0];
#pragma unroll
      for (int i = 0; i < TT; ++i) acc[i] += yc[i] * w;
    }
#pragma unroll
    for (int i = 0; i < TT; ++i) part[seg][i][col] = acc[i];
  }
  __syncthreads();
  if (t < 64) {
    float lwv = lw[t], lbv = lb[t];
#pragma unroll
    for (int i = 0; i < TT; ++i) {
      float a = part[0][i][t] + part[1][i][t];
      a += enc[(size_t)b * Cc * Ll + (size_t)t * Ll + l0 + i];
      ws[OX2 + ((size_t)(b * Ll + l0 + i)) * 64 + t] = a;
      float s = a;
#pragma unroll
      for (int o = 32; o >= 1; o >>= 1) s += __shfl_xor(s, o, 64);
      float mm = s * (1.f / 64.f);
      float dd2 = a - mm;
      float vs = dd2 * dd2;
#pragma unroll
      for (int o = 32; o >= 1; o >>= 1) vs += __shfl_xor(vs, o, 64);
      xn_s[t][i] = dd2 * rsqrtf(vs * (1.f / 64.f) + 1e-5f) * lwv + lbv;
    }
  }
  __syncthreads();
  {
    float acc2[TT];
#pragma unroll
    for (int i = 0; i < TT; ++i) acc2[i] = 0.f;
    const float* wp = w1 + (size_t)t * 64;
    for (int c = 0; c < 64; ++c) {
      float w = wp[c];
      const float* xc = &xn_s[c][0];
#pragma unroll
      for (int i = 0; i < TT; ++i) acc2[i] += xc[i] * w;
    }
#pragma unroll
    for (int i = 0; i < TT; ++i)
      ws[OH1A + ((size_t)(b * Ll + l0 + i)) * 256 + t] = geluf(acc2[i]);
  }
}

// ============ 11. FFN depthwise 3x3 + gelu, 8 tokens/block ============
__global__ __launch_bounds__(256) void k_ffndw(const float* __restrict__ dww,
                                               float* __restrict__ ws) {
  int l0 = blockIdx.x * TT, b = blockIdx.y, t = threadIdx.x;
  int h = l0 / 48, w0 = l0 % 48;
  __shared__ float tile[3][10][256];
  for (int idx = t; idx < 7680; idx += 256) {
    int r = idx / 2560, rem = idx % 2560;
    int col = rem >> 8, ch = rem & 255;
    int hh = h + r - 1, wx = w0 + col - 1;
    float v = 0.f;
    if (hh >= 0 && hh < 48 && wx >= 0 && wx < 48)
      v = ws[OH1A + ((size_t)(b * Ll + hh * 48 + wx)) * 256 + ch];
    tile[r][col][ch] = v;
  }
  __syncthreads();
  float dwr[9];
#pragma unroll
  for (int j = 0; j < 9; ++j) dwr[j] = dww[t * 9 + j];
#pragma unroll
  for (int i = 0; i < TT; ++i) {
    float acc = 0.f;
#pragma unroll
    for (int kh = 0; kh < 3; ++kh)
#pragma unroll
      for (int kw = 0; kw < 3; ++kw)
        acc += tile[kh][i + kw][t] * dwr[kh * 3 + kw];
    ws[OH1B + ((size_t)(b * Ll + l0 + i)) * 256 + t] = geluf(acc);
  }
}

// ============ 12. FFN conv2 1x1 + residual + transposed out, 8 tokens/block ============
__global__ __launch_bounds__(256) void k_ffn2(const float* __restrict__ w2,
                                              float* __restrict__ ws,
                                              float* __restrict__ out) {
  int l0 = blockIdx.x * TT, b = blockIdx.y, t = threadIdx.x;
  __shared__ float hr[256][9];
  __shared__ float part[4][TT][64];
  const float* hp = ws + OH1B + ((size_t)(b * Ll + l0)) * 256;
#pragma unroll
  for (int i = 0; i < TT; ++i) hr[t][i] = hp[(size_t)i * 256 + t];
  __syncthreads();
  int col = t & 63, seg = t >> 6;
  {
    float acc[TT];
#pragma unroll
    for (int i = 0; i < TT; ++i) acc[i] = 0.f;
    const float* wp = w2 + (size_t)col * 256 + seg * 64;
    for (int c = 0; c < 64; ++c) {
      float w = wp[c];
      const float* hc = &hr[seg * 64 + c][0];
#pragma unroll
      for (int i = 0; i < TT; ++i) acc[i] += hc[i] * w;
    }
#pragma unroll
    for (int i = 0; i < TT; ++i) part[seg][i][col] = acc[i];
  }
  __syncthreads();
  if (t < 64) {
    float av[TT];
#pragma unroll
    for (int i = 0; i < TT; ++i) {
      float a = part[0][i][t] + part[1][i][t] + part[2][i][t] + part[3][i][t];
      av[i] = a + ws[OX2 + ((size_t)(b * Ll + l0 + i)) * 64 + t];
    }
    float* opx = out + ((size_t)(b * 64 + t)) * 2304 + l0;
    *(float4*)opx = make_float4(av[0], av[1], av[2], av[3]);
    *((float4*)opx + 1) = make_float4(av[4], av[5], av[6], av[7]);
  }
}

extern "C" void kernel_launch(void* const* d_in, const int* in_sizes, int n_in,
                              void* d_out, int out_size, void* d_ws, size_t ws_size,
                              hipStream_t stream) {
  (void)in_sizes; (void)n_in; (void)out_size;
  const float* enc  = (const float*)d_in[0];
  const float* snr  = (const float*)d_in[1];
  const float* wq   = (const float*)d_in[2];
  const float* wk   = (const float*)d_in[3];
  const float* wv   = (const float*)d_in[4];
  const float* fc   = (const float*)d_in[5];
  const float* alnw = (const float*)d_in[6];
  const float* alnb = (const float*)d_in[7];
  const float* ssin = (const float*)d_in[8];
  const float* cw   = (const float*)d_in[9];
  const float* cb   = (const float*)d_in[10];
  const float* xw   = (const float*)d_in[11];
  const float* dtw  = (const float*)d_in[12];
  const float* dtb  = (const float*)d_in[13];
  const float* alog = (const float*)d_in[14];
  const float* Dp   = (const float*)d_in[15];
  const float* nw   = (const float*)d_in[16];
  const float* nb   = (const float*)d_in[17];
  const float* ow   = (const float*)d_in[18];
  const float* flnw = (const float*)d_in[19];
  const float* flnb = (const float*)d_in[20];
  const float* w1   = (const float*)d_in[21];
  const float* dww  = (const float*)d_in[22];
  const float* w2   = (const float*)d_in[23];
  float* ws = (float*)d_ws;
  float* out = (float*)d_out;

  if (ws_size < (size_t)WS_NEED_FLOATS * 4) {
    hipLaunchKernelGGL(k_code, dim3(1), dim3(64), 0, stream, out);
    return;
  }

  hipLaunchKernelGGL(k_qkv, dim3(Ll / TT, Bq), dim3(256), 0, stream, enc, wq, wk, wv, ws);
  hipLaunchKernelGGL(k_vt, dim3(Ll / 64, Bq * NHh), dim3(256), 0, stream, ws);
  hipLaunchKernelGGL(k_attn, dim3(Ll / 64, Bq * NHh, 2), dim3(256), 0, stream, snr, ws);
  hipLaunchKernelGGL(k_ocomb, dim3(Bq * Ll, 1), dim3(256), 0, stream, ws);
  hipLaunchKernelGGL(k_oprojxz, dim3(Ll / TT, Bq), dim3(256), 0, stream, enc, fc, alnw, alnb, ssin, ws);
  hipLaunchKernelGGL(k_conv, dim3(Ll / TT, Bq), dim3(256), 0, stream, cw, cb, ws);
  hipLaunchKernelGGL(k_xdbl, dim3(Ll / TT, Bq * 4), dim3(128), 0, stream, xw, dtw, dtb, ws);
  hipLaunchKernelGGL(k_scanA, dim3(SNC, Bq * 4), dim3(256), 0, stream, alog, ws);
  hipLaunchKernelGGL(k_scanB, dim3(64), dim3(256), 0, stream, ws);
  hipLaunchKernelGGL(k_scanC, dim3(SNC, Bq * 4), dim3(256), 0, stream, alog, Dp, ws);
  hipLaunchKernelGGL(k_combffn1, dim3(Ll / TT, Bq), dim3(256), 0, stream, enc, nw, nb, snr, ow, flnw, flnb, w1, ws);
  hipLaunchKernelGGL(k_ffndw, dim3(Ll / TT, Bq), dim3(256), 0, stream, dww, ws);
  hipLaunchKernelGGL(k_ffn2, dim3(Ll / TT, Bq), dim3(256), 0, stream, w2, ws, out);
}

// Round 16
// 424.735 us; speedup vs baseline: 1.0468x; 1.0211x over previous
//
#include <hip/hip_runtime.h>
#include <hip/hip_bf16.h>

#define Bq 2
#define Cc 64
#define Hh 48
#define Ww 48
#define Ll 2304
#define NHh 8
#define DKk 64
#define DVv 128
#define DNn 128
#define NSs 16
#define Rr 4
#define SCH 48
#define SNC 48
#define TT 8      // tokens per block in GEMM-ish kernels

// ---- workspace layout (float offsets) ----
#define OQ    0u                 // (B*8, L, 64) Q bf16 (ushort), pre-scaled by 1/8
#define OK_   2359296u           // (B*8, L, 64) K bf16 (ushort)
#define OV    4718592u           // (B*8, L, 128) V fp32 / attn partial-1 (B,L,1024)
#define OO    9437184u           // (B, L, 1024) attn partial-0
#define OX1P  14450688u          // (B,L,128)  [old OY2 region]
#define OZ    15040512u          // (B,L,128)  [old OX2+OXN span]
#define OVT   15630336u          // (B*8, 128, L) V^T bf16 (ushort; uses half the region)
#define OLP   (OVT + 2359296u)   // l-partials: 2 x (B*8, L) [second half of OVT region]
#define OX2   0u                 // (B,L,64)   [ODT2/OQ region, dead after scan]
#define WS_NEED_FLOATS (OVT + 4718592u)
// aliases (lifetimes: q,k,v,vt dead after k_oprojxz; o dead after k_oprojxz)
#define ODT2  OQ                 // (B*4, L, 128) dt, l-major
#define OYS2  OK_                // (B*4, L, 128) scan y, l-major
#define OX1S  (OV + 1179648u)    // (B,L,128)
#define OBS2  (OV + 1769472u)    // (B*4, L, 16)
#define OCS2  (OV + 2064384u)    // (B*4, L, 16)
#define OCSA  (OV + 2359296u)    // (B*4, SNC, 128, 16)
#define OCSB  (OV + 3145728u)    // (B*4, SNC, 128, 16)
#define OHST  (OV + 3932160u)    // (B*4, SNC, 128, 16)
#define OH1A  OO                 // (B,L,256)
#define OH1B  (OO + 1179648u)    // (B,L,256)

typedef short short8v __attribute__((ext_vector_type(8)));
typedef short short4v __attribute__((ext_vector_type(4)));
typedef float f32x4 __attribute__((ext_vector_type(4)));
typedef unsigned short ushort_t;

__device__ __forceinline__ float geluf(float x) {
  return 0.5f * x * (1.0f + erff(x * 0.70710678118654752f));
}
__device__ __forceinline__ float siluf(float x) {
  return x / (1.0f + __expf(-x));
}
__device__ __forceinline__ float softplusf(float x) {
  return fmaxf(x, 0.0f) + log1pf(__expf(-fabsf(x)));
}
__device__ __forceinline__ int spmap(int k, int l) {
  if (k == 0) return l;
  if (k == 1) return (l % 48) * 48 + l / 48;
  if (k == 2) return 2303 - l;
  int l2 = 2303 - l; return (l2 % 48) * 48 + l2 / 48;
}
__device__ __forceinline__ short f2bf(float f) {
  unsigned u = __float_as_uint(f);
  unsigned r = (u + 0x7FFFu + ((u >> 16) & 1u)) >> 16;
  return (short)r;
}

__global__ void k_code(float* out) { if (threadIdx.x == 0) out[0] = 25000.f; }

// ============ 1. QKV projection, 8 tokens/block (V fp32, coalesced) ============
__global__ __launch_bounds__(256) void k_qkv(const float* __restrict__ enc,
    const float* __restrict__ wq, const float* __restrict__ wk,
    const float* __restrict__ wv, float* __restrict__ ws) {
  int l0 = blockIdx.x * TT; int b = blockIdx.y;
  int t = threadIdx.x;
  __shared__ float xs[64][12];   // [c][token]
  {
    int idx = t, c = idx >> 3, i = idx & 7;
    xs[c][i] = enc[(size_t)b * Cc * Ll + (size_t)c * Ll + l0 + i];
    idx = t + 256; c = idx >> 3; i = idx & 7;
    xs[c][i] = enc[(size_t)b * Cc * Ll + (size_t)c * Ll + l0 + i];
  }
  __syncthreads();
  ushort_t* qb = (ushort_t*)(ws + OQ);
  ushort_t* kb = (ushort_t*)(ws + OK_);
  float* v = ws + OV;
#pragma unroll
  for (int g = 0; g < 6; ++g) {
    int j = t + g * 256;
    float acc[TT];
#pragma unroll
    for (int i = 0; i < TT; ++i) acc[i] = 0.f;
    const float* wp; int col, stride;
    if (j < 512) { wp = wq + j; stride = 512; col = j; }
    else if (j < 1024) { wp = wk + (j - 512); stride = 512; col = j - 512; }
    else { wp = wv + (j - 1024); stride = 1024; col = j - 1024; }
    for (int c = 0; c < 64; ++c) {
      float w = wp[(size_t)c * stride];
      const float4* xc = (const float4*)&xs[c][0];
      float4 x0 = xc[0], x1 = xc[1];
      acc[0] += x0.x * w; acc[1] += x0.y * w;
      acc[2] += x0.z * w; acc[3] += x0.w * w;
      acc[4] += x1.x * w; acc[5] += x1.y * w;
      acc[6] += x1.z * w; acc[7] += x1.w * w;
    }
    if (j < 512) {
#pragma unroll
      for (int i = 0; i < TT; ++i)
        qb[((size_t)(b * 8 + (col >> 6)) * Ll + l0 + i) * 64 + (col & 63)] =
            (ushort_t)f2bf(acc[i] * 0.125f);
    } else if (j < 1024) {
#pragma unroll
      for (int i = 0; i < TT; ++i)
        kb[((size_t)(b * 8 + (col >> 6)) * Ll + l0 + i) * 64 + (col & 63)] =
            (ushort_t)f2bf(acc[i]);
    } else {
#pragma unroll
      for (int i = 0; i < TT; ++i)
        v[((size_t)(b * 8 + (col >> 7)) * Ll + l0 + i) * 128 + (col & 127)] = acc[i];
    }
  }
}

// ============ 1b. transpose V -> vt bf16 (bh, dv, L) ============
__global__ __launch_bounds__(256) void k_vt(float* __restrict__ ws) {
  int bh = blockIdx.y;
  int l0 = blockIdx.x * 64;
  int t = threadIdx.x;
  __shared__ float tile[128][65];
  const float* vp = ws + OV + ((size_t)bh * Ll + l0) * 128;
  for (int i = t; i < 64 * 32; i += 256) {
    int l = i >> 5, dv4 = (i & 31) * 4;
    float4 a = *(const float4*)(vp + (size_t)l * 128 + dv4);
    tile[dv4][l] = a.x; tile[dv4 + 1][l] = a.y;
    tile[dv4 + 2][l] = a.z; tile[dv4 + 3][l] = a.w;
  }
  __syncthreads();
  ushort_t* vt = (ushort_t*)(ws + OVT) + (size_t)bh * 128 * Ll + l0;
  for (int i = t; i < 128 * 16; i += 256) {
    int dv = i >> 4, l4 = (i & 15) * 4;
    short4v a;
    a[0] = f2bf(tile[dv][l4]); a[1] = f2bf(tile[dv][l4 + 1]);
    a[2] = f2bf(tile[dv][l4 + 2]); a[3] = f2bf(tile[dv][l4 + 3]);
    *(short4v*)(vt + (size_t)dv * Ll + l4) = a;
  }
}

// ============ 2. flash attention (bf16 MFMA, fixed-max softmax, 2-way K-split) ============
#define NKT2 18
#define LSK 72
__global__ __launch_bounds__(256) void k_attn(const float* __restrict__ snr,
                                              float* __restrict__ ws) {
  int bh = blockIdx.y; int b = bh >> 3; int hd = bh & 7;
  int q0 = blockIdx.x * 64;
  int ks = blockIdx.z;
  int kbase = ks * (Ll / 2);
  int t = threadIdx.x;
  int w = t >> 6, lane = t & 63;
  int m16 = lane & 15, quad = lane >> 4;

  __shared__ __align__(16) ushort_t Ks[64 * LSK];
  __shared__ __align__(16) ushort_t Vs[128 * LSK];
  __shared__ __align__(16) ushort_t Ps[4 * 16 * LSK];
  __shared__ float sfac_s[64];

  const ushort_t* qbf = (const ushort_t*)(ws + OQ) + (size_t)bh * Ll * 64;
  const ushort_t* kbf = (const ushort_t*)(ws + OK_) + (size_t)bh * Ll * 64;
  const ushort_t* vtb = (const ushort_t*)(ws + OVT) + (size_t)bh * 128 * Ll;

  short8v qa[2];
  {
    const ushort_t* qrp = qbf + (size_t)(q0 + w * 16 + m16) * 64 + quad * 8;
    qa[0] = *(const short8v*)qrp;
    qa[1] = *(const short8v*)(qrp + 32);
  }
  int sk_key = t >> 2, sk_d0 = (t & 3) * 16;
  int sv_dv = t >> 1, sv_k0 = (t & 1) * 32;

  short8v kreg[2], vreg[4];
  float snr_reg = 0.f;
  {
    const ushort_t* ksrc = kbf + (size_t)(kbase + sk_key) * 64 + sk_d0;
    kreg[0] = *(const short8v*)ksrc;
    kreg[1] = *(const short8v*)(ksrc + 8);
    const ushort_t* vsrc = vtb + (size_t)sv_dv * Ll + kbase + sv_k0;
#pragma unroll
    for (int i = 0; i < 4; ++i) vreg[i] = *(const short8v*)(vsrc + i * 8);
    if (t < 64) snr_reg = snr[b * Ll + kbase + t];
  }

  f32x4 oacc[8];
#pragma unroll
  for (int i = 0; i < 8; ++i) oacc[i] = (f32x4)0.f;
  float l_r[4] = {0.f, 0.f, 0.f, 0.f};

  for (int kt = 0; kt < NKT2; ++kt) {
    __syncthreads();
    *(short8v*)&Ks[sk_key * LSK + sk_d0] = kreg[0];
    *(short8v*)&Ks[sk_key * LSK + sk_d0 + 8] = kreg[1];
#pragma unroll
    for (int i = 0; i < 4; ++i)
      *(short8v*)&Vs[sv_dv * LSK + sv_k0 + i * 8] = vreg[i];
    if (t < 64) sfac_s[t] = snr_reg + 1e-4f;
    __syncthreads();
    if (kt + 1 < NKT2) {
      int k0n = kbase + (kt + 1) * 64;
      const ushort_t* ksrc = kbf + (size_t)(k0n + sk_key) * 64 + sk_d0;
      kreg[0] = *(const short8v*)ksrc;
      kreg[1] = *(const short8v*)(ksrc + 8);
      const ushort_t* vsrc = vtb + (size_t)sv_dv * Ll + k0n + sv_k0;
#pragma unroll
      for (int i = 0; i < 4; ++i) vreg[i] = *(const short8v*)(vsrc + i * 8);
      if (t < 64) snr_reg = snr[b * Ll + k0n + t];
    }

    f32x4 sac[4];
#pragma unroll
    for (int n = 0; n < 4; ++n) {
      int key = n * 16 + m16;
      short8v kb0 = *(const short8v*)&Ks[key * LSK + quad * 8];
      short8v kb1 = *(const short8v*)&Ks[key * LSK + 32 + quad * 8];
      f32x4 acc = (f32x4)0.f;
      acc = __builtin_amdgcn_mfma_f32_16x16x32_bf16(qa[0], kb0, acc, 0, 0, 0);
      acc = __builtin_amdgcn_mfma_f32_16x16x32_bf16(qa[1], kb1, acc, 0, 0, 0);
      sac[n] = acc;
    }
    float sf[4];
#pragma unroll
    for (int n = 0; n < 4; ++n) sf[n] = sfac_s[n * 16 + m16];
    ushort_t* pw = &Ps[w * 16 * LSK];
#pragma unroll
    for (int r = 0; r < 4; ++r) {
#pragma unroll
      for (int n = 0; n < 4; ++n) {
        float p = __expf(sac[n][r]) * sf[n];
        l_r[r] += p;
        pw[(quad * 4 + r) * LSK + n * 16 + m16] = (ushort_t)f2bf(p);
      }
    }
    short8v pb0 = *(const short8v*)&pw[m16 * LSK + quad * 8];
    short8v pb1 = *(const short8v*)&pw[m16 * LSK + 32 + quad * 8];
#pragma unroll
    for (int dt_ = 0; dt_ < 8; ++dt_) {
      const ushort_t* vrow = &Vs[(dt_ * 16 + m16) * LSK];
      short8v va0 = *(const short8v*)&vrow[quad * 8];
      short8v va1 = *(const short8v*)&vrow[32 + quad * 8];
      f32x4 o = oacc[dt_];
      o = __builtin_amdgcn_mfma_f32_16x16x32_bf16(va0, pb0, o, 0, 0, 0);
      o = __builtin_amdgcn_mfma_f32_16x16x32_bf16(va1, pb1, o, 0, 0, 0);
      oacc[dt_] = o;
    }
  }
#pragma unroll
  for (int r = 0; r < 4; ++r) {
    float lv = l_r[r];
    lv += __shfl_xor(lv, 1, 64);
    lv += __shfl_xor(lv, 2, 64);
    lv += __shfl_xor(lv, 4, 64);
    lv += __shfl_xor(lv, 8, 64);
    l_r[r] = lv;
  }
  if (m16 == 0) {
    float* lp = ws + OLP + (size_t)ks * (Bq * NHh * Ll) + (size_t)bh * Ll;
#pragma unroll
    for (int r = 0; r < 4; ++r) lp[q0 + w * 16 + quad * 4 + r] = l_r[r];
  }
  float* opb = ws + (ks ? OV : OO);
  float* op = opb + ((size_t)(b * Ll + q0 + w * 16 + m16)) * 1024 + hd * 128;
#pragma unroll
  for (int dt_ = 0; dt_ < 8; ++dt_) {
#pragma unroll
    for (int r = 0; r < 4; ++r) {
      op[dt_ * 16 + quad * 4 + r] = oacc[dt_][r];
    }
  }
}

// ============ 3+4. combine partials + o@fc + residual + LN + xz, 8 tok/block ============
__global__ __launch_bounds__(256) void k_oprojxz(const float* __restrict__ enc,
    const float* __restrict__ fc, const float* __restrict__ lnw,
    const float* __restrict__ lnb, const float* __restrict__ ssin,
    float* __restrict__ ws) {
  int l0 = blockIdx.x * TT, b = blockIdx.y, t = threadIdx.x;
  __shared__ float orow[1024][9];
  __shared__ float part[4][TT][64];
  __shared__ float xh_s[64][9];
  __shared__ float linv_s[8][TT];
  if (t < 64) {
    int hd = t >> 3, i = t & 7;
    float l1 = ws[OLP + (size_t)(b * 8 + hd) * Ll + l0 + i];
    float l2 = ws[OLP + (size_t)(Bq * NHh * Ll) + (size_t)(b * 8 + hd) * Ll + l0 + i];
    linv_s[hd][i] = 1.f / (l1 + l2);
  }
  __syncthreads();
  const float* op0 = ws + OO + ((size_t)(b * Ll + l0)) * 1024;
  const float* op1 = ws + OV + ((size_t)(b * Ll + l0)) * 1024;
#pragma unroll
  for (int k = 0; k < 4; ++k) {
    int c = t + k * 256;
    float li[TT];
#pragma unroll
    for (int i = 0; i < TT; ++i) li[i] = linv_s[c >> 7][i];
#pragma unroll
    for (int i = 0; i < TT; ++i)
      orow[c][i] = (op0[(size_t)i * 1024 + c] + op1[(size_t)i * 1024 + c]) * li[i];
  }
  __syncthreads();
  int col = t & 63, seg = t >> 6;
  {
    float acc[TT];
#pragma unroll
    for (int i = 0; i < TT; ++i) acc[i] = 0.f;
    const float* fcs = fc + (size_t)(seg * 256) * 64 + col;
    for (int c = 0; c < 256; ++c) {
      float w = fcs[(size_t)c * 64];
      const float* orc = &orow[seg * 256 + c][0];
#pragma unroll
      for (int i = 0; i < TT; ++i) acc[i] += orc[i] * w;
    }
#pragma unroll
    for (int i = 0; i < TT; ++i) part[seg][i][col] = acc[i];
  }
  __syncthreads();
  {
    // wave-parallel LN: wave seg handles tokens seg*2, seg*2+1; lane = channel
    float lw = lnw[col], lb = lnb[col];
#pragma unroll
    for (int i2 = 0; i2 < 2; ++i2) {
      int i = seg * 2 + i2;
      float a = part[0][i][col] + part[1][i][col] + part[2][i][col] + part[3][i][col];
      a += enc[(size_t)b * Cc * Ll + (size_t)col * Ll + l0 + i];
      float s = a;
#pragma unroll
      for (int o = 32; o >= 1; o >>= 1) s += __shfl_xor(s, o, 64);
      float m = s * (1.f / 64.f);
      float dd = a - m;
      float vs = dd * dd;
#pragma unroll
      for (int o = 32; o >= 1; o >>= 1) vs += __shfl_xor(vs, o, 64);
      xh_s[col][i] = dd * rsqrtf(vs * (1.f / 64.f) + 1e-5f) * lw + lb;
    }
  }
  __syncthreads();
  {
    float acc2[TT];
#pragma unroll
    for (int i = 0; i < TT; ++i) acc2[i] = 0.f;
    for (int c = 0; c < 64; ++c) {
      float w = ssin[c * 256 + t];
      const float* xc = &xh_s[c][0];
#pragma unroll
      for (int i = 0; i < TT; ++i) acc2[i] += xc[i] * w;
    }
    if (t < 128) {
#pragma unroll
      for (int i = 0; i < TT; ++i)
        ws[OX1P + ((size_t)(b * Ll + l0 + i)) * 128 + t] = acc2[i];
    } else {
#pragma unroll
      for (int i = 0; i < TT; ++i)
        ws[OZ + ((size_t)(b * Ll + l0 + i)) * 128 + (t - 128)] = acc2[i];
    }
  }
}

// ============ 5. depthwise conv3x3 + bias + silu, 8 tokens/block ============
__global__ __launch_bounds__(256) void k_conv(const float* __restrict__ cw,
    const float* __restrict__ cb, float* __restrict__ ws) {
  int l0 = blockIdx.x * TT, b = blockIdx.y, t = threadIdx.x;
  int h = l0 / 48, w0 = l0 % 48;
  __shared__ float tile[3][10][128];
  for (int idx = t; idx < 3840; idx += 256) {
    int r = idx / 1280, rem = idx % 1280;
    int col = rem >> 7, d = rem & 127;
    int hh = h + r - 1, wx = w0 + col - 1;
    float v = 0.f;
    if (hh >= 0 && hh < 48 && wx >= 0 && wx < 48)
      v = ws[OX1P + ((size_t)(b * Ll + hh * 48 + wx)) * 128 + d];
    tile[r][col][d] = v;
  }
  __syncthreads();
  int d = t & 127, half = t >> 7;
  float cwr[9];
#pragma unroll
  for (int j = 0; j < 9; ++j) cwr[j] = cw[d * 9 + j];
  float cbv = cb[d];
#pragma unroll
  for (int j = 0; j < 4; ++j) {
    int i = half * 4 + j;
    float acc = cbv;
#pragma unroll
    for (int kh = 0; kh < 3; ++kh)
#pragma unroll
      for (int kw = 0; kw < 3; ++kw)
        acc += tile[kh][i + kw][d] * cwr[kh * 3 + kw];
    ws[OX1S + ((size_t)(b * Ll + l0 + i)) * 128 + d] = siluf(acc);
  }
}

// ============ 6. x_dbl projections, 8 tokens/block ============
__global__ __launch_bounds__(128) void k_xdbl(const float* __restrict__ xw,
    const float* __restrict__ dtw, const float* __restrict__ dtb,
    float* __restrict__ ws) {
  int l0 = blockIdx.x * TT;
  int by = blockIdx.y; int b = by >> 2; int k = by & 3;
  int t = threadIdx.x;
  __shared__ float xv[128][9];
  __shared__ float pr[36][TT];
#pragma unroll
  for (int i = 0; i < TT; ++i) {
    int sp = spmap(k, l0 + i);
    xv[t][i] = ws[OX1S + ((size_t)(b * Ll) + sp) * 128 + t];
  }
  __syncthreads();
  if (t < 36) {
    float s[TT];
#pragma unroll
    for (int i = 0; i < TT; ++i) s[i] = 0.f;
    const float* wp = xw + (size_t)(k * 36 + t) * 128;
    for (int d = 0; d < 128; ++d) {
      float w = wp[d];
      const float* xc = &xv[d][0];
#pragma unroll
      for (int i = 0; i < TT; ++i) s[i] += xc[i] * w;
    }
#pragma unroll
    for (int i = 0; i < TT; ++i) pr[t][i] = s[i];
  }
  __syncthreads();
  {
    int d = t;
    const float* wp = dtw + (size_t)(k * 128 + d) * 4;
    float w0 = wp[0], w1 = wp[1], w2 = wp[2], w3 = wp[3];
    float bb = dtb[k * 128 + d];
#pragma unroll
    for (int i = 0; i < TT; ++i) {
      float v = pr[0][i] * w0 + pr[1][i] * w1 + pr[2][i] * w2 + pr[3][i] * w3 + bb;
      ws[ODT2 + ((size_t)(by * Ll + l0 + i)) * 128 + d] = softplusf(v);
    }
  }
  if (t < 16) {
#pragma unroll
    for (int i = 0; i < TT; ++i)
      ws[OBS2 + ((size_t)(by * Ll + l0 + i)) * 16 + t] = pr[4 + t][i];
  } else if (t < 32) {
#pragma unroll
    for (int i = 0; i < TT; ++i)
      ws[OCS2 + ((size_t)(by * Ll + l0 + i)) * 16 + (t - 16)] = pr[20 + (t - 16)][i];
  }
}

// ============ 7a. scan phase A (ping-pong, 1 barrier/step) ============
__global__ __launch_bounds__(256) void k_scanA(const float* __restrict__ alog,
                                               float* __restrict__ ws) {
  int c = blockIdx.x;
  int bk = blockIdx.y;
  int b = bk >> 2, k = bk & 3;
  int t = threadIdx.x;
  int n = t & 15, dg = t >> 4;
  __shared__ float dt_s[2][128], x_s[2][128], Bs_s[2][16];
  float A_r[8], ap[8], bc[8];
#pragma unroll
  for (int i = 0; i < 8; ++i) {
    int d = dg * 8 + i;
    A_r[i] = -__expf(alog[(size_t)((k * 128 + d) * 16) + n]);
    ap[i] = 1.f; bc[i] = 0.f;
  }
  const float* dtp = ws + ODT2 + ((size_t)bk * Ll) * 128;
  const float* bsp = ws + OBS2 + ((size_t)bk * Ll) * 16;
  const float* xb = ws + OX1S + (size_t)b * Ll * 128;
  float r_a = 0.f, r_Bs = 0.f;
  {
    int l = c * SCH;
    int sp = spmap(k, l);
    if (t < 128) r_a = dtp[(size_t)l * 128 + t];
    else r_a = xb[(size_t)sp * 128 + (t - 128)];
    if (t < 16) r_Bs = bsp[(size_t)l * 16 + t];
  }
  for (int ll = 0; ll < SCH; ++ll) {
    int buf = ll & 1;
    if (t < 128) dt_s[buf][t] = r_a;
    else x_s[buf][t - 128] = r_a;
    if (t < 16) Bs_s[buf][t] = r_Bs;
    __syncthreads();
    if (ll + 1 < SCH) {
      int l2 = c * SCH + ll + 1;
      int sp2 = spmap(k, l2);
      if (t < 128) r_a = dtp[(size_t)l2 * 128 + t];
      else r_a = xb[(size_t)sp2 * 128 + (t - 128)];
      if (t < 16) r_Bs = bsp[(size_t)l2 * 16 + t];
    }
    float Bv = Bs_s[buf][n];
#pragma unroll
    for (int i = 0; i < 8; ++i) {
      int d = dg * 8 + i;
      float dtv = dt_s[buf][d];
      float a = __expf(dtv * A_r[i]);
      bc[i] = bc[i] * a + dtv * x_s[buf][d] * Bv;
      ap[i] *= a;
    }
  }
  float* csa = ws + OCSA + ((size_t)(bk * SNC + c) * 128) * 16;
  float* csb = ws + OCSB + ((size_t)(bk * SNC + c) * 128) * 16;
#pragma unroll
  for (int i = 0; i < 8; ++i) {
    int d = dg * 8 + i;
    csa[d * 16 + n] = ap[i];
    csb[d * 16 + n] = bc[i];
  }
}

// ============ 7b. scan phase B (register prefetch) ============
__global__ __launch_bounds__(256) void k_scanB(float* __restrict__ ws) {
  int g = blockIdx.x * 256 + threadIdx.x;
  int bk = g >> 11;
  int dn = g & 2047;
  const float* csa = ws + OCSA;
  const float* csb = ws + OCSB;
  float* hst = ws + OHST;
  size_t base = (size_t)bk * SNC * 2048 + dn;
  float h = 0.f;
  float a = csa[base], bq = csb[base];
  for (int c = 0; c < SNC; ++c) {
    float na = 0.f, nb = 0.f;
    if (c + 1 < SNC) {
      size_t idx2 = base + (size_t)(c + 1) * 2048;
      na = csa[idx2]; nb = csb[idx2];
    }
    hst[base + (size_t)c * 2048] = h;
    h = a * h + bq;
    a = na; bq = nb;
  }
}

// ============ 7c. scan phase C (ping-pong, 1 barrier/step) ============
__global__ __launch_bounds__(256) void k_scanC(const float* __restrict__ alog,
    const float* __restrict__ Dp, float* __restrict__ ws) {
  int c = blockIdx.x, bk = blockIdx.y;
  int b = bk >> 2, k = bk & 3;
  int t = threadIdx.x;
  int n = t & 15, dg = t >> 4;
  __shared__ float dt_s[2][128], x_s[2][128], Bs_s[2][16], Cs_s[2][16];
  float A_r[8], h[8], Dv[8];
#pragma unroll
  for (int i = 0; i < 8; ++i) {
    int d = dg * 8 + i;
    A_r[i] = -__expf(alog[(size_t)((k * 128 + d) * 16) + n]);
    h[i] = ws[OHST + ((size_t)(bk * SNC + c) * 128 + d) * 16 + n];
    Dv[i] = Dp[k * 128 + d];
  }
  const float* dtp = ws + ODT2 + ((size_t)bk * Ll) * 128;
  const float* bsp = ws + OBS2 + ((size_t)bk * Ll) * 16;
  const float* csp = ws + OCS2 + ((size_t)bk * Ll) * 16;
  const float* xb = ws + OX1S + (size_t)b * Ll * 128;
  float* yp = ws + OYS2 + ((size_t)bk * Ll) * 128;
  float r_a = 0.f, r_bc = 0.f;
  {
    int l = c * SCH;
    int sp = spmap(k, l);
    if (t < 128) r_a = dtp[(size_t)l * 128 + t];
    else r_a = xb[(size_t)sp * 128 + (t - 128)];
    if (t < 16) r_bc = bsp[(size_t)l * 16 + t];
    else if (t < 32) r_bc = csp[(size_t)l * 16 + (t - 16)];
  }
  for (int ll = 0; ll < SCH; ++ll) {
    int buf = ll & 1;
    if (t < 128) dt_s[buf][t] = r_a;
    else x_s[buf][t - 128] = r_a;
    if (t < 16) Bs_s[buf][t] = r_bc;
    else if (t < 32) Cs_s[buf][t - 16] = r_bc;
    __syncthreads();
    if (ll + 1 < SCH) {
      int l2 = c * SCH + ll + 1;
      int sp2 = spmap(k, l2);
      if (t < 128) r_a = dtp[(size_t)l2 * 128 + t];
      else r_a = xb[(size_t)sp2 * 128 + (t - 128)];
      if (t < 16) r_bc = bsp[(size_t)l2 * 16 + t];
      else if (t < 32) r_bc = csp[(size_t)l2 * 16 + (t - 16)];
    }
    int l = c * SCH + ll;
    float Bv = Bs_s[buf][n], Cv = Cs_s[buf][n];
    float yacc[8];
#pragma unroll
    for (int i = 0; i < 8; ++i) {
      int d = dg * 8 + i;
      float dtv = dt_s[buf][d];
      float a = __expf(dtv * A_r[i]);
      h[i] = h[i] * a + dtv * x_s[buf][d] * Bv;
      yacc[i] = h[i] * Cv;
    }
#pragma unroll
    for (int i = 0; i < 8; ++i) {
      float yv = yacc[i];
      yv += __shfl_xor(yv, 1, 64);
      yv += __shfl_xor(yv, 2, 64);
      yv += __shfl_xor(yv, 4, 64);
      yv += __shfl_xor(yv, 8, 64);
      yacc[i] = yv;
    }
    if (n == 0) {
#pragma unroll
      for (int i = 0; i < 8; ++i) {
        int d = dg * 8 + i;
        yp[(size_t)l * 128 + d] = yacc[i] + Dv[i] * x_s[buf][d];
      }
    }
  }
}

// ============ 8+9+10. comb + LN + gate + x2 + LN + FFN conv1 (fused, 8 tok) ============
__global__ __launch_bounds__(256) void k_combffn1(const float* __restrict__ enc,
    const float* __restrict__ nw, const float* __restrict__ nb,
    const float* __restrict__ snr, const float* __restrict__ ow,
    const float* __restrict__ lw, const float* __restrict__ lb,
    const float* __restrict__ w1, float* __restrict__ ws) {
  int l0 = blockIdx.x * TT, b = blockIdx.y, t = threadIdx.x;
  __shared__ float yr[128][9];
  __shared__ float redm[2][TT], redq[2][TT];
  __shared__ float part[2][TT][64];
  __shared__ float xn_s[64][9];
  int lane = t & 63, wid = (t >> 6) & 1;
  float v[TT], m[TT];
  if (t < 128) {
    int d = t;
    const float* ysb = ws + OYS2;
#pragma unroll
    for (int i = 0; i < TT; ++i) {
      int l = l0 + i;
      int hh = l / 48, wwp = l % 48;
      int lT = wwp * 48 + hh;
      v[i] = ysb[((size_t)(b * 4 + 0) * Ll + l) * 128 + d] +
             ysb[((size_t)(b * 4 + 2) * Ll + (2303 - l)) * 128 + d] +
             ysb[((size_t)(b * 4 + 1) * Ll + lT) * 128 + d] +
             ysb[((size_t)(b * 4 + 3) * Ll + (2303 - lT)) * 128 + d];
    }
    float s[TT];
#pragma unroll
    for (int i = 0; i < TT; ++i) s[i] = v[i];
#pragma unroll
    for (int o = 32; o >= 1; o >>= 1)
#pragma unroll
      for (int i = 0; i < TT; ++i) s[i] += __shfl_xor(s[i], o, 64);
    if (lane == 0) {
#pragma unroll
      for (int i = 0; i < TT; ++i) redm[wid][i] = s[i];
    }
  }
  __syncthreads();
  if (t < 128) {
    float q[TT];
#pragma unroll
    for (int i = 0; i < TT; ++i) {
      m[i] = (redm[0][i] + redm[1][i]) * (1.f / 128.f);
      float dv = v[i] - m[i];
      q[i] = dv * dv;
    }
#pragma unroll
    for (int o = 32; o >= 1; o >>= 1)
#pragma unroll
      for (int i = 0; i < TT; ++i) q[i] += __shfl_xor(q[i], o, 64);
    if (lane == 0) {
#pragma unroll
      for (int i = 0; i < TT; ++i) redq[wid][i] = q[i];
    }
  }
  __syncthreads();
  if (t < 128) {
    int d = t;
    float nwv = nw[d], nbv = nb[d];
#pragma unroll
    for (int i = 0; i < TT; ++i) {
      int l = l0 + i;
      float var = (redq[0][i] + redq[1][i]) * (1.f / 128.f);
      float y = (v[i] - m[i]) * rsqrtf(var + 1e-5f) * nwv + nbv;
      float zv = ws[OZ + ((size_t)(b * Ll + l)) * 128 + d];
      y *= siluf(zv);
      y *= snr[b * Ll + l];
      yr[d][i] = y;
    }
  }
  __syncthreads();
  if (t < 128) {
    int col = t & 63, seg = t >> 6;
    float acc[TT];
#pragma unroll
    for (int i = 0; i < TT; ++i) acc[i] = 0.f;
    const float* ows = ow + (size_t)(seg * 64) * 64 + col;
    for (int c = 0; c < 64; ++c) {
      float w = ows[c * 64];
      const float* yc = &yr[seg * 64 + c][0];
#pragma unroll
      for (int i = 0; i < TT; ++i) acc[i] += yc[i] * w;
    }
#pragma unroll
    for (int i = 0; i < TT; ++i) part[seg][i][col] = acc[i];
  }
  __syncthreads();
  {
    // wave-parallel LN(64): wave wv handles tokens wv*2, wv*2+1
    int wv = t >> 6, col2 = t & 63;
    float lwv = lw[col2], lbv = lb[col2];
#pragma unroll
    for (int i2 = 0; i2 < 2; ++i2) {
      int i = wv * 2 + i2;
      float a = part[0][i][col2] + part[1][i][col2];
      a += enc[(size_t)b * Cc * Ll + (size_t)col2 * Ll + l0 + i];
      ws[OX2 + ((size_t)(b * Ll + l0 + i)) * 64 + col2] = a;
      float s = a;
#pragma unroll
      for (int o = 32; o >= 1; o >>= 1) s += __shfl_xor(s, o, 64);
      float mm = s * (1.f / 64.f);
      float dd2 = a - mm;
      float vs = dd2 * dd2;
#pragma unroll
      for (int o = 32; o >= 1; o >>= 1) vs += __shfl_xor(vs, o, 64);
      xn_s[col2][i] = dd2 * rsqrtf(vs * (1.f / 64.f) + 1e-5f) * lwv + lbv;
    }
  }
  __syncthreads();
  {
    float acc2[TT];
#pragma unroll
    for (int i = 0; i < TT; ++i) acc2[i] = 0.f;
    const float* wp = w1 + (size_t)t * 64;
    for (int c = 0; c < 64; ++c) {
      float w = wp[c];
      const float* xc = &xn_s[c][0];
#pragma unroll
      for (int i = 0; i < TT; ++i) acc2[i] += xc[i] * w;
    }
#pragma unroll
    for (int i = 0; i < TT; ++i)
      ws[OH1A + ((size_t)(b * Ll + l0 + i)) * 256 + t] = geluf(acc2[i]);
  }
}

// ============ 11. FFN depthwise 3x3 + gelu, 8 tokens/block ============
__global__ __launch_bounds__(256) void k_ffndw(const float* __restrict__ dww,
                                               float* __restrict__ ws) {
  int l0 = blockIdx.x * TT, b = blockIdx.y, t = threadIdx.x;
  int h = l0 / 48, w0 = l0 % 48;
  __shared__ float tile[3][10][256];
  for (int idx = t; idx < 7680; idx += 256) {
    int r = idx / 2560, rem = idx % 2560;
    int col = rem >> 8, ch = rem & 255;
    int hh = h + r - 1, wx = w0 + col - 1;
    float v = 0.f;
    if (hh >= 0 && hh < 48 && wx >= 0 && wx < 48)
      v = ws[OH1A + ((size_t)(b * Ll + hh * 48 + wx)) * 256 + ch];
    tile[r][col][ch] = v;
  }
  __syncthreads();
  float dwr[9];
#pragma unroll
  for (int j = 0; j < 9; ++j) dwr[j] = dww[t * 9 + j];
#pragma unroll
  for (int i = 0; i < TT; ++i) {
    float acc = 0.f;
#pragma unroll
    for (int kh = 0; kh < 3; ++kh)
#pragma unroll
      for (int kw = 0; kw < 3; ++kw)
        acc += tile[kh][i + kw][t] * dwr[kh * 3 + kw];
    ws[OH1B + ((size_t)(b * Ll + l0 + i)) * 256 + t] = geluf(acc);
  }
}

// ============ 12. FFN conv2 1x1 + residual + transposed out, 8 tokens/block ============
__global__ __launch_bounds__(256) void k_ffn2(const float* __restrict__ w2,
                                              float* __restrict__ ws,
                                              float* __restrict__ out) {
  int l0 = blockIdx.x * TT, b = blockIdx.y, t = threadIdx.x;
  __shared__ float hr[256][9];
  __shared__ float part[4][TT][64];
  const float* hp = ws + OH1B + ((size_t)(b * Ll + l0)) * 256;
#pragma unroll
  for (int i = 0; i < TT; ++i) hr[t][i] = hp[(size_t)i * 256 + t];
  __syncthreads();
  int col = t & 63, seg = t >> 6;
  {
    float acc[TT];
#pragma unroll
    for (int i = 0; i < TT; ++i) acc[i] = 0.f;
    const float* wp = w2 + (size_t)col * 256 + seg * 64;
    for (int c = 0; c < 64; ++c) {
      float w = wp[c];
      const float* hc = &hr[seg * 64 + c][0];
#pragma unroll
      for (int i = 0; i < TT; ++i) acc[i] += hc[i] * w;
    }
#pragma unroll
    for (int i = 0; i < TT; ++i) part[seg][i][col] = acc[i];
  }
  __syncthreads();
  if (t < 64) {
    float av[TT];
#pragma unroll
    for (int i = 0; i < TT; ++i) {
      float a = part[0][i][t] + part[1][i][t] + part[2][i][t] + part[3][i][t];
      av[i] = a + ws[OX2 + ((size_t)(b * Ll + l0 + i)) * 64 + t];
    }
    float* opx = out + ((size_t)(b * 64 + t)) * 2304 + l0;
    *(float4*)opx = make_float4(av[0], av[1], av[2], av[3]);
    *((float4*)opx + 1) = make_float4(av[4], av[5], av[6], av[7]);
  }
}

extern "C" void kernel_launch(void* const* d_in, const int* in_sizes, int n_in,
                              void* d_out, int out_size, void* d_ws, size_t ws_size,
                              hipStream_t stream) {
  (void)in_sizes; (void)n_in; (void)out_size;
  const float* enc  = (const float*)d_in[0];
  const float* snr  = (const float*)d_in[1];
  const float* wq   = (const float*)d_in[2];
  const float* wk   = (const float*)d_in[3];
  const float* wv   = (const float*)d_in[4];
  const float* fc   = (const float*)d_in[5];
  const float* alnw = (const float*)d_in[6];
  const float* alnb = (const float*)d_in[7];
  const float* ssin = (const float*)d_in[8];
  const float* cw   = (const float*)d_in[9];
  const float* cb   = (const float*)d_in[10];
  const float* xw   = (const float*)d_in[11];
  const float* dtw  = (const float*)d_in[12];
  const float* dtb  = (const float*)d_in[13];
  const float* alog = (const float*)d_in[14];
  const float* Dp   = (const float*)d_in[15];
  const float* nw   = (const float*)d_in[16];
  const float* nb   = (const float*)d_in[17];
  const float* ow   = (const float*)d_in[18];
  const float* flnw = (const float*)d_in[19];
  const float* flnb = (const float*)d_in[20];
  const float* w1   = (const float*)d_in[21];
  const float* dww  = (const float*)d_in[22];
  const float* w2   = (const float*)d_in[23];
  float* ws = (float*)d_ws;
  float* out = (float*)d_out;

  if (ws_size < (size_t)WS_NEED_FLOATS * 4) {
    hipLaunchKernelGGL(k_code, dim3(1), dim3(64), 0, stream, out);
    return;
  }

  hipLaunchKernelGGL(k_qkv, dim3(Ll / TT, Bq), dim3(256), 0, stream, enc, wq, wk, wv, ws);
  hipLaunchKernelGGL(k_vt, dim3(Ll / 64, Bq * NHh), dim3(256), 0, stream, ws);
  hipLaunchKernelGGL(k_attn, dim3(Ll / 64, Bq * NHh, 2), dim3(256), 0, stream, snr, ws);
  hipLaunchKernelGGL(k_oprojxz, dim3(Ll / TT, Bq), dim3(256), 0, stream, enc, fc, alnw, alnb, ssin, ws);
  hipLaunchKernelGGL(k_conv, dim3(Ll / TT, Bq), dim3(256), 0, stream, cw, cb, ws);
  hipLaunchKernelGGL(k_xdbl, dim3(Ll / TT, Bq * 4), dim3(128), 0, stream, xw, dtw, dtb, ws);
  hipLaunchKernelGGL(k_scanA, dim3(SNC, Bq * 4), dim3(256), 0, stream, alog, ws);
  hipLaunchKernelGGL(k_scanB, dim3(64), dim3(256), 0, stream, ws);
  hipLaunchKernelGGL(k_scanC, dim3(SNC, Bq * 4), dim3(256), 0, stream, alog, Dp, ws);
  hipLaunchKernelGGL(k_combffn1, dim3(Ll / TT, Bq), dim3(256), 0, stream, enc, nw, nb, snr, ow, flnw, flnb, w1, ws);
  hipLaunchKernelGGL(k_ffndw, dim3(Ll / TT, Bq), dim3(256), 0, stream, dww, ws);
  hipLaunchKernelGGL(k_ffn2, dim3(Ll / TT, Bq), dim3(256), 0, stream, w2, ws, out);
}

// Round 17
// 414.999 us; speedup vs baseline: 1.0714x; 1.0235x over previous
//
#include <hip/hip_runtime.h>
#include <hip/hip_bf16.h>

#define Bq 2
#define Cc 64
#define Hh 48
#define Ww 48
#define Ll 2304
#define NHh 8
#define DKk 64
#define DVv 128
#define DNn 128
#define NSs 16
#define Rr 4
#define SCH 48
#define SNC 48
#define TT 8      // tokens per block in GEMM-ish kernels
#define TT2 16    // tokens per block in k_oprojxz (MFMA)

// ---- workspace layout (float offsets) ----
#define OQ    0u                 // (B*8, L, 64) Q bf16 (ushort), pre-scaled by 1/8
#define OK_   2359296u           // (B*8, L, 64) K bf16 (ushort)
#define OV    4718592u           // (B*8, L, 128) V fp32 / attn partial-1 bf16 (B,L,1024)
#define OO    9437184u           // attn partial-0 bf16 (B,L,1024)
#define OX1P  14450688u          // (B,L,128)
#define OZ    15040512u          // (B,L,128)
#define OVT   15630336u          // (B*8, 128, L) V^T bf16 (ushort; half region)
#define OLP   (OVT + 2359296u)   // l-partials: 2 x (B*8, L)
#define OFCB  (OVT + 2433024u)   // fc bf16 transposed [64][1024] (32768 floats)
#define OX2   0u                 // (B,L,64)   [ODT2/OQ region, dead after scan]
#define WS_NEED_FLOATS (OVT + 4718592u)
// aliases
#define ODT2  OQ                 // (B*4, L, 128) dt, l-major
#define OYS2  OK_                // (B*4, L, 128) scan y, l-major
#define OX1S  (OV + 1179648u)    // (B,L,128)
#define OBS2  (OV + 1769472u)    // (B*4, L, 16)
#define OCS2  (OV + 2064384u)    // (B*4, L, 16)
#define OCSA  (OV + 2359296u)    // (B*4, SNC, 128, 16)
#define OCSB  (OV + 3145728u)    // (B*4, SNC, 128, 16)
#define OHST  (OV + 3932160u)    // (B*4, SNC, 128, 16)
#define OH1A  OO                 // (B,L,256)
#define OH1B  (OO + 1179648u)    // (B,L,256)

typedef short short8v __attribute__((ext_vector_type(8)));
typedef short short4v __attribute__((ext_vector_type(4)));
typedef float f32x4 __attribute__((ext_vector_type(4)));
typedef unsigned short ushort_t;

__device__ __forceinline__ float geluf(float x) {
  return 0.5f * x * (1.0f + erff(x * 0.70710678118654752f));
}
__device__ __forceinline__ float siluf(float x) {
  return x / (1.0f + __expf(-x));
}
__device__ __forceinline__ float softplusf(float x) {
  return fmaxf(x, 0.0f) + log1pf(__expf(-fabsf(x)));
}
__device__ __forceinline__ int spmap(int k, int l) {
  if (k == 0) return l;
  if (k == 1) return (l % 48) * 48 + l / 48;
  if (k == 2) return 2303 - l;
  int l2 = 2303 - l; return (l2 % 48) * 48 + l2 / 48;
}
__device__ __forceinline__ short f2bf(float f) {
  unsigned u = __float_as_uint(f);
  unsigned r = (u + 0x7FFFu + ((u >> 16) & 1u)) >> 16;
  return (short)r;
}
__device__ __forceinline__ float bfu2f(ushort_t u) {
  return __uint_as_float(((unsigned)u) << 16);
}

__global__ void k_code(float* out) { if (threadIdx.x == 0) out[0] = 25000.f; }

// ============ 1. QKV projection, 8 tokens/block (V fp32, coalesced) ============
__global__ __launch_bounds__(256) void k_qkv(const float* __restrict__ enc,
    const float* __restrict__ wq, const float* __restrict__ wk,
    const float* __restrict__ wv, float* __restrict__ ws) {
  int l0 = blockIdx.x * TT; int b = blockIdx.y;
  int t = threadIdx.x;
  __shared__ float xs[64][12];
  {
    int idx = t, c = idx >> 3, i = idx & 7;
    xs[c][i] = enc[(size_t)b * Cc * Ll + (size_t)c * Ll + l0 + i];
    idx = t + 256; c = idx >> 3; i = idx & 7;
    xs[c][i] = enc[(size_t)b * Cc * Ll + (size_t)c * Ll + l0 + i];
  }
  __syncthreads();
  ushort_t* qb = (ushort_t*)(ws + OQ);
  ushort_t* kb = (ushort_t*)(ws + OK_);
  float* v = ws + OV;
#pragma unroll
  for (int g = 0; g < 6; ++g) {
    int j = t + g * 256;
    float acc[TT];
#pragma unroll
    for (int i = 0; i < TT; ++i) acc[i] = 0.f;
    const float* wp; int col, stride;
    if (j < 512) { wp = wq + j; stride = 512; col = j; }
    else if (j < 1024) { wp = wk + (j - 512); stride = 512; col = j - 512; }
    else { wp = wv + (j - 1024); stride = 1024; col = j - 1024; }
    for (int c = 0; c < 64; ++c) {
      float w = wp[(size_t)c * stride];
      const float4* xc = (const float4*)&xs[c][0];
      float4 x0 = xc[0], x1 = xc[1];
      acc[0] += x0.x * w; acc[1] += x0.y * w;
      acc[2] += x0.z * w; acc[3] += x0.w * w;
      acc[4] += x1.x * w; acc[5] += x1.y * w;
      acc[6] += x1.z * w; acc[7] += x1.w * w;
    }
    if (j < 512) {
#pragma unroll
      for (int i = 0; i < TT; ++i)
        qb[((size_t)(b * 8 + (col >> 6)) * Ll + l0 + i) * 64 + (col & 63)] =
            (ushort_t)f2bf(acc[i] * 0.125f);
    } else if (j < 1024) {
#pragma unroll
      for (int i = 0; i < TT; ++i)
        kb[((size_t)(b * 8 + (col >> 6)) * Ll + l0 + i) * 64 + (col & 63)] =
            (ushort_t)f2bf(acc[i]);
    } else {
#pragma unroll
      for (int i = 0; i < TT; ++i)
        v[((size_t)(b * 8 + (col >> 7)) * Ll + l0 + i) * 128 + (col & 127)] = acc[i];
    }
  }
}

// ============ 1b. transpose V -> vt bf16 (bh, dv, L) ============
__global__ __launch_bounds__(256) void k_vt(float* __restrict__ ws) {
  int bh = blockIdx.y;
  int l0 = blockIdx.x * 64;
  int t = threadIdx.x;
  __shared__ float tile[128][65];
  const float* vp = ws + OV + ((size_t)bh * Ll + l0) * 128;
  for (int i = t; i < 64 * 32; i += 256) {
    int l = i >> 5, dv4 = (i & 31) * 4;
    float4 a = *(const float4*)(vp + (size_t)l * 128 + dv4);
    tile[dv4][l] = a.x; tile[dv4 + 1][l] = a.y;
    tile[dv4 + 2][l] = a.z; tile[dv4 + 3][l] = a.w;
  }
  __syncthreads();
  ushort_t* vt = (ushort_t*)(ws + OVT) + (size_t)bh * 128 * Ll + l0;
  for (int i = t; i < 128 * 16; i += 256) {
    int dv = i >> 4, l4 = (i & 15) * 4;
    short4v a;
    a[0] = f2bf(tile[dv][l4]); a[1] = f2bf(tile[dv][l4 + 1]);
    a[2] = f2bf(tile[dv][l4 + 2]); a[3] = f2bf(tile[dv][l4 + 3]);
    *(short4v*)(vt + (size_t)dv * Ll + l4) = a;
  }
}

// ============ 1c. fc -> bf16 transposed [col][k] ============
__global__ __launch_bounds__(256) void k_fcbf(const float* __restrict__ fc,
                                              float* __restrict__ ws) {
  int col = blockIdx.x;
  int t = threadIdx.x;
  ushort_t* dst = (ushort_t*)(ws + OFCB) + (size_t)col * 1024;
  for (int k = t; k < 1024; k += 256)
    dst[k] = (ushort_t)f2bf(fc[(size_t)k * 64 + col]);
}

// ============ 2. flash attention (bf16 MFMA, fixed-max softmax, 2-way K-split) ============
#define NKT2 18
#define LSK 72
__global__ __launch_bounds__(256) void k_attn(const float* __restrict__ snr,
                                              float* __restrict__ ws) {
  int bh = blockIdx.y; int b = bh >> 3; int hd = bh & 7;
  int q0 = blockIdx.x * 64;
  int ks = blockIdx.z;
  int kbase = ks * (Ll / 2);
  int t = threadIdx.x;
  int w = t >> 6, lane = t & 63;
  int m16 = lane & 15, quad = lane >> 4;

  __shared__ __align__(16) ushort_t Ks[64 * LSK];
  __shared__ __align__(16) ushort_t Vs[128 * LSK];
  __shared__ __align__(16) ushort_t Ps[4 * 16 * LSK];
  __shared__ float sfac_s[64];

  const ushort_t* qbf = (const ushort_t*)(ws + OQ) + (size_t)bh * Ll * 64;
  const ushort_t* kbf = (const ushort_t*)(ws + OK_) + (size_t)bh * Ll * 64;
  const ushort_t* vtb = (const ushort_t*)(ws + OVT) + (size_t)bh * 128 * Ll;

  short8v qa[2];
  {
    const ushort_t* qrp = qbf + (size_t)(q0 + w * 16 + m16) * 64 + quad * 8;
    qa[0] = *(const short8v*)qrp;
    qa[1] = *(const short8v*)(qrp + 32);
  }
  int sk_key = t >> 2, sk_d0 = (t & 3) * 16;
  int sv_dv = t >> 1, sv_k0 = (t & 1) * 32;

  short8v kreg[2], vreg[4];
  float snr_reg = 0.f;
  {
    const ushort_t* ksrc = kbf + (size_t)(kbase + sk_key) * 64 + sk_d0;
    kreg[0] = *(const short8v*)ksrc;
    kreg[1] = *(const short8v*)(ksrc + 8);
    const ushort_t* vsrc = vtb + (size_t)sv_dv * Ll + kbase + sv_k0;
#pragma unroll
    for (int i = 0; i < 4; ++i) vreg[i] = *(const short8v*)(vsrc + i * 8);
    if (t < 64) snr_reg = snr[b * Ll + kbase + t];
  }

  f32x4 oacc[8];
#pragma unroll
  for (int i = 0; i < 8; ++i) oacc[i] = (f32x4)0.f;
  float l_r[4] = {0.f, 0.f, 0.f, 0.f};

  for (int kt = 0; kt < NKT2; ++kt) {
    __syncthreads();
    *(short8v*)&Ks[sk_key * LSK + sk_d0] = kreg[0];
    *(short8v*)&Ks[sk_key * LSK + sk_d0 + 8] = kreg[1];
#pragma unroll
    for (int i = 0; i < 4; ++i)
      *(short8v*)&Vs[sv_dv * LSK + sv_k0 + i * 8] = vreg[i];
    if (t < 64) sfac_s[t] = snr_reg + 1e-4f;
    __syncthreads();
    if (kt + 1 < NKT2) {
      int k0n = kbase + (kt + 1) * 64;
      const ushort_t* ksrc = kbf + (size_t)(k0n + sk_key) * 64 + sk_d0;
      kreg[0] = *(const short8v*)ksrc;
      kreg[1] = *(const short8v*)(ksrc + 8);
      const ushort_t* vsrc = vtb + (size_t)sv_dv * Ll + k0n + sv_k0;
#pragma unroll
      for (int i = 0; i < 4; ++i) vreg[i] = *(const short8v*)(vsrc + i * 8);
      if (t < 64) snr_reg = snr[b * Ll + k0n + t];
    }

    f32x4 sac[4];
#pragma unroll
    for (int n = 0; n < 4; ++n) {
      int key = n * 16 + m16;
      short8v kb0 = *(const short8v*)&Ks[key * LSK + quad * 8];
      short8v kb1 = *(const short8v*)&Ks[key * LSK + 32 + quad * 8];
      f32x4 acc = (f32x4)0.f;
      acc = __builtin_amdgcn_mfma_f32_16x16x32_bf16(qa[0], kb0, acc, 0, 0, 0);
      acc = __builtin_amdgcn_mfma_f32_16x16x32_bf16(qa[1], kb1, acc, 0, 0, 0);
      sac[n] = acc;
    }
    float sf[4];
#pragma unroll
    for (int n = 0; n < 4; ++n) sf[n] = sfac_s[n * 16 + m16];
    ushort_t* pw = &Ps[w * 16 * LSK];
#pragma unroll
    for (int r = 0; r < 4; ++r) {
#pragma unroll
      for (int n = 0; n < 4; ++n) {
        float p = __expf(sac[n][r]) * sf[n];
        l_r[r] += p;
        pw[(quad * 4 + r) * LSK + n * 16 + m16] = (ushort_t)f2bf(p);
      }
    }
    short8v pb0 = *(const short8v*)&pw[m16 * LSK + quad * 8];
    short8v pb1 = *(const short8v*)&pw[m16 * LSK + 32 + quad * 8];
#pragma unroll
    for (int dt_ = 0; dt_ < 8; ++dt_) {
      const ushort_t* vrow = &Vs[(dt_ * 16 + m16) * LSK];
      short8v va0 = *(const short8v*)&vrow[quad * 8];
      short8v va1 = *(const short8v*)&vrow[32 + quad * 8];
      f32x4 o = oacc[dt_];
      o = __builtin_amdgcn_mfma_f32_16x16x32_bf16(va0, pb0, o, 0, 0, 0);
      o = __builtin_amdgcn_mfma_f32_16x16x32_bf16(va1, pb1, o, 0, 0, 0);
      oacc[dt_] = o;
    }
  }
#pragma unroll
  for (int r = 0; r < 4; ++r) {
    float lv = l_r[r];
    lv += __shfl_xor(lv, 1, 64);
    lv += __shfl_xor(lv, 2, 64);
    lv += __shfl_xor(lv, 4, 64);
    lv += __shfl_xor(lv, 8, 64);
    l_r[r] = lv;
  }
  if (m16 == 0) {
    float* lp = ws + OLP + (size_t)ks * (Bq * NHh * Ll) + (size_t)bh * Ll;
#pragma unroll
    for (int r = 0; r < 4; ++r) lp[q0 + w * 16 + quad * 4 + r] = l_r[r];
  }
  // raw (unnormalized) partial O as bf16
  ushort_t* opb = (ushort_t*)(ws + (ks ? OV : OO));
  ushort_t* op = opb + ((size_t)(b * Ll + q0 + w * 16 + m16)) * 1024 + hd * 128;
#pragma unroll
  for (int dt_ = 0; dt_ < 8; ++dt_) {
    short4v o4;
#pragma unroll
    for (int r = 0; r < 4; ++r) o4[r] = f2bf(oacc[dt_][r]);
    *(short4v*)&op[dt_ * 16 + quad * 4] = o4;
  }
}

// ============ 3+4. combine + o@fc (MFMA) + residual + LN + xz, 16 tok/block ============
__global__ __launch_bounds__(256) void k_oprojxz(const float* __restrict__ enc,
    const float* __restrict__ lnw, const float* __restrict__ lnb,
    const float* __restrict__ ssin, float* __restrict__ ws) {
  int l0 = blockIdx.x * TT2, b = blockIdx.y, t = threadIdx.x;
  int w = t >> 6, lane = t & 63, m16 = lane & 15, quad = lane >> 4;
  __shared__ __align__(16) ushort_t obf[16][1040];   // [token][k]
  __shared__ float linv_s[8][16];
  __shared__ float part[16][68];
  __shared__ float xh_s[64][17];
  if (t < 128) {
    int hd = t >> 4, i = t & 15;
    float l1 = ws[OLP + (size_t)(b * 8 + hd) * Ll + l0 + i];
    float l2 = ws[OLP + (size_t)(Bq * NHh * Ll) + (size_t)(b * 8 + hd) * Ll + l0 + i];
    linv_s[hd][i] = 1.f / (l1 + l2);
  }
  __syncthreads();
  const ushort_t* p0 = (const ushort_t*)(ws + OO) + (size_t)(b * Ll + l0) * 1024;
  const ushort_t* p1 = (const ushort_t*)(ws + OV) + (size_t)(b * Ll + l0) * 1024;
#pragma unroll
  for (int g = 0; g < 8; ++g) {
    int v = t + g * 256;          // short8v index
    int tok = v >> 7, k0 = (v & 127) * 8;
    short8v a = *(const short8v*)(p0 + (size_t)tok * 1024 + k0);
    short8v bb = *(const short8v*)(p1 + (size_t)tok * 1024 + k0);
    float li = linv_s[k0 >> 7][tok];
    short8v o;
#pragma unroll
    for (int j = 0; j < 8; ++j)
      o[j] = f2bf((bfu2f((ushort_t)a[j]) + bfu2f((ushort_t)bb[j])) * li);
    *(short8v*)&obf[tok][k0] = o;
  }
  __syncthreads();
  // MFMA: C[token][col], wave w handles cols w*16..w*16+15
  f32x4 cacc = (f32x4)0.f;
  const ushort_t* fcb = (const ushort_t*)(ws + OFCB) +
                        (size_t)(w * 16 + m16) * 1024 + quad * 8;
#pragma unroll
  for (int kb = 0; kb < 32; ++kb) {
    short8v a = *(const short8v*)&obf[m16][kb * 32 + quad * 8];
    short8v bf = *(const short8v*)(fcb + kb * 32);
    cacc = __builtin_amdgcn_mfma_f32_16x16x32_bf16(a, bf, cacc, 0, 0, 0);
  }
#pragma unroll
  for (int r = 0; r < 4; ++r) part[quad * 4 + r][w * 16 + m16] = cacc[r];
  __syncthreads();
  // residual + LN(64): wave w handles tokens w*4..w*4+3, lane = channel
  {
    int col = lane;
    float lw = lnw[col], lb = lnb[col];
#pragma unroll
    for (int i2 = 0; i2 < 4; ++i2) {
      int i = w * 4 + i2;
      float a = part[i][col] + enc[(size_t)b * Cc * Ll + (size_t)col * Ll + l0 + i];
      float s = a;
#pragma unroll
      for (int o = 32; o >= 1; o >>= 1) s += __shfl_xor(s, o, 64);
      float m = s * (1.f / 64.f);
      float dd = a - m;
      float vs = dd * dd;
#pragma unroll
      for (int o = 32; o >= 1; o >>= 1) vs += __shfl_xor(vs, o, 64);
      xh_s[col][i] = dd * rsqrtf(vs * (1.f / 64.f) + 1e-5f) * lw + lb;
    }
  }
  __syncthreads();
  // xz projection (64 -> 256)
  {
    float acc2[TT2];
#pragma unroll
    for (int i = 0; i < TT2; ++i) acc2[i] = 0.f;
    for (int c = 0; c < 64; ++c) {
      float wv_ = ssin[c * 256 + t];
      const float* xc = &xh_s[c][0];
#pragma unroll
      for (int i = 0; i < TT2; ++i) acc2[i] += xc[i] * wv_;
    }
    if (t < 128) {
#pragma unroll
      for (int i = 0; i < TT2; ++i)
        ws[OX1P + ((size_t)(b * Ll + l0 + i)) * 128 + t] = acc2[i];
    } else {
#pragma unroll
      for (int i = 0; i < TT2; ++i)
        ws[OZ + ((size_t)(b * Ll + l0 + i)) * 128 + (t - 128)] = acc2[i];
    }
  }
}

// ============ 5. depthwise conv3x3 + bias + silu, 8 tokens/block ============
__global__ __launch_bounds__(256) void k_conv(const float* __restrict__ cw,
    const float* __restrict__ cb, float* __restrict__ ws) {
  int l0 = blockIdx.x * TT, b = blockIdx.y, t = threadIdx.x;
  int h = l0 / 48, w0 = l0 % 48;
  __shared__ float tile[3][10][128];
  for (int idx = t; idx < 3840; idx += 256) {
    int r = idx / 1280, rem = idx % 1280;
    int col = rem >> 7, d = rem & 127;
    int hh = h + r - 1, wx = w0 + col - 1;
    float v = 0.f;
    if (hh >= 0 && hh < 48 && wx >= 0 && wx < 48)
      v = ws[OX1P + ((size_t)(b * Ll + hh * 48 + wx)) * 128 + d];
    tile[r][col][d] = v;
  }
  __syncthreads();
  int d = t & 127, half = t >> 7;
  float cwr[9];
#pragma unroll
  for (int j = 0; j < 9; ++j) cwr[j] = cw[d * 9 + j];
  float cbv = cb[d];
#pragma unroll
  for (int j = 0; j < 4; ++j) {
    int i = half * 4 + j;
    float acc = cbv;
#pragma unroll
    for (int kh = 0; kh < 3; ++kh)
#pragma unroll
      for (int kw = 0; kw < 3; ++kw)
        acc += tile[kh][i + kw][d] * cwr[kh * 3 + kw];
    ws[OX1S + ((size_t)(b * Ll + l0 + i)) * 128 + d] = siluf(acc);
  }
}

// ============ 6. x_dbl projections, 8 tokens/block ============
__global__ __launch_bounds__(128) void k_xdbl(const float* __restrict__ xw,
    const float* __restrict__ dtw, const float* __restrict__ dtb,
    float* __restrict__ ws) {
  int l0 = blockIdx.x * TT;
  int by = blockIdx.y; int b = by >> 2; int k = by & 3;
  int t = threadIdx.x;
  __shared__ float xv[128][9];
  __shared__ float pr[36][TT];
#pragma unroll
  for (int i = 0; i < TT; ++i) {
    int sp = spmap(k, l0 + i);
    xv[t][i] = ws[OX1S + ((size_t)(b * Ll) + sp) * 128 + t];
  }
  __syncthreads();
  if (t < 36) {
    float s[TT];
#pragma unroll
    for (int i = 0; i < TT; ++i) s[i] = 0.f;
    const float* wp = xw + (size_t)(k * 36 + t) * 128;
    for (int d = 0; d < 128; ++d) {
      float w = wp[d];
      const float* xc = &xv[d][0];
#pragma unroll
      for (int i = 0; i < TT; ++i) s[i] += xc[i] * w;
    }
#pragma unroll
    for (int i = 0; i < TT; ++i) pr[t][i] = s[i];
  }
  __syncthreads();
  {
    int d = t;
    const float* wp = dtw + (size_t)(k * 128 + d) * 4;
    float w0 = wp[0], w1 = wp[1], w2 = wp[2], w3 = wp[3];
    float bb = dtb[k * 128 + d];
#pragma unroll
    for (int i = 0; i < TT; ++i) {
      float v = pr[0][i] * w0 + pr[1][i] * w1 + pr[2][i] * w2 + pr[3][i] * w3 + bb;
      ws[ODT2 + ((size_t)(by * Ll + l0 + i)) * 128 + d] = softplusf(v);
    }
  }
  if (t < 16) {
#pragma unroll
    for (int i = 0; i < TT; ++i)
      ws[OBS2 + ((size_t)(by * Ll + l0 + i)) * 16 + t] = pr[4 + t][i];
  } else if (t < 32) {
#pragma unroll
    for (int i = 0; i < TT; ++i)
      ws[OCS2 + ((size_t)(by * Ll + l0 + i)) * 16 + (t - 16)] = pr[20 + (t - 16)][i];
  }
}

// ============ 7a. scan phase A (ping-pong, 1 barrier/step) ============
__global__ __launch_bounds__(256) void k_scanA(const float* __restrict__ alog,
                                               float* __restrict__ ws) {
  int c = blockIdx.x;
  int bk = blockIdx.y;
  int b = bk >> 2, k = bk & 3;
  int t = threadIdx.x;
  int n = t & 15, dg = t >> 4;
  __shared__ float dt_s[2][128], x_s[2][128], Bs_s[2][16];
  float A_r[8], ap[8], bc[8];
#pragma unroll
  for (int i = 0; i < 8; ++i) {
    int d = dg * 8 + i;
    A_r[i] = -__expf(alog[(size_t)((k * 128 + d) * 16) + n]);
    ap[i] = 1.f; bc[i] = 0.f;
  }
  const float* dtp = ws + ODT2 + ((size_t)bk * Ll) * 128;
  const float* bsp = ws + OBS2 + ((size_t)bk * Ll) * 16;
  const float* xb = ws + OX1S + (size_t)b * Ll * 128;
  float r_a = 0.f, r_Bs = 0.f;
  {
    int l = c * SCH;
    int sp = spmap(k, l);
    if (t < 128) r_a = dtp[(size_t)l * 128 + t];
    else r_a = xb[(size_t)sp * 128 + (t - 128)];
    if (t < 16) r_Bs = bsp[(size_t)l * 16 + t];
  }
  for (int ll = 0; ll < SCH; ++ll) {
    int buf = ll & 1;
    if (t < 128) dt_s[buf][t] = r_a;
    else x_s[buf][t - 128] = r_a;
    if (t < 16) Bs_s[buf][t] = r_Bs;
    __syncthreads();
    if (ll + 1 < SCH) {
      int l2 = c * SCH + ll + 1;
      int sp2 = spmap(k, l2);
      if (t < 128) r_a = dtp[(size_t)l2 * 128 + t];
      else r_a = xb[(size_t)sp2 * 128 + (t - 128)];
      if (t < 16) r_Bs = bsp[(size_t)l2 * 16 + t];
    }
    float Bv = Bs_s[buf][n];
#pragma unroll
    for (int i = 0; i < 8; ++i) {
      int d = dg * 8 + i;
      float dtv = dt_s[buf][d];
      float a = __expf(dtv * A_r[i]);
      bc[i] = bc[i] * a + dtv * x_s[buf][d] * Bv;
      ap[i] *= a;
    }
  }
  float* csa = ws + OCSA + ((size_t)(bk * SNC + c) * 128) * 16;
  float* csb = ws + OCSB + ((size_t)(bk * SNC + c) * 128) * 16;
#pragma unroll
  for (int i = 0; i < 8; ++i) {
    int d = dg * 8 + i;
    csa[d * 16 + n] = ap[i];
    csb[d * 16 + n] = bc[i];
  }
}

// ============ 7b. scan phase B (register prefetch) ============
__global__ __launch_bounds__(256) void k_scanB(float* __restrict__ ws) {
  int g = blockIdx.x * 256 + threadIdx.x;
  int bk = g >> 11;
  int dn = g & 2047;
  const float* csa = ws + OCSA;
  const float* csb = ws + OCSB;
  float* hst = ws + OHST;
  size_t base = (size_t)bk * SNC * 2048 + dn;
  float h = 0.f;
  float a = csa[base], bq = csb[base];
  for (int c = 0; c < SNC; ++c) {
    float na = 0.f, nb = 0.f;
    if (c + 1 < SNC) {
      size_t idx2 = base + (size_t)(c + 1) * 2048;
      na = csa[idx2]; nb = csb[idx2];
    }
    hst[base + (size_t)c * 2048] = h;
    h = a * h + bq;
    a = na; bq = nb;
  }
}

// ============ 7c. scan phase C (ping-pong, 1 barrier/step) ============
__global__ __launch_bounds__(256) void k_scanC(const float* __restrict__ alog,
    const float* __restrict__ Dp, float* __restrict__ ws) {
  int c = blockIdx.x, bk = blockIdx.y;
  int b = bk >> 2, k = bk & 3;
  int t = threadIdx.x;
  int n = t & 15, dg = t >> 4;
  __shared__ float dt_s[2][128], x_s[2][128], Bs_s[2][16], Cs_s[2][16];
  float A_r[8], h[8], Dv[8];
#pragma unroll
  for (int i = 0; i < 8; ++i) {
    int d = dg * 8 + i;
    A_r[i] = -__expf(alog[(size_t)((k * 128 + d) * 16) + n]);
    h[i] = ws[OHST + ((size_t)(bk * SNC + c) * 128 + d) * 16 + n];
    Dv[i] = Dp[k * 128 + d];
  }
  const float* dtp = ws + ODT2 + ((size_t)bk * Ll) * 128;
  const float* bsp = ws + OBS2 + ((size_t)bk * Ll) * 16;
  const float* csp = ws + OCS2 + ((size_t)bk * Ll) * 16;
  const float* xb = ws + OX1S + (size_t)b * Ll * 128;
  float* yp = ws + OYS2 + ((size_t)bk * Ll) * 128;
  float r_a = 0.f, r_bc = 0.f;
  {
    int l = c * SCH;
    int sp = spmap(k, l);
    if (t < 128) r_a = dtp[(size_t)l * 128 + t];
    else r_a = xb[(size_t)sp * 128 + (t - 128)];
    if (t < 16) r_bc = bsp[(size_t)l * 16 + t];
    else if (t < 32) r_bc = csp[(size_t)l * 16 + (t - 16)];
  }
  for (int ll = 0; ll < SCH; ++ll) {
    int buf = ll & 1;
    if (t < 128) dt_s[buf][t] = r_a;
    else x_s[buf][t - 128] = r_a;
    if (t < 16) Bs_s[buf][t] = r_bc;
    else if (t < 32) Cs_s[buf][t - 16] = r_bc;
    __syncthreads();
    if (ll + 1 < SCH) {
      int l2 = c * SCH + ll + 1;
      int sp2 = spmap(k, l2);
      if (t < 128) r_a = dtp[(size_t)l2 * 128 + t];
      else r_a = xb[(size_t)sp2 * 128 + (t - 128)];
      if (t < 16) r_bc = bsp[(size_t)l2 * 16 + t];
      else if (t < 32) r_bc = csp[(size_t)l2 * 16 + (t - 16)];
    }
    int l = c * SCH + ll;
    float Bv = Bs_s[buf][n], Cv = Cs_s[buf][n];
    float yacc[8];
#pragma unroll
    for (int i = 0; i < 8; ++i) {
      int d = dg * 8 + i;
      float dtv = dt_s[buf][d];
      float a = __expf(dtv * A_r[i]);
      h[i] = h[i] * a + dtv * x_s[buf][d] * Bv;
      yacc[i] = h[i] * Cv;
    }
#pragma unroll
    for (int i = 0; i < 8; ++i) {
      float yv = yacc[i];
      yv += __shfl_xor(yv, 1, 64);
      yv += __shfl_xor(yv, 2, 64);
      yv += __shfl_xor(yv, 4, 64);
      yv += __shfl_xor(yv, 8, 64);
      yacc[i] = yv;
    }
    if (n == 0) {
#pragma unroll
      for (int i = 0; i < 8; ++i) {
        int d = dg * 8 + i;
        yp[(size_t)l * 128 + d] = yacc[i] + Dv[i] * x_s[buf][d];
      }
    }
  }
}

// ============ 8+9+10. comb + LN + gate + x2 + LN + FFN conv1 (fused, 8 tok) ============
__global__ __launch_bounds__(256) void k_combffn1(const float* __restrict__ enc,
    const float* __restrict__ nw, const float* __restrict__ nb,
    const float* __restrict__ snr, const float* __restrict__ ow,
    const float* __restrict__ lw, const float* __restrict__ lb,
    const float* __restrict__ w1, float* __restrict__ ws) {
  int l0 = blockIdx.x * TT, b = blockIdx.y, t = threadIdx.x;
  __shared__ float yr[128][9];
  __shared__ float redm[2][TT], redq[2][TT];
  __shared__ float part[2][TT][64];
  __shared__ float xn_s[64][9];
  int lane = t & 63, wid = (t >> 6) & 1;
  float v[TT], m[TT];
  if (t < 128) {
    int d = t;
    const float* ysb = ws + OYS2;
#pragma unroll
    for (int i = 0; i < TT; ++i) {
      int l = l0 + i;
      int hh = l / 48, wwp = l % 48;
      int lT = wwp * 48 + hh;
      v[i] = ysb[((size_t)(b * 4 + 0) * Ll + l) * 128 + d] +
             ysb[((size_t)(b * 4 + 2) * Ll + (2303 - l)) * 128 + d] +
             ysb[((size_t)(b * 4 + 1) * Ll + lT) * 128 + d] +
             ysb[((size_t)(b * 4 + 3) * Ll + (2303 - lT)) * 128 + d];
    }
    float s[TT];
#pragma unroll
    for (int i = 0; i < TT; ++i) s[i] = v[i];
#pragma unroll
    for (int o = 32; o >= 1; o >>= 1)
#pragma unroll
      for (int i = 0; i < TT; ++i) s[i] += __shfl_xor(s[i], o, 64);
    if (lane == 0) {
#pragma unroll
      for (int i = 0; i < TT; ++i) redm[wid][i] = s[i];
    }
  }
  __syncthreads();
  if (t < 128) {
    float q[TT];
#pragma unroll
    for (int i = 0; i < TT; ++i) {
      m[i] = (redm[0][i] + redm[1][i]) * (1.f / 128.f);
      float dv = v[i] - m[i];
      q[i] = dv * dv;
    }
#pragma unroll
    for (int o = 32; o >= 1; o >>= 1)
#pragma unroll
      for (int i = 0; i < TT; ++i) q[i] += __shfl_xor(q[i], o, 64);
    if (lane == 0) {
#pragma unroll
      for (int i = 0; i < TT; ++i) redq[wid][i] = q[i];
    }
  }
  __syncthreads();
  if (t < 128) {
    int d = t;
    float nwv = nw[d], nbv = nb[d];
#pragma unroll
    for (int i = 0; i < TT; ++i) {
      int l = l0 + i;
      float var = (redq[0][i] + redq[1][i]) * (1.f / 128.f);
      float y = (v[i] - m[i]) * rsqrtf(var + 1e-5f) * nwv + nbv;
      float zv = ws[OZ + ((size_t)(b * Ll + l)) * 128 + d];
      y *= siluf(zv);
      y *= snr[b * Ll + l];
      yr[d][i] = y;
    }
  }
  __syncthreads();
  if (t < 128) {
    int col = t & 63, seg = t >> 6;
    float acc[TT];
#pragma unroll
    for (int i = 0; i < TT; ++i) acc[i] = 0.f;
    const float* ows = ow + (size_t)(seg * 64) * 64 + col;
    for (int c = 0; c < 64; ++c) {
      float w = ows[c * 64];
      const float* yc = &yr[seg * 64 + c][0];
#pragma unroll
      for (int i = 0; i < TT; ++i) acc[i] += yc[i] * w;
    }
#pragma unroll
    for (int i = 0; i < TT; ++i) part[seg][i][col] = acc[i];
  }
  __syncthreads();
  {
    int wv = t >> 6, col2 = t & 63;
    float lwv = lw[col2], lbv = lb[col2];
#pragma unroll
    for (int i2 = 0; i2 < 2; ++i2) {
      int i = wv * 2 + i2;
      float a = part[0][i][col2] + part[1][i][col2];
      a += enc[(size_t)b * Cc * Ll + (size_t)col2 * Ll + l0 + i];
      ws[OX2 + ((size_t)(b * Ll + l0 + i)) * 64 + col2] = a;
      float s = a;
#pragma unroll
      for (int o = 32; o >= 1; o >>= 1) s += __shfl_xor(s, o, 64);
      float mm = s * (1.f / 64.f);
      float dd2 = a - mm;
      float vs = dd2 * dd2;
#pragma unroll
      for (int o = 32; o >= 1; o >>= 1) vs += __shfl_xor(vs, o, 64);
      xn_s[col2][i] = dd2 * rsqrtf(vs * (1.f / 64.f) + 1e-5f) * lwv + lbv;
    }
  }
  __syncthreads();
  {
    float acc2[TT];
#pragma unroll
    for (int i = 0; i < TT; ++i) acc2[i] = 0.f;
    const float* wp = w1 + (size_t)t * 64;
    for (int c = 0; c < 64; ++c) {
      float w = wp[c];
      const float* xc = &xn_s[c][0];
#pragma unroll
      for (int i = 0; i < TT; ++i) acc2[i] += xc[i] * w;
    }
#pragma unroll
    for (int i = 0; i < TT; ++i)
      ws[OH1A + ((size_t)(b * Ll + l0 + i)) * 256 + t] = geluf(acc2[i]);
  }
}

// ============ 11. FFN depthwise 3x3 + gelu, 8 tokens/block ============
__global__ __launch_bounds__(256) void k_ffndw(const float* __restrict__ dww,
                                               float* __restrict__ ws) {
  int l0 = blockIdx.x * TT, b = blockIdx.y, t = threadIdx.x;
  int h = l0 / 48, w0 = l0 % 48;
  __shared__ float tile[3][10][256];
  for (int idx = t; idx < 7680; idx += 256) {
    int r = idx / 2560, rem = idx % 2560;
    int col = rem >> 8, ch = rem & 255;
    int hh = h + r - 1, wx = w0 + col - 1;
    float v = 0.f;
    if (hh >= 0 && hh < 48 && wx >= 0 && wx < 48)
      v = ws[OH1A + ((size_t)(b * Ll + hh * 48 + wx)) * 256 + ch];
    tile[r][col][ch] = v;
  }
  __syncthreads();
  float dwr[9];
#pragma unroll
  for (int j = 0; j < 9; ++j) dwr[j] = dww[t * 9 + j];
#pragma unroll
  for (int i = 0; i < TT; ++i) {
    float acc = 0.f;
#pragma unroll
    for (int kh = 0; kh < 3; ++kh)
#pragma unroll
      for (int kw = 0; kw < 3; ++kw)
        acc += tile[kh][i + kw][t] * dwr[kh * 3 + kw];
    ws[OH1B + ((size_t)(b * Ll + l0 + i)) * 256 + t] = geluf(acc);
  }
}

// ============ 12. FFN conv2 1x1 + residual + transposed out, 8 tokens/block ============
__global__ __launch_bounds__(256) void k_ffn2(const float* __restrict__ w2,
                                              float* __restrict__ ws,
                                              float* __restrict__ out) {
  int l0 = blockIdx.x * TT, b = blockIdx.y, t = threadIdx.x;
  __shared__ float hr[256][9];
  __shared__ float part[4][TT][64];
  const float* hp = ws + OH1B + ((size_t)(b * Ll + l0)) * 256;
#pragma unroll
  for (int i = 0; i < TT; ++i) hr[t][i] = hp[(size_t)i * 256 + t];
  __syncthreads();
  int col = t & 63, seg = t >> 6;
  {
    float acc[TT];
#pragma unroll
    for (int i = 0; i < TT; ++i) acc[i] = 0.f;
    const float* wp = w2 + (size_t)col * 256 + seg * 64;
    for (int c = 0; c < 64; ++c) {
      float w = wp[c];
      const float* hc = &hr[seg * 64 + c][0];
#pragma unroll
      for (int i = 0; i < TT; ++i) acc[i] += hc[i] * w;
    }
#pragma unroll
    for (int i = 0; i < TT; ++i) part[seg][i][col] = acc[i];
  }
  __syncthreads();
  if (t < 64) {
    float av[TT];
#pragma unroll
    for (int i = 0; i < TT; ++i) {
      float a = part[0][i][t] + part[1][i][t] + part[2][i][t] + part[3][i][t];
      av[i] = a + ws[OX2 + ((size_t)(b * Ll + l0 + i)) * 64 + t];
    }
    float* opx = out + ((size_t)(b * 64 + t)) * 2304 + l0;
    *(float4*)opx = make_float4(av[0], av[1], av[2], av[3]);
    *((float4*)opx + 1) = make_float4(av[4], av[5], av[6], av[7]);
  }
}

extern "C" void kernel_launch(void* const* d_in, const int* in_sizes, int n_in,
                              void* d_out, int out_size, void* d_ws, size_t ws_size,
                              hipStream_t stream) {
  (void)in_sizes; (void)n_in; (void)out_size;
  const float* enc  = (const float*)d_in[0];
  const float* snr  = (const float*)d_in[1];
  const float* wq   = (const float*)d_in[2];
  const float* wk   = (const float*)d_in[3];
  const float* wv   = (const float*)d_in[4];
  const float* fc   = (const float*)d_in[5];
  const float* alnw = (const float*)d_in[6];
  const float* alnb = (const float*)d_in[7];
  const float* ssin = (const float*)d_in[8];
  const float* cw   = (const float*)d_in[9];
  const float* cb   = (const float*)d_in[10];
  const float* xw   = (const float*)d_in[11];
  const float* dtw  = (const float*)d_in[12];
  const float* dtb  = (const float*)d_in[13];
  const float* alog = (const float*)d_in[14];
  const float* Dp   = (const float*)d_in[15];
  const float* nw   = (const float*)d_in[16];
  const float* nb   = (const float*)d_in[17];
  const float* ow   = (const float*)d_in[18];
  const float* flnw = (const float*)d_in[19];
  const float* flnb = (const float*)d_in[20];
  const float* w1   = (const float*)d_in[21];
  const float* dww  = (const float*)d_in[22];
  const float* w2   = (const float*)d_in[23];
  float* ws = (float*)d_ws;
  float* out = (float*)d_out;

  if (ws_size < (size_t)WS_NEED_FLOATS * 4) {
    hipLaunchKernelGGL(k_code, dim3(1), dim3(64), 0, stream, out);
    return;
  }

  hipLaunchKernelGGL(k_qkv, dim3(Ll / TT, Bq), dim3(256), 0, stream, enc, wq, wk, wv, ws);
  hipLaunchKernelGGL(k_vt, dim3(Ll / 64, Bq * NHh), dim3(256), 0, stream, ws);
  hipLaunchKernelGGL(k_fcbf, dim3(64), dim3(256), 0, stream, fc, ws);
  hipLaunchKernelGGL(k_attn, dim3(Ll / 64, Bq * NHh, 2), dim3(256), 0, stream, snr, ws);
  hipLaunchKernelGGL(k_oprojxz, dim3(Ll / TT2, Bq), dim3(256), 0, stream, enc, alnw, alnb, ssin, ws);
  hipLaunchKernelGGL(k_conv, dim3(Ll / TT, Bq), dim3(256), 0, stream, cw, cb, ws);
  hipLaunchKernelGGL(k_xdbl, dim3(Ll / TT, Bq * 4), dim3(128), 0, stream, xw, dtw, dtb, ws);
  hipLaunchKernelGGL(k_scanA, dim3(SNC, Bq * 4), dim3(256), 0, stream, alog, ws);
  hipLaunchKernelGGL(k_scanB, dim3(64), dim3(256), 0, stream, ws);
  hipLaunchKernelGGL(k_scanC, dim3(SNC, Bq * 4), dim3(256), 0, stream, alog, Dp, ws);
  hipLaunchKernelGGL(k_combffn1, dim3(Ll / TT, Bq), dim3(256), 0, stream, enc, nw, nb, snr, ow, flnw, flnb, w1, ws);
  hipLaunchKernelGGL(k_ffndw, dim3(Ll / TT, Bq), dim3(256), 0, stream, dww, ws);
  hipLaunchKernelGGL(k_ffn2, dim3(Ll / TT, Bq), dim3(256), 0, stream, w2, ws, out);
}

// Round 18
// 395.818 us; speedup vs baseline: 1.1233x; 1.0485x over previous
//
#include <hip/hip_runtime.h>
#include <hip/hip_bf16.h>

#define Bq 2
#define Cc 64
#define Hh 48
#define Ww 48
#define Ll 2304
#define NHh 8
#define DKk 64
#define DVv 128
#define DNn 128
#define NSs 16
#define Rr 4
#define SCH 48
#define SNC 48
#define TT 8      // tokens per block in GEMM-ish kernels
#define TT2 16    // tokens per block in k_oprojxz / k_qkv (MFMA)

// ---- workspace layout (float offsets) ----
#define OQ    0u                 // (B*8, L, 64) Q bf16 (ushort), pre-scaled by 1/8
#define OK_   2359296u           // (B*8, L, 64) K bf16 (ushort)
#define OV    4718592u           // (B*8, L, 128) V fp32 / attn partial-1 bf16 (B,L,1024)
#define OO    9437184u           // attn partial-0 bf16 (B,L,1024)
#define OX1P  14450688u          // (B,L,128)
#define OZ    15040512u          // (B,L,128)
#define OVT   15630336u          // (B*8, 128, L) V^T bf16 (ushort; half region)
#define OLP   (OVT + 2359296u)   // l-partials: 2 x (B*8, L)
#define OFCB  (OVT + 2433024u)   // fc bf16 transposed [64][1024] (32768 floats)
#define OWQKV (OFCB + 32768u)    // wqkv bf16 transposed [2048][64] (65536 floats)
#define OX2   0u                 // (B,L,64)   [ODT2/OQ region, dead after scan]
#define WS_NEED_FLOATS (OVT + 4718592u)
// aliases
#define ODT2  OQ                 // (B*4, L, 128) dt, l-major
#define OYS2  OK_                // (B*4, L, 128) scan y, l-major
#define OX1S  (OV + 1179648u)    // (B,L,128)
#define OBS2  (OV + 1769472u)    // (B*4, L, 16)
#define OCS2  (OV + 2064384u)    // (B*4, L, 16)
#define OCSA  (OV + 2359296u)    // (B*4, SNC, 128, 16)
#define OCSB  (OV + 3145728u)    // (B*4, SNC, 128, 16)
#define OHST  (OV + 3932160u)    // (B*4, SNC, 128, 16)
#define OH1A  OO                 // (B,L,256)

typedef short short8v __attribute__((ext_vector_type(8)));
typedef short short4v __attribute__((ext_vector_type(4)));
typedef float f32x4 __attribute__((ext_vector_type(4)));
typedef unsigned short ushort_t;

__device__ __forceinline__ float geluf(float x) {
  return 0.5f * x * (1.0f + erff(x * 0.70710678118654752f));
}
__device__ __forceinline__ float siluf(float x) {
  return x / (1.0f + __expf(-x));
}
__device__ __forceinline__ float softplusf(float x) {
  return fmaxf(x, 0.0f) + log1pf(__expf(-fabsf(x)));
}
__device__ __forceinline__ int spmap(int k, int l) {
  if (k == 0) return l;
  if (k == 1) return (l % 48) * 48 + l / 48;
  if (k == 2) return 2303 - l;
  int l2 = 2303 - l; return (l2 % 48) * 48 + l2 / 48;
}
__device__ __forceinline__ short f2bf(float f) {
  unsigned u = __float_as_uint(f);
  unsigned r = (u + 0x7FFFu + ((u >> 16) & 1u)) >> 16;
  return (short)r;
}
__device__ __forceinline__ float bfu2f(ushort_t u) {
  return __uint_as_float(((unsigned)u) << 16);
}

__global__ void k_code(float* out) { if (threadIdx.x == 0) out[0] = 25000.f; }

// ============ 0. prep: wq/wk/wv -> bf16 transposed [col][c] ============
__global__ __launch_bounds__(256) void k_prep(const float* __restrict__ wq,
    const float* __restrict__ wk, const float* __restrict__ wv,
    float* __restrict__ ws) {
  int col0 = blockIdx.x * 16;
  int t = threadIdx.x;
  ushort_t* dst = (ushort_t*)(ws + OWQKV);
#pragma unroll
  for (int g = 0; g < 4; ++g) {
    int e = t + g * 256;
    int c = e >> 4, lcol = e & 15;
    int col = col0 + lcol;
    float v;
    if (col < 512) v = wq[(size_t)c * 512 + col];
    else if (col < 1024) v = wk[(size_t)c * 512 + (col - 512)];
    else v = wv[(size_t)c * 1024 + (col - 1024)];
    dst[(size_t)col * 64 + c] = (ushort_t)f2bf(v);
  }
}

// ============ 1. QKV projection (MFMA), 16 tokens/block, col-quarter split ============
__global__ __launch_bounds__(256) void k_qkv(const float* __restrict__ enc,
                                             float* __restrict__ ws) {
  int l0 = blockIdx.x * TT2; int b = blockIdx.y; int z = blockIdx.z;
  int t = threadIdx.x;
  int w = t >> 6, lane = t & 63, m16 = lane & 15, quad = lane >> 4;
  __shared__ __align__(16) ushort_t xs[16][72];   // [token][c]
  {
    int e = t * 4;
    int c = e >> 4, tok0 = e & 15;
    float4 a = *(const float4*)(enc + (size_t)b * Cc * Ll + (size_t)c * Ll + l0 + tok0);
    xs[tok0][c] = (ushort_t)f2bf(a.x);
    xs[tok0 + 1][c] = (ushort_t)f2bf(a.y);
    xs[tok0 + 2][c] = (ushort_t)f2bf(a.z);
    xs[tok0 + 3][c] = (ushort_t)f2bf(a.w);
  }
  __syncthreads();
  short8v qa0 = *(const short8v*)&xs[m16][quad * 8];
  short8v qa1 = *(const short8v*)&xs[m16][32 + quad * 8];
  ushort_t* qb = (ushort_t*)(ws + OQ);
  ushort_t* kb = (ushort_t*)(ws + OK_);
  float* v = ws + OV;
  const ushort_t* wb = (const ushort_t*)(ws + OWQKV);
#pragma unroll
  for (int it = 0; it < 8; ++it) {
    int j0 = z * 512 + it * 64 + w * 16;
    const ushort_t* bp = wb + (size_t)(j0 + m16) * 64 + quad * 8;
    short8v b0 = *(const short8v*)bp;
    short8v b1 = *(const short8v*)(bp + 32);
    f32x4 cacc = (f32x4)0.f;
    cacc = __builtin_amdgcn_mfma_f32_16x16x32_bf16(qa0, b0, cacc, 0, 0, 0);
    cacc = __builtin_amdgcn_mfma_f32_16x16x32_bf16(qa1, b1, cacc, 0, 0, 0);
    int col = j0 + m16;
    if (col < 512) {
#pragma unroll
      for (int r = 0; r < 4; ++r) {
        int tok = quad * 4 + r;
        qb[((size_t)(b * 8 + (col >> 6)) * Ll + l0 + tok) * 64 + (col & 63)] =
            (ushort_t)f2bf(cacc[r] * 0.125f);
      }
    } else if (col < 1024) {
      int cc = col - 512;
#pragma unroll
      for (int r = 0; r < 4; ++r) {
        int tok = quad * 4 + r;
        kb[((size_t)(b * 8 + (cc >> 6)) * Ll + l0 + tok) * 64 + (cc & 63)] =
            (ushort_t)f2bf(cacc[r]);
      }
    } else {
      int cc = col - 1024;
#pragma unroll
      for (int r = 0; r < 4; ++r) {
        int tok = quad * 4 + r;
        v[((size_t)(b * 8 + (cc >> 7)) * Ll + l0 + tok) * 128 + (cc & 127)] = cacc[r];
      }
    }
  }
}

// ============ 1b. transpose V -> vt bf16 (bh, dv, L)  [+ fc transpose slice] ============
__global__ __launch_bounds__(256) void k_vt(const float* __restrict__ fc,
                                            float* __restrict__ ws) {
  int t = threadIdx.x;
  if (blockIdx.y == 16) {
    int col0 = blockIdx.x * 2;
    if (col0 < 64) {
      ushort_t* dst = (ushort_t*)(ws + OFCB);
#pragma unroll
      for (int g = 0; g < 8; ++g) {
        int e = t + g * 256;
        int lc = e >> 10, k = e & 1023;
        dst[(size_t)(col0 + lc) * 1024 + k] =
            (ushort_t)f2bf(fc[(size_t)k * 64 + col0 + lc]);
      }
    }
    return;
  }
  int bh = blockIdx.y;
  int l0 = blockIdx.x * 64;
  __shared__ float tile[128][65];
  const float* vp = ws + OV + ((size_t)bh * Ll + l0) * 128;
  for (int i = t; i < 64 * 32; i += 256) {
    int l = i >> 5, dv4 = (i & 31) * 4;
    float4 a = *(const float4*)(vp + (size_t)l * 128 + dv4);
    tile[dv4][l] = a.x; tile[dv4 + 1][l] = a.y;
    tile[dv4 + 2][l] = a.z; tile[dv4 + 3][l] = a.w;
  }
  __syncthreads();
  ushort_t* vt = (ushort_t*)(ws + OVT) + (size_t)bh * 128 * Ll + l0;
  for (int i = t; i < 128 * 16; i += 256) {
    int dv = i >> 4, l4 = (i & 15) * 4;
    short4v a;
    a[0] = f2bf(tile[dv][l4]); a[1] = f2bf(tile[dv][l4 + 1]);
    a[2] = f2bf(tile[dv][l4 + 2]); a[3] = f2bf(tile[dv][l4 + 3]);
    *(short4v*)(vt + (size_t)dv * Ll + l4) = a;
  }
}

// ============ 2. flash attention (bf16 MFMA, fixed-max softmax, 2-way K-split) ============
#define NKT2 18
#define LSK 72
__global__ __launch_bounds__(256) void k_attn(const float* __restrict__ snr,
                                              float* __restrict__ ws) {
  int bh = blockIdx.y; int b = bh >> 3; int hd = bh & 7;
  int q0 = blockIdx.x * 64;
  int ks = blockIdx.z;
  int kbase = ks * (Ll / 2);
  int t = threadIdx.x;
  int w = t >> 6, lane = t & 63;
  int m16 = lane & 15, quad = lane >> 4;

  __shared__ __align__(16) ushort_t Ks[64 * LSK];
  __shared__ __align__(16) ushort_t Vs[128 * LSK];
  __shared__ __align__(16) ushort_t Ps[4 * 16 * LSK];
  __shared__ float sfac_s[64];

  const ushort_t* qbf = (const ushort_t*)(ws + OQ) + (size_t)bh * Ll * 64;
  const ushort_t* kbf = (const ushort_t*)(ws + OK_) + (size_t)bh * Ll * 64;
  const ushort_t* vtb = (const ushort_t*)(ws + OVT) + (size_t)bh * 128 * Ll;

  short8v qa[2];
  {
    const ushort_t* qrp = qbf + (size_t)(q0 + w * 16 + m16) * 64 + quad * 8;
    qa[0] = *(const short8v*)qrp;
    qa[1] = *(const short8v*)(qrp + 32);
  }
  int sk_key = t >> 2, sk_d0 = (t & 3) * 16;
  int sv_dv = t >> 1, sv_k0 = (t & 1) * 32;

  short8v kreg[2], vreg[4];
  float snr_reg = 0.f;
  {
    const ushort_t* ksrc = kbf + (size_t)(kbase + sk_key) * 64 + sk_d0;
    kreg[0] = *(const short8v*)ksrc;
    kreg[1] = *(const short8v*)(ksrc + 8);
    const ushort_t* vsrc = vtb + (size_t)sv_dv * Ll + kbase + sv_k0;
#pragma unroll
    for (int i = 0; i < 4; ++i) vreg[i] = *(const short8v*)(vsrc + i * 8);
    if (t < 64) snr_reg = snr[b * Ll + kbase + t];
  }

  f32x4 oacc[8];
#pragma unroll
  for (int i = 0; i < 8; ++i) oacc[i] = (f32x4)0.f;
  float l_r[4] = {0.f, 0.f, 0.f, 0.f};

  for (int kt = 0; kt < NKT2; ++kt) {
    __syncthreads();
    *(short8v*)&Ks[sk_key * LSK + sk_d0] = kreg[0];
    *(short8v*)&Ks[sk_key * LSK + sk_d0 + 8] = kreg[1];
#pragma unroll
    for (int i = 0; i < 4; ++i)
      *(short8v*)&Vs[sv_dv * LSK + sv_k0 + i * 8] = vreg[i];
    if (t < 64) sfac_s[t] = snr_reg + 1e-4f;
    __syncthreads();
    if (kt + 1 < NKT2) {
      int k0n = kbase + (kt + 1) * 64;
      const ushort_t* ksrc = kbf + (size_t)(k0n + sk_key) * 64 + sk_d0;
      kreg[0] = *(const short8v*)ksrc;
      kreg[1] = *(const short8v*)(ksrc + 8);
      const ushort_t* vsrc = vtb + (size_t)sv_dv * Ll + k0n + sv_k0;
#pragma unroll
      for (int i = 0; i < 4; ++i) vreg[i] = *(const short8v*)(vsrc + i * 8);
      if (t < 64) snr_reg = snr[b * Ll + k0n + t];
    }

    f32x4 sac[4];
#pragma unroll
    for (int n = 0; n < 4; ++n) {
      int key = n * 16 + m16;
      short8v kb0 = *(const short8v*)&Ks[key * LSK + quad * 8];
      short8v kb1 = *(const short8v*)&Ks[key * LSK + 32 + quad * 8];
      f32x4 acc = (f32x4)0.f;
      acc = __builtin_amdgcn_mfma_f32_16x16x32_bf16(qa[0], kb0, acc, 0, 0, 0);
      acc = __builtin_amdgcn_mfma_f32_16x16x32_bf16(qa[1], kb1, acc, 0, 0, 0);
      sac[n] = acc;
    }
    float sf[4];
#pragma unroll
    for (int n = 0; n < 4; ++n) sf[n] = sfac_s[n * 16 + m16];
    ushort_t* pw = &Ps[w * 16 * LSK];
#pragma unroll
    for (int r = 0; r < 4; ++r) {
#pragma unroll
      for (int n = 0; n < 4; ++n) {
        float p = __expf(sac[n][r]) * sf[n];
        l_r[r] += p;
        pw[(quad * 4 + r) * LSK + n * 16 + m16] = (ushort_t)f2bf(p);
      }
    }
    short8v pb0 = *(const short8v*)&pw[m16 * LSK + quad * 8];
    short8v pb1 = *(const short8v*)&pw[m16 * LSK + 32 + quad * 8];
#pragma unroll
    for (int dt_ = 0; dt_ < 8; ++dt_) {
      const ushort_t* vrow = &Vs[(dt_ * 16 + m16) * LSK];
      short8v va0 = *(const short8v*)&vrow[quad * 8];
      short8v va1 = *(const short8v*)&vrow[32 + quad * 8];
      f32x4 o = oacc[dt_];
      o = __builtin_amdgcn_mfma_f32_16x16x32_bf16(va0, pb0, o, 0, 0, 0);
      o = __builtin_amdgcn_mfma_f32_16x16x32_bf16(va1, pb1, o, 0, 0, 0);
      oacc[dt_] = o;
    }
  }
#pragma unroll
  for (int r = 0; r < 4; ++r) {
    float lv = l_r[r];
    lv += __shfl_xor(lv, 1, 64);
    lv += __shfl_xor(lv, 2, 64);
    lv += __shfl_xor(lv, 4, 64);
    lv += __shfl_xor(lv, 8, 64);
    l_r[r] = lv;
  }
  if (m16 == 0) {
    float* lp = ws + OLP + (size_t)ks * (Bq * NHh * Ll) + (size_t)bh * Ll;
#pragma unroll
    for (int r = 0; r < 4; ++r) lp[q0 + w * 16 + quad * 4 + r] = l_r[r];
  }
  ushort_t* opb = (ushort_t*)(ws + (ks ? OV : OO));
  ushort_t* op = opb + ((size_t)(b * Ll + q0 + w * 16 + m16)) * 1024 + hd * 128;
#pragma unroll
  for (int dt_ = 0; dt_ < 8; ++dt_) {
    short4v o4;
#pragma unroll
    for (int r = 0; r < 4; ++r) o4[r] = f2bf(oacc[dt_][r]);
    *(short4v*)&op[dt_ * 16 + quad * 4] = o4;
  }
}

// ============ 3+4. combine + o@fc (MFMA) + residual + LN + xz, 16 tok/block ============
__global__ __launch_bounds__(256) void k_oprojxz(const float* __restrict__ enc,
    const float* __restrict__ lnw, const float* __restrict__ lnb,
    const float* __restrict__ ssin, float* __restrict__ ws) {
  int l0 = blockIdx.x * TT2, b = blockIdx.y, t = threadIdx.x;
  int w = t >> 6, lane = t & 63, m16 = lane & 15, quad = lane >> 4;
  __shared__ __align__(16) ushort_t obf[16][1040];
  __shared__ float linv_s[8][16];
  __shared__ float part[16][68];
  __shared__ float xh_s[64][17];
  if (t < 128) {
    int hd = t >> 4, i = t & 15;
    float l1 = ws[OLP + (size_t)(b * 8 + hd) * Ll + l0 + i];
    float l2 = ws[OLP + (size_t)(Bq * NHh * Ll) + (size_t)(b * 8 + hd) * Ll + l0 + i];
    linv_s[hd][i] = 1.f / (l1 + l2);
  }
  __syncthreads();
  const ushort_t* p0 = (const ushort_t*)(ws + OO) + (size_t)(b * Ll + l0) * 1024;
  const ushort_t* p1 = (const ushort_t*)(ws + OV) + (size_t)(b * Ll + l0) * 1024;
#pragma unroll
  for (int g = 0; g < 8; ++g) {
    int v = t + g * 256;
    int tok = v >> 7, k0 = (v & 127) * 8;
    short8v a = *(const short8v*)(p0 + (size_t)tok * 1024 + k0);
    short8v bb = *(const short8v*)(p1 + (size_t)tok * 1024 + k0);
    float li = linv_s[k0 >> 7][tok];
    short8v o;
#pragma unroll
    for (int j = 0; j < 8; ++j)
      o[j] = f2bf((bfu2f((ushort_t)a[j]) + bfu2f((ushort_t)bb[j])) * li);
    *(short8v*)&obf[tok][k0] = o;
  }
  __syncthreads();
  f32x4 cacc = (f32x4)0.f;
  const ushort_t* fcb = (const ushort_t*)(ws + OFCB) +
                        (size_t)(w * 16 + m16) * 1024 + quad * 8;
#pragma unroll
  for (int kb = 0; kb < 32; ++kb) {
    short8v a = *(const short8v*)&obf[m16][kb * 32 + quad * 8];
    short8v bf = *(const short8v*)(fcb + kb * 32);
    cacc = __builtin_amdgcn_mfma_f32_16x16x32_bf16(a, bf, cacc, 0, 0, 0);
  }
#pragma unroll
  for (int r = 0; r < 4; ++r) part[quad * 4 + r][w * 16 + m16] = cacc[r];
  __syncthreads();
  {
    int col = lane;
    float lw = lnw[col], lb = lnb[col];
#pragma unroll
    for (int i2 = 0; i2 < 4; ++i2) {
      int i = w * 4 + i2;
      float a = part[i][col] + enc[(size_t)b * Cc * Ll + (size_t)col * Ll + l0 + i];
      float s = a;
#pragma unroll
      for (int o = 32; o >= 1; o >>= 1) s += __shfl_xor(s, o, 64);
      float m = s * (1.f / 64.f);
      float dd = a - m;
      float vs = dd * dd;
#pragma unroll
      for (int o = 32; o >= 1; o >>= 1) vs += __shfl_xor(vs, o, 64);
      xh_s[col][i] = dd * rsqrtf(vs * (1.f / 64.f) + 1e-5f) * lw + lb;
    }
  }
  __syncthreads();
  {
    float acc2[TT2];
#pragma unroll
    for (int i = 0; i < TT2; ++i) acc2[i] = 0.f;
    for (int c = 0; c < 64; ++c) {
      float wv_ = ssin[c * 256 + t];
      const float* xc = &xh_s[c][0];
#pragma unroll
      for (int i = 0; i < TT2; ++i) acc2[i] += xc[i] * wv_;
    }
    if (t < 128) {
#pragma unroll
      for (int i = 0; i < TT2; ++i)
        ws[OX1P + ((size_t)(b * Ll + l0 + i)) * 128 + t] = acc2[i];
    } else {
#pragma unroll
      for (int i = 0; i < TT2; ++i)
        ws[OZ + ((size_t)(b * Ll + l0 + i)) * 128 + (t - 128)] = acc2[i];
    }
  }
}

// ============ 5. depthwise conv3x3 + bias + silu, 8 tokens/block ============
__global__ __launch_bounds__(256) void k_conv(const float* __restrict__ cw,
    const float* __restrict__ cb, float* __restrict__ ws) {
  int l0 = blockIdx.x * TT, b = blockIdx.y, t = threadIdx.x;
  int h = l0 / 48, w0 = l0 % 48;
  __shared__ float tile[3][10][128];
  for (int idx = t; idx < 3840; idx += 256) {
    int r = idx / 1280, rem = idx % 1280;
    int col = rem >> 7, d = rem & 127;
    int hh = h + r - 1, wx = w0 + col - 1;
    float v = 0.f;
    if (hh >= 0 && hh < 48 && wx >= 0 && wx < 48)
      v = ws[OX1P + ((size_t)(b * Ll + hh * 48 + wx)) * 128 + d];
    tile[r][col][d] = v;
  }
  __syncthreads();
  int d = t & 127, half = t >> 7;
  float cwr[9];
#pragma unroll
  for (int j = 0; j < 9; ++j) cwr[j] = cw[d * 9 + j];
  float cbv = cb[d];
#pragma unroll
  for (int j = 0; j < 4; ++j) {
    int i = half * 4 + j;
    float acc = cbv;
#pragma unroll
    for (int kh = 0; kh < 3; ++kh)
#pragma unroll
      for (int kw = 0; kw < 3; ++kw)
        acc += tile[kh][i + kw][d] * cwr[kh * 3 + kw];
    ws[OX1S + ((size_t)(b * Ll + l0 + i)) * 128 + d] = siluf(acc);
  }
}

// ============ 6. x_dbl projections, 8 tokens/block ============
__global__ __launch_bounds__(128) void k_xdbl(const float* __restrict__ xw,
    const float* __restrict__ dtw, const float* __restrict__ dtb,
    float* __restrict__ ws) {
  int l0 = blockIdx.x * TT;
  int by = blockIdx.y; int b = by >> 2; int k = by & 3;
  int t = threadIdx.x;
  __shared__ float xv[128][9];
  __shared__ float pr[36][TT];
#pragma unroll
  for (int i = 0; i < TT; ++i) {
    int sp = spmap(k, l0 + i);
    xv[t][i] = ws[OX1S + ((size_t)(b * Ll) + sp) * 128 + t];
  }
  __syncthreads();
  if (t < 36) {
    float s[TT];
#pragma unroll
    for (int i = 0; i < TT; ++i) s[i] = 0.f;
    const float* wp = xw + (size_t)(k * 36 + t) * 128;
    for (int d = 0; d < 128; ++d) {
      float w = wp[d];
      const float* xc = &xv[d][0];
#pragma unroll
      for (int i = 0; i < TT; ++i) s[i] += xc[i] * w;
    }
#pragma unroll
    for (int i = 0; i < TT; ++i) pr[t][i] = s[i];
  }
  __syncthreads();
  {
    int d = t;
    const float* wp = dtw + (size_t)(k * 128 + d) * 4;
    float w0 = wp[0], w1 = wp[1], w2 = wp[2], w3 = wp[3];
    float bb = dtb[k * 128 + d];
#pragma unroll
    for (int i = 0; i < TT; ++i) {
      float v = pr[0][i] * w0 + pr[1][i] * w1 + pr[2][i] * w2 + pr[3][i] * w3 + bb;
      ws[ODT2 + ((size_t)(by * Ll + l0 + i)) * 128 + d] = softplusf(v);
    }
  }
  if (t < 16) {
#pragma unroll
    for (int i = 0; i < TT; ++i)
      ws[OBS2 + ((size_t)(by * Ll + l0 + i)) * 16 + t] = pr[4 + t][i];
  } else if (t < 32) {
#pragma unroll
    for (int i = 0; i < TT; ++i)
      ws[OCS2 + ((size_t)(by * Ll + l0 + i)) * 16 + (t - 16)] = pr[20 + (t - 16)][i];
  }
}

// ============ 7a. scan phase A (ping-pong, 1 barrier/step) ============
__global__ __launch_bounds__(256) void k_scanA(const float* __restrict__ alog,
                                               float* __restrict__ ws) {
  int c = blockIdx.x;
  int bk = blockIdx.y;
  int b = bk >> 2, k = bk & 3;
  int t = threadIdx.x;
  int n = t & 15, dg = t >> 4;
  __shared__ float dt_s[2][128], x_s[2][128], Bs_s[2][16];
  float A_r[8], ap[8], bc[8];
#pragma unroll
  for (int i = 0; i < 8; ++i) {
    int d = dg * 8 + i;
    A_r[i] = -__expf(alog[(size_t)((k * 128 + d) * 16) + n]);
    ap[i] = 1.f; bc[i] = 0.f;
  }
  const float* dtp = ws + ODT2 + ((size_t)bk * Ll) * 128;
  const float* bsp = ws + OBS2 + ((size_t)bk * Ll) * 16;
  const float* xb = ws + OX1S + (size_t)b * Ll * 128;
  float r_a = 0.f, r_Bs = 0.f;
  {
    int l = c * SCH;
    int sp = spmap(k, l);
    if (t < 128) r_a = dtp[(size_t)l * 128 + t];
    else r_a = xb[(size_t)sp * 128 + (t - 128)];
    if (t < 16) r_Bs = bsp[(size_t)l * 16 + t];
  }
  for (int ll = 0; ll < SCH; ++ll) {
    int buf = ll & 1;
    if (t < 128) dt_s[buf][t] = r_a;
    else x_s[buf][t - 128] = r_a;
    if (t < 16) Bs_s[buf][t] = r_Bs;
    __syncthreads();
    if (ll + 1 < SCH) {
      int l2 = c * SCH + ll + 1;
      int sp2 = spmap(k, l2);
      if (t < 128) r_a = dtp[(size_t)l2 * 128 + t];
      else r_a = xb[(size_t)sp2 * 128 + (t - 128)];
      if (t < 16) r_Bs = bsp[(size_t)l2 * 16 + t];
    }
    float Bv = Bs_s[buf][n];
#pragma unroll
    for (int i = 0; i < 8; ++i) {
      int d = dg * 8 + i;
      float dtv = dt_s[buf][d];
      float a = __expf(dtv * A_r[i]);
      bc[i] = bc[i] * a + dtv * x_s[buf][d] * Bv;
      ap[i] *= a;
    }
  }
  float* csa = ws + OCSA + ((size_t)(bk * SNC + c) * 128) * 16;
  float* csb = ws + OCSB + ((size_t)(bk * SNC + c) * 128) * 16;
#pragma unroll
  for (int i = 0; i < 8; ++i) {
    int d = dg * 8 + i;
    csa[d * 16 + n] = ap[i];
    csb[d * 16 + n] = bc[i];
  }
}

// ============ 7b. scan phase B (register prefetch) ============
__global__ __launch_bounds__(256) void k_scanB(float* __restrict__ ws) {
  int g = blockIdx.x * 256 + threadIdx.x;
  int bk = g >> 11;
  int dn = g & 2047;
  const float* csa = ws + OCSA;
  const float* csb = ws + OCSB;
  float* hst = ws + OHST;
  size_t base = (size_t)bk * SNC * 2048 + dn;
  float h = 0.f;
  float a = csa[base], bq = csb[base];
  for (int c = 0; c < SNC; ++c) {
    float na = 0.f, nb = 0.f;
    if (c + 1 < SNC) {
      size_t idx2 = base + (size_t)(c + 1) * 2048;
      na = csa[idx2]; nb = csb[idx2];
    }
    hst[base + (size_t)c * 2048] = h;
    h = a * h + bq;
    a = na; bq = nb;
  }
}

// ============ 7c. scan phase C (ping-pong, 1 barrier/step) ============
__global__ __launch_bounds__(256) void k_scanC(const float* __restrict__ alog,
    const float* __restrict__ Dp, float* __restrict__ ws) {
  int c = blockIdx.x, bk = blockIdx.y;
  int b = bk >> 2, k = bk & 3;
  int t = threadIdx.x;
  int n = t & 15, dg = t >> 4;
  __shared__ float dt_s[2][128], x_s[2][128], Bs_s[2][16], Cs_s[2][16];
  float A_r[8], h[8], Dv[8];
#pragma unroll
  for (int i = 0; i < 8; ++i) {
    int d = dg * 8 + i;
    A_r[i] = -__expf(alog[(size_t)((k * 128 + d) * 16) + n]);
    h[i] = ws[OHST + ((size_t)(bk * SNC + c) * 128 + d) * 16 + n];
    Dv[i] = Dp[k * 128 + d];
  }
  const float* dtp = ws + ODT2 + ((size_t)bk * Ll) * 128;
  const float* bsp = ws + OBS2 + ((size_t)bk * Ll) * 16;
  const float* csp = ws + OCS2 + ((size_t)bk * Ll) * 16;
  const float* xb = ws + OX1S + (size_t)b * Ll * 128;
  float* yp = ws + OYS2 + ((size_t)bk * Ll) * 128;
  float r_a = 0.f, r_bc = 0.f;
  {
    int l = c * SCH;
    int sp = spmap(k, l);
    if (t < 128) r_a = dtp[(size_t)l * 128 + t];
    else r_a = xb[(size_t)sp * 128 + (t - 128)];
    if (t < 16) r_bc = bsp[(size_t)l * 16 + t];
    else if (t < 32) r_bc = csp[(size_t)l * 16 + (t - 16)];
  }
  for (int ll = 0; ll < SCH; ++ll) {
    int buf = ll & 1;
    if (t < 128) dt_s[buf][t] = r_a;
    else x_s[buf][t - 128] = r_a;
    if (t < 16) Bs_s[buf][t] = r_bc;
    else if (t < 32) Cs_s[buf][t - 16] = r_bc;
    __syncthreads();
    if (ll + 1 < SCH) {
      int l2 = c * SCH + ll + 1;
      int sp2 = spmap(k, l2);
      if (t < 128) r_a = dtp[(size_t)l2 * 128 + t];
      else r_a = xb[(size_t)sp2 * 128 + (t - 128)];
      if (t < 16) r_bc = bsp[(size_t)l2 * 16 + t];
      else if (t < 32) r_bc = csp[(size_t)l2 * 16 + (t - 16)];
    }
    int l = c * SCH + ll;
    float Bv = Bs_s[buf][n], Cv = Cs_s[buf][n];
    float yacc[8];
#pragma unroll
    for (int i = 0; i < 8; ++i) {
      int d = dg * 8 + i;
      float dtv = dt_s[buf][d];
      float a = __expf(dtv * A_r[i]);
      h[i] = h[i] * a + dtv * x_s[buf][d] * Bv;
      yacc[i] = h[i] * Cv;
    }
#pragma unroll
    for (int i = 0; i < 8; ++i) {
      float yv = yacc[i];
      yv += __shfl_xor(yv, 1, 64);
      yv += __shfl_xor(yv, 2, 64);
      yv += __shfl_xor(yv, 4, 64);
      yv += __shfl_xor(yv, 8, 64);
      yacc[i] = yv;
    }
    if (n == 0) {
#pragma unroll
      for (int i = 0; i < 8; ++i) {
        int d = dg * 8 + i;
        yp[(size_t)l * 128 + d] = yacc[i] + Dv[i] * x_s[buf][d];
      }
    }
  }
}

// ============ 8+9+10. comb + LN + gate + x2 + LN + FFN conv1 (fused, 8 tok) ============
__global__ __launch_bounds__(256) void k_combffn1(const float* __restrict__ enc,
    const float* __restrict__ nw, const float* __restrict__ nb,
    const float* __restrict__ snr, const float* __restrict__ ow,
    const float* __restrict__ lw, const float* __restrict__ lb,
    const float* __restrict__ w1, float* __restrict__ ws) {
  int l0 = blockIdx.x * TT, b = blockIdx.y, t = threadIdx.x;
  __shared__ float yr[128][9];
  __shared__ float redm[2][TT], redq[2][TT];
  __shared__ float part[2][TT][64];
  __shared__ float xn_s[64][9];
  int lane = t & 63, wid = (t >> 6) & 1;
  float v[TT], m[TT];
  if (t < 128) {
    int d = t;
    const float* ysb = ws + OYS2;
#pragma unroll
    for (int i = 0; i < TT; ++i) {
      int l = l0 + i;
      int hh = l / 48, wwp = l % 48;
      int lT = wwp * 48 + hh;
      v[i] = ysb[((size_t)(b * 4 + 0) * Ll + l) * 128 + d] +
             ysb[((size_t)(b * 4 + 2) * Ll + (2303 - l)) * 128 + d] +
             ysb[((size_t)(b * 4 + 1) * Ll + lT) * 128 + d] +
             ysb[((size_t)(b * 4 + 3) * Ll + (2303 - lT)) * 128 + d];
    }
    float s[TT];
#pragma unroll
    for (int i = 0; i < TT; ++i) s[i] = v[i];
#pragma unroll
    for (int o = 32; o >= 1; o >>= 1)
#pragma unroll
      for (int i = 0; i < TT; ++i) s[i] += __shfl_xor(s[i], o, 64);
    if (lane == 0) {
#pragma unroll
      for (int i = 0; i < TT; ++i) redm[wid][i] = s[i];
    }
  }
  __syncthreads();
  if (t < 128) {
    float q[TT];
#pragma unroll
    for (int i = 0; i < TT; ++i) {
      m[i] = (redm[0][i] + redm[1][i]) * (1.f / 128.f);
      float dv = v[i] - m[i];
      q[i] = dv * dv;
    }
#pragma unroll
    for (int o = 32; o >= 1; o >>= 1)
#pragma unroll
      for (int i = 0; i < TT; ++i) q[i] += __shfl_xor(q[i], o, 64);
    if (lane == 0) {
#pragma unroll
      for (int i = 0; i < TT; ++i) redq[wid][i] = q[i];
    }
  }
  __syncthreads();
  if (t < 128) {
    int d = t;
    float nwv = nw[d], nbv = nb[d];
#pragma unroll
    for (int i = 0; i < TT; ++i) {
      int l = l0 + i;
      float var = (redq[0][i] + redq[1][i]) * (1.f / 128.f);
      float y = (v[i] - m[i]) * rsqrtf(var + 1e-5f) * nwv + nbv;
      float zv = ws[OZ + ((size_t)(b * Ll + l)) * 128 + d];
      y *= siluf(zv);
      y *= snr[b * Ll + l];
      yr[d][i] = y;
    }
  }
  __syncthreads();
  if (t < 128) {
    int col = t & 63, seg = t >> 6;
    float acc[TT];
#pragma unroll
    for (int i = 0; i < TT; ++i) acc[i] = 0.f;
    const float* ows = ow + (size_t)(seg * 64) * 64 + col;
    for (int c = 0; c < 64; ++c) {
      float w = ows[c * 64];
      const float* yc = &yr[seg * 64 + c][0];
#pragma unroll
      for (int i = 0; i < TT; ++i) acc[i] += yc[i] * w;
    }
#pragma unroll
    for (int i = 0; i < TT; ++i) part[seg][i][col] = acc[i];
  }
  __syncthreads();
  {
    int wv = t >> 6, col2 = t & 63;
    float lwv = lw[col2], lbv = lb[col2];
#pragma unroll
    for (int i2 = 0; i2 < 2; ++i2) {
      int i = wv * 2 + i2;
      float a = part[0][i][col2] + part[1][i][col2];
      a += enc[(size_t)b * Cc * Ll + (size_t)col2 * Ll + l0 + i];
      ws[OX2 + ((size_t)(b * Ll + l0 + i)) * 64 + col2] = a;
      float s = a;
#pragma unroll
      for (int o = 32; o >= 1; o >>= 1) s += __shfl_xor(s, o, 64);
      float mm = s * (1.f / 64.f);
      float dd2 = a - mm;
      float vs = dd2 * dd2;
#pragma unroll
      for (int o = 32; o >= 1; o >>= 1) vs += __shfl_xor(vs, o, 64);
      xn_s[col2][i] = dd2 * rsqrtf(vs * (1.f / 64.f) + 1e-5f) * lwv + lbv;
    }
  }
  __syncthreads();
  {
    float acc2[TT];
#pragma unroll
    for (int i = 0; i < TT; ++i) acc2[i] = 0.f;
    const float* wp = w1 + (size_t)t * 64;
    for (int c = 0; c < 64; ++c) {
      float w = wp[c];
      const float* xc = &xn_s[c][0];
#pragma unroll
      for (int i = 0; i < TT; ++i) acc2[i] += xc[i] * w;
    }
#pragma unroll
    for (int i = 0; i < TT; ++i)
      ws[OH1A + ((size_t)(b * Ll + l0 + i)) * 256 + t] = geluf(acc2[i]);
  }
}

// ============ 11+12. FFN depthwise 3x3 + gelu + conv2 + residual + out (fused) ============
__global__ __launch_bounds__(256) void k_ffndw2(const float* __restrict__ dww,
    const float* __restrict__ w2, float* __restrict__ ws,
    float* __restrict__ out) {
  int l0 = blockIdx.x * TT, b = blockIdx.y, t = threadIdx.x;
  int h = l0 / 48, w0 = l0 % 48;
  __shared__ float smem[3 * 10 * 256];   // tile, then reused as hr[256][9]
  __shared__ float part[4][TT][64];
  float* tile = smem;
  for (int idx = t; idx < 7680; idx += 256) {
    int r = idx / 2560, rem = idx % 2560;
    int col = rem >> 8, ch = rem & 255;
    int hh = h + r - 1, wx = w0 + col - 1;
    float v = 0.f;
    if (hh >= 0 && hh < 48 && wx >= 0 && wx < 48)
      v = ws[OH1A + ((size_t)(b * Ll + hh * 48 + wx)) * 256 + ch];
    tile[r * 2560 + col * 256 + ch] = v;
  }
  __syncthreads();
  float dwr[9];
#pragma unroll
  for (int j = 0; j < 9; ++j) dwr[j] = dww[t * 9 + j];
  float hv[TT];
#pragma unroll
  for (int i = 0; i < TT; ++i) {
    float acc = 0.f;
#pragma unroll
    for (int kh = 0; kh < 3; ++kh)
#pragma unroll
      for (int kw = 0; kw < 3; ++kw)
        acc += tile[kh * 2560 + (i + kw) * 256 + t] * dwr[kh * 3 + kw];
    hv[i] = geluf(acc);
  }
  __syncthreads();
  float* hr = smem;   // reused: [256][9]
#pragma unroll
  for (int i = 0; i < TT; ++i) hr[t * 9 + i] = hv[i];
  __syncthreads();
  int col = t & 63, seg = t >> 6;
  {
    float acc[TT];
#pragma unroll
    for (int i = 0; i < TT; ++i) acc[i] = 0.f;
    const float* wp = w2 + (size_t)col * 256 + seg * 64;
    for (int c = 0; c < 64; ++c) {
      float w = wp[c];
      const float* hc = &hr[(seg * 64 + c) * 9];
#pragma unroll
      for (int i = 0; i < TT; ++i) acc[i] += hc[i] * w;
    }
#pragma unroll
    for (int i = 0; i < TT; ++i) part[seg][i][col] = acc[i];
  }
  __syncthreads();
  if (t < 64) {
    float av[TT];
#pragma unroll
    for (int i = 0; i < TT; ++i) {
      float a = part[0][i][t] + part[1][i][t] + part[2][i][t] + part[3][i][t];
      av[i] = a + ws[OX2 + ((size_t)(b * Ll + l0 + i)) * 64 + t];
    }
    float* opx = out + ((size_t)(b * 64 + t)) * 2304 + l0;
    *(float4*)opx = make_float4(av[0], av[1], av[2], av[3]);
    *((float4*)opx + 1) = make_float4(av[4], av[5], av[6], av[7]);
  }
}

extern "C" void kernel_launch(void* const* d_in, const int* in_sizes, int n_in,
                              void* d_out, int out_size, void* d_ws, size_t ws_size,
                              hipStream_t stream) {
  (void)in_sizes; (void)n_in; (void)out_size;
  const float* enc  = (const float*)d_in[0];
  const float* snr  = (const float*)d_in[1];
  const float* wq   = (const float*)d_in[2];
  const float* wk   = (const float*)d_in[3];
  const float* wv   = (const float*)d_in[4];
  const float* fc   = (const float*)d_in[5];
  const float* alnw = (const float*)d_in[6];
  const float* alnb = (const float*)d_in[7];
  const float* ssin = (const float*)d_in[8];
  const float* cw   = (const float*)d_in[9];
  const float* cb   = (const float*)d_in[10];
  const float* xw   = (const float*)d_in[11];
  const float* dtw  = (const float*)d_in[12];
  const float* dtb  = (const float*)d_in[13];
  const float* alog = (const float*)d_in[14];
  const float* Dp   = (const float*)d_in[15];
  const float* nw   = (const float*)d_in[16];
  const float* nb   = (const float*)d_in[17];
  const float* ow   = (const float*)d_in[18];
  const float* flnw = (const float*)d_in[19];
  const float* flnb = (const float*)d_in[20];
  const float* w1   = (const float*)d_in[21];
  const float* dww  = (const float*)d_in[22];
  const float* w2   = (const float*)d_in[23];
  float* ws = (float*)d_ws;
  float* out = (float*)d_out;

  if (ws_size < (size_t)WS_NEED_FLOATS * 4) {
    hipLaunchKernelGGL(k_code, dim3(1), dim3(64), 0, stream, out);
    return;
  }

  hipLaunchKernelGGL(k_prep, dim3(128), dim3(256), 0, stream, wq, wk, wv, ws);
  hipLaunchKernelGGL(k_qkv, dim3(Ll / TT2, Bq, 4), dim3(256), 0, stream, enc, ws);
  hipLaunchKernelGGL(k_vt, dim3(Ll / 64, 17), dim3(256), 0, stream, fc, ws);
  hipLaunchKernelGGL(k_attn, dim3(Ll / 64, Bq * NHh, 2), dim3(256), 0, stream, snr, ws);
  hipLaunchKernelGGL(k_oprojxz, dim3(Ll / TT2, Bq), dim3(256), 0, stream, enc, alnw, alnb, ssin, ws);
  hipLaunchKernelGGL(k_conv, dim3(Ll / TT, Bq), dim3(256), 0, stream, cw, cb, ws);
  hipLaunchKernelGGL(k_xdbl, dim3(Ll / TT, Bq * 4), dim3(128), 0, stream, xw, dtw, dtb, ws);
  hipLaunchKernelGGL(k_scanA, dim3(SNC, Bq * 4), dim3(256), 0, stream, alog, ws);
  hipLaunchKernelGGL(k_scanB, dim3(64), dim3(256), 0, stream, ws);
  hipLaunchKernelGGL(k_scanC, dim3(SNC, Bq * 4), dim3(256), 0, stream, alog, Dp, ws);
  hipLaunchKernelGGL(k_combffn1, dim3(Ll / TT, Bq), dim3(256), 0, stream, enc, nw, nb, snr, ow, flnw, flnb, w1, ws);
  hipLaunchKernelGGL(k_ffndw2, dim3(Ll / TT, Bq), dim3(256), 0, stream, dww, w2, ws, out);
}